// Round 5
// baseline (2370.151 us; speedup 1.0000x reference)
//
#include <hip/hip_runtime.h>

typedef unsigned short u16;
typedef unsigned int u32;

using s8v = __attribute__((ext_vector_type(8))) short;  // 8 bf16
using f4v = __attribute__((ext_vector_type(4))) float;  // 4 fp32

#define LN_EPS 0.001f
#define STAB 0.001f
#define NORM_OBJ 0.35355339059327373f   // 64^-0.25
#define NORM_ROAD 0.7071067811865476f   // 4^-0.25

__device__ __forceinline__ float bf2f(u16 v) { return __uint_as_float(((u32)v) << 16); }
__device__ __forceinline__ u16 f2bf(float f) {
  u32 u = __float_as_uint(f);
  u32 r = (u + 0x7fffu + ((u >> 16) & 1u)) >> 16;
  return (u16)r;
}
__device__ __forceinline__ f4v mfma16(s8v a, s8v b, f4v c) {
  return __builtin_amdgcn_mfma_f32_16x16x32_bf16(a, b, c, 0, 0, 0);
}
// async global->LDS, 16 B/lane; LDS dest = wave-uniform base + lane*16
__device__ __forceinline__ void ldsload16(void* lds, const void* g) {
  __builtin_amdgcn_global_load_lds((const __attribute__((address_space(1))) u32*)g,
                                   (__attribute__((address_space(3))) u32*)lds, 16, 0, 0);
}

// ---------------- transpose+convert: src[K][N] f32 -> dst[N][K] bf16 ----------------
struct TPair { const float* s; u16* d; };
struct TP11 { TPair p[11]; };

__global__ __launch_bounds__(256) void transpose_kernel(TP11 ps, int K, int N) {
  const float* __restrict__ src = ps.p[blockIdx.z].s;
  u16* __restrict__ dst = ps.p[blockIdx.z].d;
  int n0 = blockIdx.x * 64, k0 = blockIdx.y * 64;
  int t = threadIdx.x;
  __shared__ __align__(16) u16 lt[64 * 72];
#pragma unroll
  for (int j = 0; j < 4; ++j) {
    int p = t + 256 * j;
    int r = p >> 4, cb = p & 15;
    float4 v = *(const float4*)(src + (size_t)(k0 + r) * N + n0 + cb * 4);
    lt[r * 72 + cb * 4 + 0] = f2bf(v.x);
    lt[r * 72 + cb * 4 + 1] = f2bf(v.y);
    lt[r * 72 + cb * 4 + 2] = f2bf(v.z);
    lt[r * 72 + cb * 4 + 3] = f2bf(v.w);
  }
  __syncthreads();
#pragma unroll
  for (int j = 0; j < 2; ++j) {
    int q = t + 256 * j;
    int on = q >> 3, ocb = q & 7;
    u16 e[8];
#pragma unroll
    for (int i = 0; i < 8; ++i) e[i] = lt[(ocb * 8 + i) * 72 + on];
    uint4 v;
    v.x = (u32)e[0] | ((u32)e[1] << 16);
    v.y = (u32)e[2] | ((u32)e[3] << 16);
    v.z = (u32)e[4] | ((u32)e[5] << 16);
    v.w = (u32)e[6] | ((u32)e[7] << 16);
    *(uint4*)(dst + (size_t)(n0 + on) * K + k0 + ocb * 8) = v;
  }
}

// ---------------- f32 -> bf16 convert ----------------
__global__ __launch_bounds__(256) void cvt_kernel(const float* __restrict__ src,
                                                  u16* __restrict__ dst) {
  int i = (blockIdx.x * 256 + threadIdx.x) * 4;
  float4 v = *(const float4*)(src + i);
  uint2 o;
  o.x = (u32)f2bf(v.x) | ((u32)f2bf(v.y) << 16);
  o.y = (u32)f2bf(v.z) | ((u32)f2bf(v.w) << 16);
  *(uint2*)(dst + i) = o;
}

// ---------------- road: x = relu(road @ Wd + bd), 65536 x (8->16) ----------------
__global__ __launch_bounds__(256) void r0_kernel(const float* __restrict__ road,
    const float* __restrict__ W, const float* __restrict__ bias, float* __restrict__ x) {
  int row = blockIdx.x * 256 + threadIdx.x;
  float in[8];
  float4 v0 = *(const float4*)(road + (size_t)row * 8);
  float4 v1 = *(const float4*)(road + (size_t)row * 8 + 4);
  in[0] = v0.x; in[1] = v0.y; in[2] = v0.z; in[3] = v0.w;
  in[4] = v1.x; in[5] = v1.y; in[6] = v1.z; in[7] = v1.w;
#pragma unroll
  for (int j = 0; j < 16; ++j) {
    float s = bias[j];
#pragma unroll
    for (int c = 0; c < 8; ++c) s += in[c] * W[c * 16 + j];
    x[(size_t)row * 16 + j] = fmaxf(s, 0.f);
  }
}

// ---------------- road favor pass1: accumulate kv_road/ksum_road ----------------
__global__ __launch_bounds__(256) void ra_kernel(const float* __restrict__ x,
    const float* __restrict__ qkvW, const float* __restrict__ qkvb,
    const float* __restrict__ Wk, const float* __restrict__ Wv,
    float* __restrict__ kvr, float* __restrict__ ksr) {
  int t = threadIdx.x;
  int row = blockIdx.x * 256 + t;
  int b = row >> 13;
  float xv[16];
#pragma unroll
  for (int e = 0; e < 16; ++e) xv[e] = x[(size_t)row * 16 + e];
  float q16[16];
#pragma unroll
  for (int j = 0; j < 16; ++j) {
    float s = qkvb[j];
#pragma unroll
    for (int c = 0; c < 16; ++c) s += xv[c] * qkvW[c * 48 + j];
    q16[j] = fmaxf(s, 0.f);
  }
  float kp[16], vh[16];
#pragma unroll
  for (int hm = 0; hm < 16; ++hm) {
    float sk = 0.f, sv = 0.f;
#pragma unroll
    for (int c = 0; c < 16; ++c) {
      float q = q16[c];
      sk += q * Wk[c * 16 + hm];
      sv += q * Wv[c * 16 + hm];
    }
    kp[hm] = fmaxf(sk * NORM_ROAD, 0.f) + STAB;
    vh[hm] = sv;
  }
  __shared__ float l[80];
  if (t < 80) l[t] = 0.f;
  __syncthreads();
#pragma unroll
  for (int h = 0; h < 4; ++h)
#pragma unroll
    for (int m = 0; m < 4; ++m) {
      float kpv = kp[h * 4 + m];
      atomicAdd(&l[64 + h * 4 + m], kpv);
#pragma unroll
      for (int d = 0; d < 4; ++d) atomicAdd(&l[h * 16 + m * 4 + d], kpv * vh[h * 4 + d]);
    }
  __syncthreads();
  if (t < 64) atomicAdd(&kvr[b * 64 + t], l[t]);
  else if (t < 80) atomicAdd(&ksr[b * 16 + (t - 64)], l[t]);
}

__device__ __forceinline__ void ln16(const float* tv, const float* g, const float* bb, float* o) {
  float m = 0.f;
#pragma unroll
  for (int e = 0; e < 16; ++e) m += tv[e];
  m *= (1.f / 16.f);
  float var = 0.f;
#pragma unroll
  for (int e = 0; e < 16; ++e) { float d = tv[e] - m; var += d * d; }
  var *= (1.f / 16.f);
  float rstd = rsqrtf(var + LN_EPS);
#pragma unroll
  for (int e = 0; e < 16; ++e) o[e] = (tv[e] - m) * rstd * g[e] + bb[e];
}

// ---------------- road favor pass2 + LN + fc + LN (in-place x update) ----------------
__global__ __launch_bounds__(256) void rb_kernel(float* __restrict__ x,
    const float* __restrict__ qkvW, const float* __restrict__ qkvb,
    const float* __restrict__ Wq, const float* __restrict__ Wo,
    const float* __restrict__ lng, const float* __restrict__ lnb,
    const float* __restrict__ fcW, const float* __restrict__ fcb,
    const float* __restrict__ kvr, const float* __restrict__ ksr) {
  int row = blockIdx.x * 256 + threadIdx.x;
  int b = row >> 13;
  float xv[16];
#pragma unroll
  for (int e = 0; e < 16; ++e) xv[e] = x[(size_t)row * 16 + e];
  float q16[16];
#pragma unroll
  for (int j = 0; j < 16; ++j) {
    float s = qkvb[j];
#pragma unroll
    for (int c = 0; c < 16; ++c) s += xv[c] * qkvW[c * 48 + j];
    q16[j] = fmaxf(s, 0.f);
  }
  float qp[16];
#pragma unroll
  for (int hm = 0; hm < 16; ++hm) {
    float s = 0.f;
#pragma unroll
    for (int c = 0; c < 16; ++c) s += q16[c] * Wq[c * 16 + hm];
    qp[hm] = fmaxf(s * NORM_ROAD, 0.f) + STAB;
  }
  float attn[16];
#pragma unroll
  for (int e = 0; e < 16; ++e) attn[e] = 0.f;
#pragma unroll
  for (int h = 0; h < 4; ++h) {
    float den = 0.f;
#pragma unroll
    for (int m = 0; m < 4; ++m) den += qp[h * 4 + m] * ksr[b * 16 + h * 4 + m];
    float od[4];
#pragma unroll
    for (int d = 0; d < 4; ++d) {
      float num = 0.f;
#pragma unroll
      for (int m = 0; m < 4; ++m) num += qp[h * 4 + m] * kvr[b * 64 + h * 16 + m * 4 + d];
      od[d] = num / den;
    }
#pragma unroll
    for (int d = 0; d < 4; ++d)
#pragma unroll
      for (int e = 0; e < 16; ++e) attn[e] += od[d] * Wo[(h * 4 + d) * 16 + e];
  }
  float tv[16], n[16], o2[16];
#pragma unroll
  for (int e = 0; e < 16; ++e) tv[e] = attn[e] + xv[e];
  ln16(tv, lng, lnb, n);
#pragma unroll
  for (int j = 0; j < 16; ++j) {
    float s = fcb[j];
#pragma unroll
    for (int e = 0; e < 16; ++e) s += n[e] * fcW[e * 16 + j];
    tv[j] = n[j] + fmaxf(s, 0.f);
  }
  ln16(tv, lng, lnb, o2);
#pragma unroll
  for (int e = 0; e < 16; ++e) x[(size_t)row * 16 + e] = o2[e];
}

// ---------------- rg_out = relu(x_road @ rg_out_W + b) -> bf16, 65536x1024 ----------------
__global__ __launch_bounds__(256) void rc_kernel(const float* __restrict__ x,
    const float* __restrict__ W, const float* __restrict__ bias, u16* __restrict__ out) {
  const int t = threadIdx.x;
  const int cg = t & 63, rg = t >> 6;
  const int c0 = blockIdx.x * 256 + cg * 4;
  const int r0 = blockIdx.y * 16;
  __shared__ float lx[256];
  lx[t] = x[(size_t)(r0 + (t >> 4)) * 16 + (t & 15)];
  __syncthreads();
  float4 wv[16];
#pragma unroll
  for (int c = 0; c < 16; ++c) wv[c] = *(const float4*)(W + (size_t)c * 1024 + c0);
  float4 bv = *(const float4*)(bias + c0);
#pragma unroll
  for (int k = 0; k < 4; ++k) {
    int rr = rg * 4 + k;
    float s0 = bv.x, s1 = bv.y, s2 = bv.z, s3 = bv.w;
#pragma unroll
    for (int c = 0; c < 16; ++c) {
      float xv = lx[rr * 16 + c];
      s0 += xv * wv[c].x; s1 += xv * wv[c].y; s2 += xv * wv[c].z; s3 += xv * wv[c].w;
    }
    uint2 o;
    o.x = (u32)f2bf(fmaxf(s0, 0.f)) | ((u32)f2bf(fmaxf(s1, 0.f)) << 16);
    o.y = (u32)f2bf(fmaxf(s2, 0.f)) | ((u32)f2bf(fmaxf(s3, 0.f)) << 16);
    *(uint2*)(out + (size_t)(r0 + rr) * 1024 + c0) = o;
  }
}

// ---------------- MFMA GEMM, 64x128 tile: C = act(A[MxK] @ BT[NxK]^T) ----------------
// grid (N/128, M/64); XOR-swizzled global_load_lds staging
__global__ __launch_bounds__(256) void gemm64_kernel(
    const u16* __restrict__ A, const u16* __restrict__ BT, int K,
    float* __restrict__ outF, u16* __restrict__ outB,
    const float* __restrict__ bias, const float* __restrict__ resF, int resmod,
    float scale, int do_relu, float post) {
  const int n0 = blockIdx.x * 128, m0 = blockIdx.y * 64;
  const int t = threadIdx.x;
  const int wid = t >> 6, lane = t & 63, quad = lane >> 4, m16 = lane & 15;
  const int wm = wid >> 1, wn = wid & 1;
  const int lrr = lane >> 3;
  const int lcs = (((lane & 7) ^ lrr) * 8);
  const int sw = m16 & 7;
  __shared__ __align__(16) u16 smem[64 * 64 + 128 * 64];
  u16* Al = smem;
  u16* Bl = smem + 64 * 64;
  f4v acc[2][4];
#pragma unroll
  for (int i = 0; i < 2; ++i)
#pragma unroll
    for (int j = 0; j < 4; ++j) acc[i][j] = {0.f, 0.f, 0.f, 0.f};

  for (int kc = 0; kc < K; kc += 64) {
    __syncthreads();
#pragma unroll
    for (int j = 0; j < 2; ++j) {
      int rbase = wid * 16 + j * 8;
      ldsload16(Al + rbase * 64, A + (size_t)(m0 + rbase + lrr) * K + kc + lcs);
    }
#pragma unroll
    for (int j = 0; j < 4; ++j) {
      int rbase = wid * 32 + j * 8;
      ldsload16(Bl + rbase * 64, BT + (size_t)(n0 + rbase + lrr) * K + kc + lcs);
    }
    __syncthreads();
#pragma unroll
    for (int ko = 0; ko < 64; ko += 32) {
      int g0 = ko >> 3;
      s8v af[2], bfr[4];
#pragma unroll
      for (int tm = 0; tm < 2; ++tm)
        af[tm] = *(const s8v*)(Al + (wm * 32 + tm * 16 + m16) * 64 + ((g0 + quad) ^ sw) * 8);
#pragma unroll
      for (int tn = 0; tn < 4; ++tn)
        bfr[tn] = *(const s8v*)(Bl + (wn * 64 + tn * 16 + m16) * 64 + ((g0 + quad) ^ sw) * 8);
#pragma unroll
      for (int tm = 0; tm < 2; ++tm)
#pragma unroll
        for (int tn = 0; tn < 4; ++tn)
          acc[tm][tn] = mfma16(af[tm], bfr[tn], acc[tm][tn]);
    }
  }
#pragma unroll
  for (int tm = 0; tm < 2; ++tm)
#pragma unroll
    for (int tn = 0; tn < 4; ++tn)
#pragma unroll
      for (int r = 0; r < 4; ++r) {
        int row = m0 + wm * 32 + tm * 16 + quad * 4 + r;
        int col = n0 + wn * 64 + tn * 16 + m16;
        float v = acc[tm][tn][r] * scale;
        if (bias) v += bias[col];
        if (do_relu) v = fmaxf(v, 0.f);
        v += post;
        if (resF) v += resF[(size_t)(row % resmod) * 1024 + col];
        if (outF) outF[(size_t)row * 1024 + col] = v;
        if (outB) outB[(size_t)row * 1024 + col] = f2bf(v);
      }
}

// ---------------- fused K/V projection + kv/ksum accumulation, 2 heads/block ----------------
// grid (8 head-pairs, 64 s-tiles, 8 batches); tile 128 s-rows x 256 cols (2 heads x (64k|64v))
__global__ __launch_bounds__(256) void kv_kernel(
    const u16* __restrict__ rgout, const u16* __restrict__ WkT, const u16* __restrict__ WvT,
    float* __restrict__ kv, float* __restrict__ ksum) {
  const int hp = blockIdx.x, mt = blockIdx.y, b = blockIdx.z;
  const int t = threadIdx.x;
  const int wid = t >> 6, lane = t & 63, quad = lane >> 4, m16 = lane & 15;
  const int wm = wid >> 1, wn = wid & 1;
  const int lrr = lane >> 3;
  const int lcs = (((lane & 7) ^ lrr) * 8);
  const int sw = m16 & 7;
  const int HSZ = 64 * 136;  // one transpose matrix, u16 elems
  __shared__ __align__(16) u16 smem[4 * 64 * 136];  // 69632 B; main loop uses 49152 B
  u16* Al = smem;              // [128][64] swizzled
  u16* Bl = smem + 128 * 64;   // [256][64] swizzled
  const size_t abase = ((size_t)b * 8192 + (size_t)mt * 128) * 1024;
  f4v acc[4][8];
#pragma unroll
  for (int i = 0; i < 4; ++i)
#pragma unroll
    for (int j = 0; j < 8; ++j) acc[i][j] = {0.f, 0.f, 0.f, 0.f};

  for (int kc = 0; kc < 1024; kc += 64) {
    __syncthreads();
#pragma unroll
    for (int j = 0; j < 4; ++j) {
      int rbase = wid * 32 + j * 8;
      ldsload16(Al + rbase * 64, rgout + abase + (size_t)(rbase + lrr) * 1024 + kc + lcs);
    }
#pragma unroll
    for (int j = 0; j < 8; ++j) {
      int rbase = wid * 64 + j * 8;
      int r = rbase + lrr;
      int h = hp * 2 + (r >> 7), rr = r & 127;
      const u16* bsrc = (rr < 64) ? (WkT + (size_t)(h * 64 + rr) * 1024)
                                  : (WvT + (size_t)(h * 64 + (rr - 64)) * 1024);
      ldsload16(Bl + rbase * 64, bsrc + kc + lcs);
    }
    __syncthreads();
#pragma unroll
    for (int ko = 0; ko < 64; ko += 32) {
      int g0 = ko >> 3;
      s8v af[4], bfr[8];
#pragma unroll
      for (int tm = 0; tm < 4; ++tm)
        af[tm] = *(const s8v*)(Al + (wm * 64 + tm * 16 + m16) * 64 + ((g0 + quad) ^ sw) * 8);
#pragma unroll
      for (int tn = 0; tn < 8; ++tn)
        bfr[tn] = *(const s8v*)(Bl + (wn * 128 + tn * 16 + m16) * 64 + ((g0 + quad) ^ sw) * 8);
#pragma unroll
      for (int tm = 0; tm < 4; ++tm)
#pragma unroll
        for (int tn = 0; tn < 8; ++tn)
          acc[tm][tn] = mfma16(af[tm], bfr[tn], acc[tm][tn]);
    }
  }
  __syncthreads();
  // epilogue: wave wn owns head hp*2+wn; local col c<64 => kp (relu*norm+stab), else v
  {
    u16* KPT = smem + (size_t)(wn * 2) * HSZ;
    u16* VT = KPT + HSZ;
#pragma unroll
    for (int tm = 0; tm < 4; ++tm)
#pragma unroll
      for (int tn = 0; tn < 8; ++tn)
#pragma unroll
        for (int r = 0; r < 4; ++r) {
          int srow = wm * 64 + tm * 16 + quad * 4 + r;
          int c = tn * 16 + m16;
          float v = acc[tm][tn][r];
          if (tn < 4) {
            v = fmaxf(v * NORM_OBJ, 0.f) + STAB;
            KPT[c * 136 + srow] = f2bf(v);
          } else {
            VT[(c - 64) * 136 + srow] = f2bf(v);
          }
        }
  }
  __syncthreads();
  // ksum partials: 128 threads, head = t>>6, m = t&63
  if (t < 128) {
    int hh = t >> 6, m = t & 63;
    const u16* base = smem + (size_t)(hh * 2) * HSZ + m * 136;
    float s = 0.f;
#pragma unroll
    for (int i = 0; i < 128; i += 8) {
      uint4 v = *(const uint4*)(base + i);
      u32 a[4] = {v.x, v.y, v.z, v.w};
#pragma unroll
      for (int q = 0; q < 4; ++q) {
        s += __uint_as_float(a[q] << 16);
        s += __uint_as_float(a[q] & 0xffff0000u);
      }
    }
    atomicAdd(&ksum[(size_t)(b * 16 + hp * 2 + hh) * 64 + m], s);
  }
  // second GEMM per head: kv_partial[64 m][64 d] = sum_s kp[s][m]*v[s][d], K=128
  // wave (wm,wn): head = wn, m-rows [wm*32, wm*32+32)
  {
    u16* KPh = smem + (size_t)(wn * 2) * HSZ;
    u16* Vh = KPh + HSZ;
    f4v a2[2][4];
#pragma unroll
    for (int i = 0; i < 2; ++i)
#pragma unroll
      for (int j = 0; j < 4; ++j) a2[i][j] = {0.f, 0.f, 0.f, 0.f};
#pragma unroll
    for (int ks = 0; ks < 128; ks += 32) {
      s8v af2[2], bv[4];
#pragma unroll
      for (int tm = 0; tm < 2; ++tm)
        af2[tm] = *(const s8v*)(KPh + (wm * 32 + tm * 16 + m16) * 136 + ks + quad * 8);
#pragma unroll
      for (int tn = 0; tn < 4; ++tn)
        bv[tn] = *(const s8v*)(Vh + (tn * 16 + m16) * 136 + ks + quad * 8);
#pragma unroll
      for (int tm = 0; tm < 2; ++tm)
#pragma unroll
        for (int tn = 0; tn < 4; ++tn)
          a2[tm][tn] = mfma16(af2[tm], bv[tn], a2[tm][tn]);
    }
    int h = hp * 2 + wn;
#pragma unroll
    for (int tm = 0; tm < 2; ++tm)
#pragma unroll
      for (int tn = 0; tn < 4; ++tn)
#pragma unroll
        for (int r = 0; r < 4; ++r) {
          int m = wm * 32 + tm * 16 + quad * 4 + r;
          int d = tn * 16 + m16;
          atomicAdd(&kv[((size_t)(b * 16 + h) * 64 + m) * 64 + d], a2[tm][tn][r]);
        }
  }
}

// ---------------- obj favor: out = (qp @ kv) / (qp . ksum) per row/head ----------------
// grid (256 row-blocks, 4 head-groups)
__global__ __launch_bounds__(256) void q2_kernel(const u16* __restrict__ qp,
    const float* __restrict__ kv, const float* __restrict__ ks, u16* __restrict__ out) {
  int wid = threadIdx.x >> 6, lane = threadIdx.x & 63;
  int row = blockIdx.x * 4 + wid;
  int b = row >> 7;
  int h0 = blockIdx.y * 4;
  for (int h = h0; h < h0 + 4; ++h) {
    const float* kvp = kv + (size_t)((b * 16 + h) * 64) * 64;
    const float* ksp = ks + (size_t)(b * 16 + h) * 64;
    const u16* qpp = qp + (size_t)row * 1024 + h * 64;
    float num = 0.f, den = 0.f;
    for (int m = 0; m < 64; ++m) {
      float qv = bf2f(qpp[m]);
      num += qv * kvp[m * 64 + lane];
      den += qv * ksp[m];
    }
    out[(size_t)row * 1024 + h * 64 + lane] = f2bf(num / den);
  }
}

// ---------------- layernorm over 1024, one block per row ----------------
__global__ __launch_bounds__(256) void ln_kernel(const float* __restrict__ in,
    const float* __restrict__ g, const float* __restrict__ bb,
    float* __restrict__ outF, u16* __restrict__ outB) {
  int row = blockIdx.x, t = threadIdx.x;
  const float* x = in + (size_t)row * 1024;
  float v[4];
  float s = 0.f, ss = 0.f;
#pragma unroll
  for (int j = 0; j < 4; ++j) {
    v[j] = x[t + 256 * j];
    s += v[j];
    ss += v[j] * v[j];
  }
  __shared__ float rs[256], rss[256];
  rs[t] = s; rss[t] = ss;
  __syncthreads();
  for (int o = 128; o > 0; o >>= 1) {
    if (t < o) { rs[t] += rs[t + o]; rss[t] += rss[t + o]; }
    __syncthreads();
  }
  float mean = rs[0] * (1.f / 1024.f);
  float var = rss[0] * (1.f / 1024.f) - mean * mean;
  float rstd = rsqrtf(var + LN_EPS);
#pragma unroll
  for (int j = 0; j < 4; ++j) {
    int c = t + 256 * j;
    float o = (v[j] - mean) * rstd * g[c] + bb[c];
    if (outF) outF[(size_t)row * 1024 + c] = o;
    if (outB) outB[(size_t)row * 1024 + c] = f2bf(o);
  }
}

// ---------------- workspace layout (bytes) ----------------
static constexpr size_t MBy = 1048576;
static constexpr size_t OFF_XROAD = 0;                       // 4 MB f32 (65536x16)
static constexpr size_t OFF_RGOUT = 4 * MBy;                 // 128 MiB bf16 (65536x1024)
static constexpr size_t OFF_KVR = OFF_RGOUT + 128 * MBy;     // 2048 B
static constexpr size_t OFF_KSR = OFF_KVR + 2048;            // 512 B
static constexpr size_t OFF_KVO = OFF_KVR + 4096;            // 2 MB f32
static constexpr size_t OFF_KSO = OFF_KVO + 2 * MBy;         // 32 KB f32
static constexpr size_t OFF_WT = OFF_KSO + 65536;            // 21 MB bf16 transposed weights
static constexpr size_t OFF_XOBJ = OFF_WT + 21 * MBy;        // 4 MB f32
static constexpr size_t OFF_XOBJB = OFF_XOBJ + 4 * MBy;      // 2 MB bf16
static constexpr size_t OFF_QP = OFF_XOBJB + 2 * MBy;        // 2 MB bf16
static constexpr size_t OFF_FOUT = OFF_QP + 2 * MBy;         // 2 MB bf16
static constexpr size_t OFF_T1 = OFF_FOUT + 2 * MBy;         // 4 MB f32
static constexpr size_t OFF_N = OFF_T1 + 4 * MBy;            // 4 MB f32
static constexpr size_t OFF_NB = OFF_N + 4 * MBy;            // 2 MB bf16
static constexpr size_t OFF_OBJB = OFF_NB + 2 * MBy;         // 1 MB bf16 (1024x512)

extern "C" void kernel_launch(void* const* d_in, const int* in_sizes, int n_in,
                              void* d_out, int out_size, void* d_ws, size_t ws_size,
                              hipStream_t stream) {
  (void)in_sizes; (void)n_in; (void)out_size; (void)ws_size;
  const float* obj = (const float*)d_in[0];
  const float* road = (const float*)d_in[1];
  const float* rgdW = (const float*)d_in[2];
  const float* rgdb = (const float*)d_in[3];
  const float* qkvW = (const float*)d_in[4];
  const float* qkvb = (const float*)d_in[5];
  const float* rgWq = (const float*)d_in[6];
  const float* rgWk = (const float*)d_in[7];
  const float* rgWv = (const float*)d_in[8];
  const float* rgWo = (const float*)d_in[9];
  const float* rglng = (const float*)d_in[10];
  const float* rglnb = (const float*)d_in[11];
  const float* rgfcW = (const float*)d_in[12];
  const float* rgfcb = (const float*)d_in[13];
  const float* rgoW = (const float*)d_in[14];
  const float* rgob = (const float*)d_in[15];
  const float* denW = (const float*)d_in[16];
  const float* denb = (const float*)d_in[17];
  const float* pose = (const float*)d_in[18];
  const float* Wq = (const float*)d_in[19];
  const float* Wk = (const float*)d_in[20];
  const float* Wv = (const float*)d_in[21];
  const float* Wo = (const float*)d_in[22];
  const float* lng = (const float*)d_in[23];
  const float* lnb = (const float*)d_in[24];
  const float* fcW = (const float*)d_in[25];
  const float* fcb = (const float*)d_in[26];

  char* w = (char*)d_ws;
  float* xroad = (float*)(w + OFF_XROAD);
  u16* rgout = (u16*)(w + OFF_RGOUT);
  float* kvr = (float*)(w + OFF_KVR);
  float* ksr = (float*)(w + OFF_KSR);
  float* kvo = (float*)(w + OFF_KVO);
  float* kso = (float*)(w + OFF_KSO);
  u16* wt = (u16*)(w + OFF_WT);
  float* xobj = (float*)(w + OFF_XOBJ);
  u16* xobjb = (u16*)(w + OFF_XOBJB);
  u16* qpB = (u16*)(w + OFF_QP);
  u16* fout = (u16*)(w + OFF_FOUT);
  float* t1 = (float*)(w + OFF_T1);
  float* nF = (float*)(w + OFF_N);
  u16* nB = (u16*)(w + OFF_NB);
  u16* objb = (u16*)(w + OFF_OBJB);

  const size_t E = 1048576;  // elems of a 1024x1024 matrix
  u16* wqT[2] = {wt + 0 * E, wt + 1 * E};
  u16* wkT[2] = {wt + 2 * E, wt + 3 * E};
  u16* wvT[2] = {wt + 4 * E, wt + 5 * E};
  u16* woT[2] = {wt + 6 * E, wt + 7 * E};
  u16* fcT[2] = {wt + 8 * E, wt + 9 * E};
  u16* denT = wt + 10 * E;

  // one-time weight transposes+convert (f32 K x N -> bf16 N x K)
  TP11 tb;
  const float* srcs[10] = {Wq, Wq + E, Wk, Wk + E, Wv, Wv + E, Wo, Wo + E, fcW, fcW + E};
  u16* dsts[10] = {wqT[0], wqT[1], wkT[0], wkT[1], wvT[0], wvT[1], woT[0], woT[1], fcT[0], fcT[1]};
  for (int j = 0; j < 11; ++j) { tb.p[j].s = srcs[j < 10 ? j : 0]; tb.p[j].d = dsts[j < 10 ? j : 0]; }
  transpose_kernel<<<dim3(16, 16, 10), 256, 0, stream>>>(tb, 1024, 1024);
  TP11 td;
  for (int j = 0; j < 11; ++j) { td.p[j].s = denW; td.p[j].d = denT; }
  transpose_kernel<<<dim3(16, 8, 1), 256, 0, stream>>>(td, 512, 1024);
  // obj f32 -> bf16 (1024x512 = 524288 elems)
  cvt_kernel<<<dim3(512), 256, 0, stream>>>(obj, objb);

  // road-graph encoder
  r0_kernel<<<dim3(256), 256, 0, stream>>>(road, rgdW, rgdb, xroad);
  for (int i = 0; i < 2; ++i) {
    hipMemsetAsync(w + OFF_KVR, 0, 2560, stream);
    ra_kernel<<<dim3(256), 256, 0, stream>>>(xroad, qkvW, qkvb, rgWk + i * 256, rgWv + i * 256,
                                             kvr, ksr);
    rb_kernel<<<dim3(256), 256, 0, stream>>>(xroad, qkvW, qkvb, rgWq + i * 256, rgWo + i * 256,
                                             rglng + i * 16, rglnb + i * 16, rgfcW + i * 256,
                                             rgfcb + i * 16, kvr, ksr);
  }
  rc_kernel<<<dim3(4, 4096), 256, 0, stream>>>(xroad, rgoW, rgob, rgout);

  // object encoder init: x = relu(obj @ dense_W + b) + pos_emb
  gemm64_kernel<<<dim3(8, 16), 256, 0, stream>>>(objb, denT, 512, xobj, xobjb, denb, pose, 128,
                                                 1.f, 1, 0.f);

  for (int i = 0; i < 2; ++i) {
    hipMemsetAsync(w + OFF_KVO, 0, 2 * MBy + 32768, stream);
    kv_kernel<<<dim3(8, 64, 8), 256, 0, stream>>>(rgout, wkT[i], wvT[i], kvo, kso);
    gemm64_kernel<<<dim3(8, 16), 256, 0, stream>>>(xobjb, wqT[i], 1024, nullptr, qpB, nullptr,
                                                   nullptr, 1024, NORM_OBJ, 1, STAB);
    q2_kernel<<<dim3(256, 4), 256, 0, stream>>>(qpB, kvo, kso, fout);
    gemm64_kernel<<<dim3(8, 16), 256, 0, stream>>>(fout, woT[i], 1024, t1, nullptr, nullptr, xobj,
                                                   1024, 1.f, 0, 0.f);
    ln_kernel<<<dim3(1024), 256, 0, stream>>>(t1, lng + i * 1024, lnb + i * 1024, nF, nB);
    gemm64_kernel<<<dim3(8, 16), 256, 0, stream>>>(nB, fcT[i], 1024, t1, nullptr, fcb + i * 1024,
                                                   nF, 1024, 1.f, 1, 0.f);
    if (i == 0)
      ln_kernel<<<dim3(1024), 256, 0, stream>>>(t1, lng, lnb, xobj, xobjb);
    else
      ln_kernel<<<dim3(1024), 256, 0, stream>>>(t1, lng + 1024, lnb + 1024, (float*)d_out, nullptr);
  }
}

// Round 6
// 2254.792 us; speedup vs baseline: 1.0512x; 1.0512x over previous
//
#include <hip/hip_runtime.h>

typedef unsigned short u16;
typedef unsigned int u32;

using s8v = __attribute__((ext_vector_type(8))) short;  // 8 bf16
using f4v = __attribute__((ext_vector_type(4))) float;  // 4 fp32

#define LN_EPS 0.001f
#define STAB 0.001f
#define NORM_OBJ 0.35355339059327373f   // 64^-0.25
#define NORM_ROAD 0.7071067811865476f   // 4^-0.25

__device__ __forceinline__ float bf2f(u16 v) { return __uint_as_float(((u32)v) << 16); }
__device__ __forceinline__ u16 f2bf(float f) {
  u32 u = __float_as_uint(f);
  u32 r = (u + 0x7fffu + ((u >> 16) & 1u)) >> 16;
  return (u16)r;
}
__device__ __forceinline__ f4v mfma16(s8v a, s8v b, f4v c) {
  return __builtin_amdgcn_mfma_f32_16x16x32_bf16(a, b, c, 0, 0, 0);
}
// async global->LDS, 16 B/lane; LDS dest = wave-uniform base + lane*16
__device__ __forceinline__ void ldsload16(void* lds, const void* g) {
  __builtin_amdgcn_global_load_lds((const __attribute__((address_space(1))) u32*)g,
                                   (__attribute__((address_space(3))) u32*)lds, 16, 0, 0);
}

// ---------------- transpose+convert: src[K][N] f32 -> dst[N][K] bf16 ----------------
struct TPair { const float* s; u16* d; };
struct TP11 { TPair p[11]; };

__global__ __launch_bounds__(256) void transpose_kernel(TP11 ps, int K, int N) {
  const float* __restrict__ src = ps.p[blockIdx.z].s;
  u16* __restrict__ dst = ps.p[blockIdx.z].d;
  int n0 = blockIdx.x * 64, k0 = blockIdx.y * 64;
  int t = threadIdx.x;
  __shared__ __align__(16) u16 lt[64 * 72];
#pragma unroll
  for (int j = 0; j < 4; ++j) {
    int p = t + 256 * j;
    int r = p >> 4, cb = p & 15;
    float4 v = *(const float4*)(src + (size_t)(k0 + r) * N + n0 + cb * 4);
    lt[r * 72 + cb * 4 + 0] = f2bf(v.x);
    lt[r * 72 + cb * 4 + 1] = f2bf(v.y);
    lt[r * 72 + cb * 4 + 2] = f2bf(v.z);
    lt[r * 72 + cb * 4 + 3] = f2bf(v.w);
  }
  __syncthreads();
#pragma unroll
  for (int j = 0; j < 2; ++j) {
    int q = t + 256 * j;
    int on = q >> 3, ocb = q & 7;
    u16 e[8];
#pragma unroll
    for (int i = 0; i < 8; ++i) e[i] = lt[(ocb * 8 + i) * 72 + on];
    uint4 v;
    v.x = (u32)e[0] | ((u32)e[1] << 16);
    v.y = (u32)e[2] | ((u32)e[3] << 16);
    v.z = (u32)e[4] | ((u32)e[5] << 16);
    v.w = (u32)e[6] | ((u32)e[7] << 16);
    *(uint4*)(dst + (size_t)(n0 + on) * K + k0 + ocb * 8) = v;
  }
}

// ---------------- f32 -> bf16 convert ----------------
__global__ __launch_bounds__(256) void cvt_kernel(const float* __restrict__ src,
                                                  u16* __restrict__ dst) {
  int i = (blockIdx.x * 256 + threadIdx.x) * 4;
  float4 v = *(const float4*)(src + i);
  uint2 o;
  o.x = (u32)f2bf(v.x) | ((u32)f2bf(v.y) << 16);
  o.y = (u32)f2bf(v.z) | ((u32)f2bf(v.w) << 16);
  *(uint2*)(dst + i) = o;
}

// ---------------- road: x = relu(road @ Wd + bd), 65536 x (8->16) ----------------
__global__ __launch_bounds__(256) void r0_kernel(const float* __restrict__ road,
    const float* __restrict__ W, const float* __restrict__ bias, float* __restrict__ x) {
  int row = blockIdx.x * 256 + threadIdx.x;
  float in[8];
  float4 v0 = *(const float4*)(road + (size_t)row * 8);
  float4 v1 = *(const float4*)(road + (size_t)row * 8 + 4);
  in[0] = v0.x; in[1] = v0.y; in[2] = v0.z; in[3] = v0.w;
  in[4] = v1.x; in[5] = v1.y; in[6] = v1.z; in[7] = v1.w;
#pragma unroll
  for (int j = 0; j < 16; ++j) {
    float s = bias[j];
#pragma unroll
    for (int c = 0; c < 8; ++c) s += in[c] * W[c * 16 + j];
    x[(size_t)row * 16 + j] = fmaxf(s, 0.f);
  }
}

// ---------------- road favor pass1: accumulate kv_road/ksum_road ----------------
__global__ __launch_bounds__(256) void ra_kernel(const float* __restrict__ x,
    const float* __restrict__ qkvW, const float* __restrict__ qkvb,
    const float* __restrict__ Wk, const float* __restrict__ Wv,
    float* __restrict__ kvr, float* __restrict__ ksr) {
  int t = threadIdx.x;
  int row = blockIdx.x * 256 + t;
  int b = row >> 13;
  float xv[16];
#pragma unroll
  for (int e = 0; e < 16; ++e) xv[e] = x[(size_t)row * 16 + e];
  float q16[16];
#pragma unroll
  for (int j = 0; j < 16; ++j) {
    float s = qkvb[j];
#pragma unroll
    for (int c = 0; c < 16; ++c) s += xv[c] * qkvW[c * 48 + j];
    q16[j] = fmaxf(s, 0.f);
  }
  float kp[16], vh[16];
#pragma unroll
  for (int hm = 0; hm < 16; ++hm) {
    float sk = 0.f, sv = 0.f;
#pragma unroll
    for (int c = 0; c < 16; ++c) {
      float q = q16[c];
      sk += q * Wk[c * 16 + hm];
      sv += q * Wv[c * 16 + hm];
    }
    kp[hm] = fmaxf(sk * NORM_ROAD, 0.f) + STAB;
    vh[hm] = sv;
  }
  __shared__ float l[80];
  if (t < 80) l[t] = 0.f;
  __syncthreads();
#pragma unroll
  for (int h = 0; h < 4; ++h)
#pragma unroll
    for (int m = 0; m < 4; ++m) {
      float kpv = kp[h * 4 + m];
      atomicAdd(&l[64 + h * 4 + m], kpv);
#pragma unroll
      for (int d = 0; d < 4; ++d) atomicAdd(&l[h * 16 + m * 4 + d], kpv * vh[h * 4 + d]);
    }
  __syncthreads();
  if (t < 64) atomicAdd(&kvr[b * 64 + t], l[t]);
  else if (t < 80) atomicAdd(&ksr[b * 16 + (t - 64)], l[t]);
}

__device__ __forceinline__ void ln16(const float* tv, const float* g, const float* bb, float* o) {
  float m = 0.f;
#pragma unroll
  for (int e = 0; e < 16; ++e) m += tv[e];
  m *= (1.f / 16.f);
  float var = 0.f;
#pragma unroll
  for (int e = 0; e < 16; ++e) { float d = tv[e] - m; var += d * d; }
  var *= (1.f / 16.f);
  float rstd = rsqrtf(var + LN_EPS);
#pragma unroll
  for (int e = 0; e < 16; ++e) o[e] = (tv[e] - m) * rstd * g[e] + bb[e];
}

// ---------------- road favor pass2 + LN + fc + LN (in-place x update) ----------------
__global__ __launch_bounds__(256) void rb_kernel(float* __restrict__ x,
    const float* __restrict__ qkvW, const float* __restrict__ qkvb,
    const float* __restrict__ Wq, const float* __restrict__ Wo,
    const float* __restrict__ lng, const float* __restrict__ lnb,
    const float* __restrict__ fcW, const float* __restrict__ fcb,
    const float* __restrict__ kvr, const float* __restrict__ ksr) {
  int row = blockIdx.x * 256 + threadIdx.x;
  int b = row >> 13;
  float xv[16];
#pragma unroll
  for (int e = 0; e < 16; ++e) xv[e] = x[(size_t)row * 16 + e];
  float q16[16];
#pragma unroll
  for (int j = 0; j < 16; ++j) {
    float s = qkvb[j];
#pragma unroll
    for (int c = 0; c < 16; ++c) s += xv[c] * qkvW[c * 48 + j];
    q16[j] = fmaxf(s, 0.f);
  }
  float qp[16];
#pragma unroll
  for (int hm = 0; hm < 16; ++hm) {
    float s = 0.f;
#pragma unroll
    for (int c = 0; c < 16; ++c) s += q16[c] * Wq[c * 16 + hm];
    qp[hm] = fmaxf(s * NORM_ROAD, 0.f) + STAB;
  }
  float attn[16];
#pragma unroll
  for (int e = 0; e < 16; ++e) attn[e] = 0.f;
#pragma unroll
  for (int h = 0; h < 4; ++h) {
    float den = 0.f;
#pragma unroll
    for (int m = 0; m < 4; ++m) den += qp[h * 4 + m] * ksr[b * 16 + h * 4 + m];
    float od[4];
#pragma unroll
    for (int d = 0; d < 4; ++d) {
      float num = 0.f;
#pragma unroll
      for (int m = 0; m < 4; ++m) num += qp[h * 4 + m] * kvr[b * 64 + h * 16 + m * 4 + d];
      od[d] = num / den;
    }
#pragma unroll
    for (int d = 0; d < 4; ++d)
#pragma unroll
      for (int e = 0; e < 16; ++e) attn[e] += od[d] * Wo[(h * 4 + d) * 16 + e];
  }
  float tv[16], n[16], o2[16];
#pragma unroll
  for (int e = 0; e < 16; ++e) tv[e] = attn[e] + xv[e];
  ln16(tv, lng, lnb, n);
#pragma unroll
  for (int j = 0; j < 16; ++j) {
    float s = fcb[j];
#pragma unroll
    for (int e = 0; e < 16; ++e) s += n[e] * fcW[e * 16 + j];
    tv[j] = n[j] + fmaxf(s, 0.f);
  }
  ln16(tv, lng, lnb, o2);
#pragma unroll
  for (int e = 0; e < 16; ++e) x[(size_t)row * 16 + e] = o2[e];
}

// ---------------- rg_out = relu(x_road @ rg_out_W + b) -> bf16, 65536x1024 ----------------
__global__ __launch_bounds__(256) void rc_kernel(const float* __restrict__ x,
    const float* __restrict__ W, const float* __restrict__ bias, u16* __restrict__ out) {
  const int t = threadIdx.x;
  const int cg = t & 63, rg = t >> 6;
  const int c0 = blockIdx.x * 256 + cg * 4;
  const int r0 = blockIdx.y * 16;
  __shared__ float lx[256];
  lx[t] = x[(size_t)(r0 + (t >> 4)) * 16 + (t & 15)];
  __syncthreads();
  float4 wv[16];
#pragma unroll
  for (int c = 0; c < 16; ++c) wv[c] = *(const float4*)(W + (size_t)c * 1024 + c0);
  float4 bv = *(const float4*)(bias + c0);
#pragma unroll
  for (int k = 0; k < 4; ++k) {
    int rr = rg * 4 + k;
    float s0 = bv.x, s1 = bv.y, s2 = bv.z, s3 = bv.w;
#pragma unroll
    for (int c = 0; c < 16; ++c) {
      float xv = lx[rr * 16 + c];
      s0 += xv * wv[c].x; s1 += xv * wv[c].y; s2 += xv * wv[c].z; s3 += xv * wv[c].w;
    }
    uint2 o;
    o.x = (u32)f2bf(fmaxf(s0, 0.f)) | ((u32)f2bf(fmaxf(s1, 0.f)) << 16);
    o.y = (u32)f2bf(fmaxf(s2, 0.f)) | ((u32)f2bf(fmaxf(s3, 0.f)) << 16);
    *(uint2*)(out + (size_t)(r0 + rr) * 1024 + c0) = o;
  }
}

// ---------------- generic MFMA GEMM: C = act(A[MxK] @ BT[NxK]^T), 128x128 tile ----------------
// LDS staged via global_load_lds with XOR swizzle
__global__ __launch_bounds__(256) void gemm_kernel(
    const u16* __restrict__ A, const u16* __restrict__ BT, int K,
    float* __restrict__ outF, u16* __restrict__ outB,
    const float* __restrict__ bias, const float* __restrict__ resF, int resmod,
    float scale, int do_relu, float post) {
  const int n0 = blockIdx.x * 128, m0 = blockIdx.y * 128;
  const int t = threadIdx.x;
  const int wid = t >> 6, lane = t & 63, quad = lane >> 4, m16 = lane & 15;
  const int wm = wid >> 1, wn = wid & 1;
  const int lrr = lane >> 3;
  const int lcs = (((lane & 7) ^ lrr) * 8);
  const int sw = m16 & 7;
  __shared__ __align__(16) u16 smem[2 * 128 * 64];
  u16* Al = smem;
  u16* Bl = smem + 128 * 64;
  f4v acc[4][4];
#pragma unroll
  for (int i = 0; i < 4; ++i)
#pragma unroll
    for (int j = 0; j < 4; ++j) acc[i][j] = {0.f, 0.f, 0.f, 0.f};

  for (int kc = 0; kc < K; kc += 64) {
    __syncthreads();
#pragma unroll
    for (int j = 0; j < 4; ++j) {
      int rbase = wid * 32 + j * 8;
      ldsload16(Al + rbase * 64, A + (size_t)(m0 + rbase + lrr) * K + kc + lcs);
      ldsload16(Bl + rbase * 64, BT + (size_t)(n0 + rbase + lrr) * K + kc + lcs);
    }
    __syncthreads();
#pragma unroll
    for (int ko = 0; ko < 64; ko += 32) {
      int g0 = ko >> 3;
      s8v af[4], bfr[4];
#pragma unroll
      for (int tm = 0; tm < 4; ++tm)
        af[tm] = *(const s8v*)(Al + (wm * 64 + tm * 16 + m16) * 64 + ((g0 + quad) ^ sw) * 8);
#pragma unroll
      for (int tn = 0; tn < 4; ++tn)
        bfr[tn] = *(const s8v*)(Bl + (wn * 64 + tn * 16 + m16) * 64 + ((g0 + quad) ^ sw) * 8);
#pragma unroll
      for (int tm = 0; tm < 4; ++tm)
#pragma unroll
        for (int tn = 0; tn < 4; ++tn)
          acc[tm][tn] = mfma16(af[tm], bfr[tn], acc[tm][tn]);
    }
  }
#pragma unroll
  for (int tm = 0; tm < 4; ++tm)
#pragma unroll
    for (int tn = 0; tn < 4; ++tn)
#pragma unroll
      for (int r = 0; r < 4; ++r) {
        int row = m0 + wm * 64 + tm * 16 + quad * 4 + r;
        int col = n0 + wn * 64 + tn * 16 + m16;
        float v = acc[tm][tn][r] * scale;
        if (bias) v += bias[col];
        if (do_relu) v = fmaxf(v, 0.f);
        v += post;
        if (resF) v += resF[(size_t)(row % resmod) * 1024 + col];
        if (outF) outF[(size_t)row * 1024 + col] = v;
        if (outB) outB[(size_t)row * 1024 + col] = f2bf(v);
      }
}

// ---------------- fused K/V projection + kv/ksum accumulation ----------------
// grid (128, 1, 8): blockIdx.x = h*8 + mt2 so linear id % 8 = mt2 -> all 16 heads for a
// given s-range land on the same XCD (A-tile L2 reuse). Each block processes 8 consecutive
// 128-row s-tiles (T=8), amortizing epilogue and atomics 8x.
__global__ __launch_bounds__(256) void kv_kernel(
    const u16* __restrict__ rgout, const u16* __restrict__ WkT, const u16* __restrict__ WvT,
    float* __restrict__ kv, float* __restrict__ ksum) {
  const int h = blockIdx.x >> 3, mt2 = blockIdx.x & 7, b = blockIdx.z;
  const int t = threadIdx.x;
  const int wid = t >> 6, lane = t & 63, quad = lane >> 4, m16 = lane & 15;
  const int wm = wid >> 1, wn = wid & 1;
  const int lrr = lane >> 3;
  const int lcs = (((lane & 7) ^ lrr) * 8);
  const int sw = m16 & 7;
  __shared__ __align__(16) u16 smem[2 * 128 * 72];
  u16* Al = smem;              // [128][64] swizzled
  u16* Bl = smem + 128 * 64;   // [128][64] swizzled
  u16* KPT = smem;             // [64 m][136 s] (epilogue reuse)
  u16* VT = smem + 64 * 136;   // [64 d][136 s]

  f4v a2[4];                   // persistent kv accumulator: 16 m-rows (wid) x 64 d
#pragma unroll
  for (int tn = 0; tn < 4; ++tn) a2[tn] = {0.f, 0.f, 0.f, 0.f};
  float ksacc = 0.f;           // persistent ksum accumulator (t<64)

  for (int tt = 0; tt < 8; ++tt) {
    const size_t abase = ((size_t)b * 8192 + (size_t)(mt2 * 8 + tt) * 128) * 1024;
    f4v acc[4][4];
#pragma unroll
    for (int i = 0; i < 4; ++i)
#pragma unroll
      for (int j = 0; j < 4; ++j) acc[i][j] = {0.f, 0.f, 0.f, 0.f};

    for (int kc = 0; kc < 1024; kc += 64) {
      __syncthreads();
#pragma unroll
      for (int j = 0; j < 4; ++j) {
        int rbase = wid * 32 + j * 8;
        int r = rbase + lrr;
        ldsload16(Al + rbase * 64, rgout + abase + (size_t)r * 1024 + kc + lcs);
        const u16* bsrc = (r < 64) ? (WkT + (size_t)(h * 64 + r) * 1024)
                                   : (WvT + (size_t)(h * 64 + (r - 64)) * 1024);
        ldsload16(Bl + rbase * 64, bsrc + kc + lcs);
      }
      __syncthreads();
#pragma unroll
      for (int ko = 0; ko < 64; ko += 32) {
        int g0 = ko >> 3;
        s8v af[4], bfr[4];
#pragma unroll
        for (int tm = 0; tm < 4; ++tm)
          af[tm] = *(const s8v*)(Al + (wm * 64 + tm * 16 + m16) * 64 + ((g0 + quad) ^ sw) * 8);
#pragma unroll
        for (int tn = 0; tn < 4; ++tn)
          bfr[tn] = *(const s8v*)(Bl + (wn * 64 + tn * 16 + m16) * 64 + ((g0 + quad) ^ sw) * 8);
#pragma unroll
        for (int tm = 0; tm < 4; ++tm)
#pragma unroll
          for (int tn = 0; tn < 4; ++tn)
            acc[tm][tn] = mfma16(af[tm], bfr[tn], acc[tm][tn]);
      }
    }
    __syncthreads();
    // epilogue: kp = relu(k*norm)+stab (wn==0), v unchanged (wn==1); transpose to LDS
    {
      u16* dst = wn ? VT : KPT;
#pragma unroll
      for (int tm = 0; tm < 4; ++tm)
#pragma unroll
        for (int tn = 0; tn < 4; ++tn)
#pragma unroll
          for (int r = 0; r < 4; ++r) {
            int srow = wm * 64 + tm * 16 + quad * 4 + r;
            int feat = tn * 16 + m16;
            float v = acc[tm][tn][r];
            if (wn == 0) v = fmaxf(v * NORM_OBJ, 0.f) + STAB;
            dst[feat * 136 + srow] = f2bf(v);
          }
    }
    __syncthreads();
    // ksum partial accumulate (registers)
    if (t < 64) {
#pragma unroll
      for (int i = 0; i < 128; i += 8) {
        uint4 v = *(const uint4*)(KPT + t * 136 + i);
        u32 a[4] = {v.x, v.y, v.z, v.w};
#pragma unroll
        for (int q = 0; q < 4; ++q) {
          ksacc += __uint_as_float(a[q] << 16);
          ksacc += __uint_as_float(a[q] & 0xffff0000u);
        }
      }
    }
    // second GEMM accumulate: kv_partial[64 m][64 d] += sum_s kp[s][m]*v[s][d], K=128
#pragma unroll
    for (int ks = 0; ks < 128; ks += 32) {
      s8v af = *(const s8v*)(KPT + (wid * 16 + m16) * 136 + ks + quad * 8);
#pragma unroll
      for (int tn = 0; tn < 4; ++tn) {
        s8v bv = *(const s8v*)(VT + (tn * 16 + m16) * 136 + ks + quad * 8);
        a2[tn] = mfma16(af, bv, a2[tn]);
      }
    }
  }
  if (t < 64) atomicAdd(&ksum[(size_t)(b * 16 + h) * 64 + t], ksacc);
#pragma unroll
  for (int tn = 0; tn < 4; ++tn)
#pragma unroll
    for (int r = 0; r < 4; ++r) {
      int m = wid * 16 + quad * 4 + r;
      int d = tn * 16 + m16;
      atomicAdd(&kv[((size_t)(b * 16 + h) * 64 + m) * 64 + d], a2[tn][r]);
    }
}

// ---------------- obj favor: out = (qp @ kv) / (qp . ksum) per row/head ----------------
// grid (256 row-blocks, 4 head-groups)
__global__ __launch_bounds__(256) void q2_kernel(const u16* __restrict__ qp,
    const float* __restrict__ kv, const float* __restrict__ ks, u16* __restrict__ out) {
  int wid = threadIdx.x >> 6, lane = threadIdx.x & 63;
  int row = blockIdx.x * 4 + wid;
  int b = row >> 7;
  int h0 = blockIdx.y * 4;
  for (int h = h0; h < h0 + 4; ++h) {
    const float* kvp = kv + (size_t)((b * 16 + h) * 64) * 64;
    const float* ksp = ks + (size_t)(b * 16 + h) * 64;
    const u16* qpp = qp + (size_t)row * 1024 + h * 64;
    float num = 0.f, den = 0.f;
    for (int m = 0; m < 64; ++m) {
      float qv = bf2f(qpp[m]);
      num += qv * kvp[m * 64 + lane];
      den += qv * ksp[m];
    }
    out[(size_t)row * 1024 + h * 64 + lane] = f2bf(num / den);
  }
}

// ---------------- layernorm over 1024, one block per row ----------------
__global__ __launch_bounds__(256) void ln_kernel(const float* __restrict__ in,
    const float* __restrict__ g, const float* __restrict__ bb,
    float* __restrict__ outF, u16* __restrict__ outB) {
  int row = blockIdx.x, t = threadIdx.x;
  const float* x = in + (size_t)row * 1024;
  float v[4];
  float s = 0.f, ss = 0.f;
#pragma unroll
  for (int j = 0; j < 4; ++j) {
    v[j] = x[t + 256 * j];
    s += v[j];
    ss += v[j] * v[j];
  }
  __shared__ float rs[256], rss[256];
  rs[t] = s; rss[t] = ss;
  __syncthreads();
  for (int o = 128; o > 0; o >>= 1) {
    if (t < o) { rs[t] += rs[t + o]; rss[t] += rss[t + o]; }
    __syncthreads();
  }
  float mean = rs[0] * (1.f / 1024.f);
  float var = rss[0] * (1.f / 1024.f) - mean * mean;
  float rstd = rsqrtf(var + LN_EPS);
#pragma unroll
  for (int j = 0; j < 4; ++j) {
    int c = t + 256 * j;
    float o = (v[j] - mean) * rstd * g[c] + bb[c];
    if (outF) outF[(size_t)row * 1024 + c] = o;
    if (outB) outB[(size_t)row * 1024 + c] = f2bf(o);
  }
}

// ---------------- workspace layout (bytes) ----------------
static constexpr size_t MBy = 1048576;
static constexpr size_t OFF_XROAD = 0;                       // 4 MB f32 (65536x16)
static constexpr size_t OFF_RGOUT = 4 * MBy;                 // 128 MiB bf16 (65536x1024)
static constexpr size_t OFF_KVR = OFF_RGOUT + 128 * MBy;     // 2048 B
static constexpr size_t OFF_KSR = OFF_KVR + 2048;            // 512 B
static constexpr size_t OFF_KVO = OFF_KVR + 4096;            // 2 MB f32
static constexpr size_t OFF_KSO = OFF_KVO + 2 * MBy;         // 32 KB f32
static constexpr size_t OFF_WT = OFF_KSO + 65536;            // 21 MB bf16 transposed weights
static constexpr size_t OFF_XOBJ = OFF_WT + 21 * MBy;        // 4 MB f32
static constexpr size_t OFF_XOBJB = OFF_XOBJ + 4 * MBy;      // 2 MB bf16
static constexpr size_t OFF_QP = OFF_XOBJB + 2 * MBy;        // 2 MB bf16
static constexpr size_t OFF_FOUT = OFF_QP + 2 * MBy;         // 2 MB bf16
static constexpr size_t OFF_T1 = OFF_FOUT + 2 * MBy;         // 4 MB f32
static constexpr size_t OFF_N = OFF_T1 + 4 * MBy;            // 4 MB f32
static constexpr size_t OFF_NB = OFF_N + 4 * MBy;            // 2 MB bf16
static constexpr size_t OFF_OBJB = OFF_NB + 2 * MBy;         // 1 MB bf16 (1024x512)

extern "C" void kernel_launch(void* const* d_in, const int* in_sizes, int n_in,
                              void* d_out, int out_size, void* d_ws, size_t ws_size,
                              hipStream_t stream) {
  (void)in_sizes; (void)n_in; (void)out_size; (void)ws_size;
  const float* obj = (const float*)d_in[0];
  const float* road = (const float*)d_in[1];
  const float* rgdW = (const float*)d_in[2];
  const float* rgdb = (const float*)d_in[3];
  const float* qkvW = (const float*)d_in[4];
  const float* qkvb = (const float*)d_in[5];
  const float* rgWq = (const float*)d_in[6];
  const float* rgWk = (const float*)d_in[7];
  const float* rgWv = (const float*)d_in[8];
  const float* rgWo = (const float*)d_in[9];
  const float* rglng = (const float*)d_in[10];
  const float* rglnb = (const float*)d_in[11];
  const float* rgfcW = (const float*)d_in[12];
  const float* rgfcb = (const float*)d_in[13];
  const float* rgoW = (const float*)d_in[14];
  const float* rgob = (const float*)d_in[15];
  const float* denW = (const float*)d_in[16];
  const float* denb = (const float*)d_in[17];
  const float* pose = (const float*)d_in[18];
  const float* Wq = (const float*)d_in[19];
  const float* Wk = (const float*)d_in[20];
  const float* Wv = (const float*)d_in[21];
  const float* Wo = (const float*)d_in[22];
  const float* lng = (const float*)d_in[23];
  const float* lnb = (const float*)d_in[24];
  const float* fcW = (const float*)d_in[25];
  const float* fcb = (const float*)d_in[26];

  char* w = (char*)d_ws;
  float* xroad = (float*)(w + OFF_XROAD);
  u16* rgout = (u16*)(w + OFF_RGOUT);
  float* kvr = (float*)(w + OFF_KVR);
  float* ksr = (float*)(w + OFF_KSR);
  float* kvo = (float*)(w + OFF_KVO);
  float* kso = (float*)(w + OFF_KSO);
  u16* wt = (u16*)(w + OFF_WT);
  float* xobj = (float*)(w + OFF_XOBJ);
  u16* xobjb = (u16*)(w + OFF_XOBJB);
  u16* qpB = (u16*)(w + OFF_QP);
  u16* fout = (u16*)(w + OFF_FOUT);
  float* t1 = (float*)(w + OFF_T1);
  float* nF = (float*)(w + OFF_N);
  u16* nB = (u16*)(w + OFF_NB);
  u16* objb = (u16*)(w + OFF_OBJB);

  const size_t E = 1048576;  // elems of a 1024x1024 matrix
  u16* wqT[2] = {wt + 0 * E, wt + 1 * E};
  u16* wkT[2] = {wt + 2 * E, wt + 3 * E};
  u16* wvT[2] = {wt + 4 * E, wt + 5 * E};
  u16* woT[2] = {wt + 6 * E, wt + 7 * E};
  u16* fcT[2] = {wt + 8 * E, wt + 9 * E};
  u16* denT = wt + 10 * E;

  // one-time weight transposes+convert (f32 K x N -> bf16 N x K)
  TP11 tb;
  const float* srcs[10] = {Wq, Wq + E, Wk, Wk + E, Wv, Wv + E, Wo, Wo + E, fcW, fcW + E};
  u16* dsts[10] = {wqT[0], wqT[1], wkT[0], wkT[1], wvT[0], wvT[1], woT[0], woT[1], fcT[0], fcT[1]};
  for (int j = 0; j < 11; ++j) { tb.p[j].s = srcs[j < 10 ? j : 0]; tb.p[j].d = dsts[j < 10 ? j : 0]; }
  transpose_kernel<<<dim3(16, 16, 10), 256, 0, stream>>>(tb, 1024, 1024);
  TP11 td;
  for (int j = 0; j < 11; ++j) { td.p[j].s = denW; td.p[j].d = denT; }
  transpose_kernel<<<dim3(16, 8, 1), 256, 0, stream>>>(td, 512, 1024);
  // obj f32 -> bf16 (1024x512 = 524288 elems)
  cvt_kernel<<<dim3(512), 256, 0, stream>>>(obj, objb);

  // road-graph encoder
  r0_kernel<<<dim3(256), 256, 0, stream>>>(road, rgdW, rgdb, xroad);
  for (int i = 0; i < 2; ++i) {
    hipMemsetAsync(w + OFF_KVR, 0, 2560, stream);
    ra_kernel<<<dim3(256), 256, 0, stream>>>(xroad, qkvW, qkvb, rgWk + i * 256, rgWv + i * 256,
                                             kvr, ksr);
    rb_kernel<<<dim3(256), 256, 0, stream>>>(xroad, qkvW, qkvb, rgWq + i * 256, rgWo + i * 256,
                                             rglng + i * 16, rglnb + i * 16, rgfcW + i * 256,
                                             rgfcb + i * 16, kvr, ksr);
  }
  rc_kernel<<<dim3(4, 4096), 256, 0, stream>>>(xroad, rgoW, rgob, rgout);

  // object encoder init: x = relu(obj @ dense_W + b) + pos_emb
  gemm_kernel<<<dim3(8, 8), 256, 0, stream>>>(objb, denT, 512, xobj, xobjb, denb, pose, 128,
                                              1.f, 1, 0.f);

  for (int i = 0; i < 2; ++i) {
    hipMemsetAsync(w + OFF_KVO, 0, 2 * MBy + 32768, stream);
    kv_kernel<<<dim3(128, 1, 8), 256, 0, stream>>>(rgout, wkT[i], wvT[i], kvo, kso);
    gemm_kernel<<<dim3(8, 8), 256, 0, stream>>>(xobjb, wqT[i], 1024, nullptr, qpB, nullptr,
                                                nullptr, 1024, NORM_OBJ, 1, STAB);
    q2_kernel<<<dim3(256, 4), 256, 0, stream>>>(qpB, kvo, kso, fout);
    gemm_kernel<<<dim3(8, 8), 256, 0, stream>>>(fout, woT[i], 1024, t1, nullptr, nullptr, xobj,
                                                1024, 1.f, 0, 0.f);
    ln_kernel<<<dim3(1024), 256, 0, stream>>>(t1, lng + i * 1024, lnb + i * 1024, nF, nB);
    gemm_kernel<<<dim3(8, 8), 256, 0, stream>>>(nB, fcT[i], 1024, t1, nullptr, fcb + i * 1024, nF,
                                                1024, 1.f, 1, 0.f);
    if (i == 0)
      ln_kernel<<<dim3(1024), 256, 0, stream>>>(t1, lng, lnb, xobj, xobjb);
    else
      ln_kernel<<<dim3(1024), 256, 0, stream>>>(t1, lng + 1024, lnb + 1024, (float*)d_out, nullptr);
  }
}

// Round 7
// 2184.241 us; speedup vs baseline: 1.0851x; 1.0323x over previous
//
#include <hip/hip_runtime.h>

typedef unsigned short u16;
typedef unsigned int u32;

using s8v = __attribute__((ext_vector_type(8))) short;  // 8 bf16
using f4v = __attribute__((ext_vector_type(4))) float;  // 4 fp32

#define LN_EPS 0.001f
#define STAB 0.001f
#define NORM_OBJ 0.35355339059327373f   // 64^-0.25
#define NORM_ROAD 0.7071067811865476f   // 4^-0.25

__device__ __forceinline__ float bf2f(u16 v) { return __uint_as_float(((u32)v) << 16); }
__device__ __forceinline__ u16 f2bf(float f) {
  u32 u = __float_as_uint(f);
  u32 r = (u + 0x7fffu + ((u >> 16) & 1u)) >> 16;
  return (u16)r;
}
__device__ __forceinline__ f4v mfma16(s8v a, s8v b, f4v c) {
  return __builtin_amdgcn_mfma_f32_16x16x32_bf16(a, b, c, 0, 0, 0);
}
// async global->LDS, 16 B/lane; LDS dest = wave-uniform base + lane*16
__device__ __forceinline__ void ldsload16(void* lds, const void* g) {
  __builtin_amdgcn_global_load_lds((const __attribute__((address_space(1))) u32*)g,
                                   (__attribute__((address_space(3))) u32*)lds, 16, 0, 0);
}

// ---------------- transpose+convert: src[K][N] f32 -> dst[N][K] bf16 ----------------
struct TPair { const float* s; u16* d; };
struct TP11 { TPair p[11]; };

__global__ __launch_bounds__(256) void transpose_kernel(TP11 ps, int K, int N) {
  const float* __restrict__ src = ps.p[blockIdx.z].s;
  u16* __restrict__ dst = ps.p[blockIdx.z].d;
  int n0 = blockIdx.x * 64, k0 = blockIdx.y * 64;
  int t = threadIdx.x;
  __shared__ __align__(16) u16 lt[64 * 72];
#pragma unroll
  for (int j = 0; j < 4; ++j) {
    int p = t + 256 * j;
    int r = p >> 4, cb = p & 15;
    float4 v = *(const float4*)(src + (size_t)(k0 + r) * N + n0 + cb * 4);
    lt[r * 72 + cb * 4 + 0] = f2bf(v.x);
    lt[r * 72 + cb * 4 + 1] = f2bf(v.y);
    lt[r * 72 + cb * 4 + 2] = f2bf(v.z);
    lt[r * 72 + cb * 4 + 3] = f2bf(v.w);
  }
  __syncthreads();
#pragma unroll
  for (int j = 0; j < 2; ++j) {
    int q = t + 256 * j;
    int on = q >> 3, ocb = q & 7;
    u16 e[8];
#pragma unroll
    for (int i = 0; i < 8; ++i) e[i] = lt[(ocb * 8 + i) * 72 + on];
    uint4 v;
    v.x = (u32)e[0] | ((u32)e[1] << 16);
    v.y = (u32)e[2] | ((u32)e[3] << 16);
    v.z = (u32)e[4] | ((u32)e[5] << 16);
    v.w = (u32)e[6] | ((u32)e[7] << 16);
    *(uint4*)(dst + (size_t)(n0 + on) * K + k0 + ocb * 8) = v;
  }
}

// ---------------- f32 -> bf16 convert ----------------
__global__ __launch_bounds__(256) void cvt_kernel(const float* __restrict__ src,
                                                  u16* __restrict__ dst) {
  int i = (blockIdx.x * 256 + threadIdx.x) * 4;
  float4 v = *(const float4*)(src + i);
  uint2 o;
  o.x = (u32)f2bf(v.x) | ((u32)f2bf(v.y) << 16);
  o.y = (u32)f2bf(v.z) | ((u32)f2bf(v.w) << 16);
  *(uint2*)(dst + i) = o;
}

// ---------------- road: x = relu(road @ Wd + bd), 65536 x (8->16) ----------------
__global__ __launch_bounds__(256) void r0_kernel(const float* __restrict__ road,
    const float* __restrict__ W, const float* __restrict__ bias, float* __restrict__ x) {
  int row = blockIdx.x * 256 + threadIdx.x;
  float in[8];
  float4 v0 = *(const float4*)(road + (size_t)row * 8);
  float4 v1 = *(const float4*)(road + (size_t)row * 8 + 4);
  in[0] = v0.x; in[1] = v0.y; in[2] = v0.z; in[3] = v0.w;
  in[4] = v1.x; in[5] = v1.y; in[6] = v1.z; in[7] = v1.w;
#pragma unroll
  for (int j = 0; j < 16; ++j) {
    float s = bias[j];
#pragma unroll
    for (int c = 0; c < 8; ++c) s += in[c] * W[c * 16 + j];
    x[(size_t)row * 16 + j] = fmaxf(s, 0.f);
  }
}

// ---------------- road favor pass1: accumulate kv_road/ksum_road ----------------
__global__ __launch_bounds__(256) void ra_kernel(const float* __restrict__ x,
    const float* __restrict__ qkvW, const float* __restrict__ qkvb,
    const float* __restrict__ Wk, const float* __restrict__ Wv,
    float* __restrict__ kvr, float* __restrict__ ksr) {
  int t = threadIdx.x;
  int row = blockIdx.x * 256 + t;
  int b = row >> 13;
  float xv[16];
#pragma unroll
  for (int e = 0; e < 16; ++e) xv[e] = x[(size_t)row * 16 + e];
  float q16[16];
#pragma unroll
  for (int j = 0; j < 16; ++j) {
    float s = qkvb[j];
#pragma unroll
    for (int c = 0; c < 16; ++c) s += xv[c] * qkvW[c * 48 + j];
    q16[j] = fmaxf(s, 0.f);
  }
  float kp[16], vh[16];
#pragma unroll
  for (int hm = 0; hm < 16; ++hm) {
    float sk = 0.f, sv = 0.f;
#pragma unroll
    for (int c = 0; c < 16; ++c) {
      float q = q16[c];
      sk += q * Wk[c * 16 + hm];
      sv += q * Wv[c * 16 + hm];
    }
    kp[hm] = fmaxf(sk * NORM_ROAD, 0.f) + STAB;
    vh[hm] = sv;
  }
  __shared__ float l[80];
  if (t < 80) l[t] = 0.f;
  __syncthreads();
#pragma unroll
  for (int h = 0; h < 4; ++h)
#pragma unroll
    for (int m = 0; m < 4; ++m) {
      float kpv = kp[h * 4 + m];
      atomicAdd(&l[64 + h * 4 + m], kpv);
#pragma unroll
      for (int d = 0; d < 4; ++d) atomicAdd(&l[h * 16 + m * 4 + d], kpv * vh[h * 4 + d]);
    }
  __syncthreads();
  if (t < 64) atomicAdd(&kvr[b * 64 + t], l[t]);
  else if (t < 80) atomicAdd(&ksr[b * 16 + (t - 64)], l[t]);
}

__device__ __forceinline__ void ln16(const float* tv, const float* g, const float* bb, float* o) {
  float m = 0.f;
#pragma unroll
  for (int e = 0; e < 16; ++e) m += tv[e];
  m *= (1.f / 16.f);
  float var = 0.f;
#pragma unroll
  for (int e = 0; e < 16; ++e) { float d = tv[e] - m; var += d * d; }
  var *= (1.f / 16.f);
  float rstd = rsqrtf(var + LN_EPS);
#pragma unroll
  for (int e = 0; e < 16; ++e) o[e] = (tv[e] - m) * rstd * g[e] + bb[e];
}

// ---------------- road favor pass2 + LN + fc + LN (in-place x update) ----------------
__global__ __launch_bounds__(256) void rb_kernel(float* __restrict__ x,
    const float* __restrict__ qkvW, const float* __restrict__ qkvb,
    const float* __restrict__ Wq, const float* __restrict__ Wo,
    const float* __restrict__ lng, const float* __restrict__ lnb,
    const float* __restrict__ fcW, const float* __restrict__ fcb,
    const float* __restrict__ kvr, const float* __restrict__ ksr) {
  int row = blockIdx.x * 256 + threadIdx.x;
  int b = row >> 13;
  float xv[16];
#pragma unroll
  for (int e = 0; e < 16; ++e) xv[e] = x[(size_t)row * 16 + e];
  float q16[16];
#pragma unroll
  for (int j = 0; j < 16; ++j) {
    float s = qkvb[j];
#pragma unroll
    for (int c = 0; c < 16; ++c) s += xv[c] * qkvW[c * 48 + j];
    q16[j] = fmaxf(s, 0.f);
  }
  float qp[16];
#pragma unroll
  for (int hm = 0; hm < 16; ++hm) {
    float s = 0.f;
#pragma unroll
    for (int c = 0; c < 16; ++c) s += q16[c] * Wq[c * 16 + hm];
    qp[hm] = fmaxf(s * NORM_ROAD, 0.f) + STAB;
  }
  float attn[16];
#pragma unroll
  for (int e = 0; e < 16; ++e) attn[e] = 0.f;
#pragma unroll
  for (int h = 0; h < 4; ++h) {
    float den = 0.f;
#pragma unroll
    for (int m = 0; m < 4; ++m) den += qp[h * 4 + m] * ksr[b * 16 + h * 4 + m];
    float od[4];
#pragma unroll
    for (int d = 0; d < 4; ++d) {
      float num = 0.f;
#pragma unroll
      for (int m = 0; m < 4; ++m) num += qp[h * 4 + m] * kvr[b * 64 + h * 16 + m * 4 + d];
      od[d] = num / den;
    }
#pragma unroll
    for (int d = 0; d < 4; ++d)
#pragma unroll
      for (int e = 0; e < 16; ++e) attn[e] += od[d] * Wo[(h * 4 + d) * 16 + e];
  }
  float tv[16], n[16], o2[16];
#pragma unroll
  for (int e = 0; e < 16; ++e) tv[e] = attn[e] + xv[e];
  ln16(tv, lng, lnb, n);
#pragma unroll
  for (int j = 0; j < 16; ++j) {
    float s = fcb[j];
#pragma unroll
    for (int e = 0; e < 16; ++e) s += n[e] * fcW[e * 16 + j];
    tv[j] = n[j] + fmaxf(s, 0.f);
  }
  ln16(tv, lng, lnb, o2);
#pragma unroll
  for (int e = 0; e < 16; ++e) x[(size_t)row * 16 + e] = o2[e];
}

// ---------------- rg_out = relu(x_road @ rg_out_W + b) -> bf16, 65536x1024 ----------------
__global__ __launch_bounds__(256) void rc_kernel(const float* __restrict__ x,
    const float* __restrict__ W, const float* __restrict__ bias, u16* __restrict__ out) {
  const int t = threadIdx.x;
  const int cg = t & 63, rg = t >> 6;
  const int c0 = blockIdx.x * 256 + cg * 4;
  const int r0 = blockIdx.y * 16;
  __shared__ float lx[256];
  lx[t] = x[(size_t)(r0 + (t >> 4)) * 16 + (t & 15)];
  __syncthreads();
  float4 wv[16];
#pragma unroll
  for (int c = 0; c < 16; ++c) wv[c] = *(const float4*)(W + (size_t)c * 1024 + c0);
  float4 bv = *(const float4*)(bias + c0);
#pragma unroll
  for (int k = 0; k < 4; ++k) {
    int rr = rg * 4 + k;
    float s0 = bv.x, s1 = bv.y, s2 = bv.z, s3 = bv.w;
#pragma unroll
    for (int c = 0; c < 16; ++c) {
      float xv = lx[rr * 16 + c];
      s0 += xv * wv[c].x; s1 += xv * wv[c].y; s2 += xv * wv[c].z; s3 += xv * wv[c].w;
    }
    uint2 o;
    o.x = (u32)f2bf(fmaxf(s0, 0.f)) | ((u32)f2bf(fmaxf(s1, 0.f)) << 16);
    o.y = (u32)f2bf(fmaxf(s2, 0.f)) | ((u32)f2bf(fmaxf(s3, 0.f)) << 16);
    *(uint2*)(out + (size_t)(r0 + rr) * 1024 + c0) = o;
  }
}

// ---------------- generic MFMA GEMM: C = act(A[MxK] @ BT[NxK]^T), 128x128 tile ----------------
// LDS staged via global_load_lds with XOR swizzle
__global__ __launch_bounds__(256) void gemm_kernel(
    const u16* __restrict__ A, const u16* __restrict__ BT, int K,
    float* __restrict__ outF, u16* __restrict__ outB,
    const float* __restrict__ bias, const float* __restrict__ resF, int resmod,
    float scale, int do_relu, float post) {
  const int n0 = blockIdx.x * 128, m0 = blockIdx.y * 128;
  const int t = threadIdx.x;
  const int wid = t >> 6, lane = t & 63, quad = lane >> 4, m16 = lane & 15;
  const int wm = wid >> 1, wn = wid & 1;
  const int lrr = lane >> 3;
  const int lcs = (((lane & 7) ^ lrr) * 8);
  const int sw = m16 & 7;
  __shared__ __align__(16) u16 smem[2 * 128 * 64];
  u16* Al = smem;
  u16* Bl = smem + 128 * 64;
  f4v acc[4][4];
#pragma unroll
  for (int i = 0; i < 4; ++i)
#pragma unroll
    for (int j = 0; j < 4; ++j) acc[i][j] = {0.f, 0.f, 0.f, 0.f};

  for (int kc = 0; kc < K; kc += 64) {
    __syncthreads();
#pragma unroll
    for (int j = 0; j < 4; ++j) {
      int rbase = wid * 32 + j * 8;
      ldsload16(Al + rbase * 64, A + (size_t)(m0 + rbase + lrr) * K + kc + lcs);
      ldsload16(Bl + rbase * 64, BT + (size_t)(n0 + rbase + lrr) * K + kc + lcs);
    }
    __syncthreads();
#pragma unroll
    for (int ko = 0; ko < 64; ko += 32) {
      int g0 = ko >> 3;
      s8v af[4], bfr[4];
#pragma unroll
      for (int tm = 0; tm < 4; ++tm)
        af[tm] = *(const s8v*)(Al + (wm * 64 + tm * 16 + m16) * 64 + ((g0 + quad) ^ sw) * 8);
#pragma unroll
      for (int tn = 0; tn < 4; ++tn)
        bfr[tn] = *(const s8v*)(Bl + (wn * 64 + tn * 16 + m16) * 64 + ((g0 + quad) ^ sw) * 8);
#pragma unroll
      for (int tm = 0; tm < 4; ++tm)
#pragma unroll
        for (int tn = 0; tn < 4; ++tn)
          acc[tm][tn] = mfma16(af[tm], bfr[tn], acc[tm][tn]);
    }
  }
#pragma unroll
  for (int tm = 0; tm < 4; ++tm)
#pragma unroll
    for (int tn = 0; tn < 4; ++tn)
#pragma unroll
      for (int r = 0; r < 4; ++r) {
        int row = m0 + wm * 64 + tm * 16 + quad * 4 + r;
        int col = n0 + wn * 64 + tn * 16 + m16;
        float v = acc[tm][tn][r] * scale;
        if (bias) v += bias[col];
        if (do_relu) v = fmaxf(v, 0.f);
        v += post;
        if (resF) v += resF[(size_t)(row % resmod) * 1024 + col];
        if (outF) outF[(size_t)row * 1024 + col] = v;
        if (outB) outB[(size_t)row * 1024 + col] = f2bf(v);
      }
}

// ---------------- fused K/V projection + kv/ksum accumulation ----------------
// grid (64 s-tiles, 16 heads, 8 batches): blockIdx.x = mt so the 16 head-blocks sharing an
// A-tile have linear ids spaced 64 apart (64 % 8 == 0) -> same XCD -> A-tile L2 reuse.
__global__ __launch_bounds__(256) void kv_kernel(
    const u16* __restrict__ rgout, const u16* __restrict__ WkT, const u16* __restrict__ WvT,
    float* __restrict__ kv, float* __restrict__ ksum) {
  const int mt = blockIdx.x, h = blockIdx.y, b = blockIdx.z;
  const int t = threadIdx.x;
  const int wid = t >> 6, lane = t & 63, quad = lane >> 4, m16 = lane & 15;
  const int wm = wid >> 1, wn = wid & 1;
  const int lrr = lane >> 3;
  const int lcs = (((lane & 7) ^ lrr) * 8);
  const int sw = m16 & 7;
  __shared__ __align__(16) u16 smem[2 * 128 * 72];
  u16* Al = smem;              // [128][64] swizzled
  u16* Bl = smem + 128 * 64;   // [128][64] swizzled
  const size_t abase = ((size_t)b * 8192 + (size_t)mt * 128) * 1024;
  f4v acc[4][4];
#pragma unroll
  for (int i = 0; i < 4; ++i)
#pragma unroll
    for (int j = 0; j < 4; ++j) acc[i][j] = {0.f, 0.f, 0.f, 0.f};

  for (int kc = 0; kc < 1024; kc += 64) {
    __syncthreads();
#pragma unroll
    for (int j = 0; j < 4; ++j) {
      int rbase = wid * 32 + j * 8;
      int r = rbase + lrr;
      ldsload16(Al + rbase * 64, rgout + abase + (size_t)r * 1024 + kc + lcs);
      const u16* bsrc = (r < 64) ? (WkT + (size_t)(h * 64 + r) * 1024)
                                 : (WvT + (size_t)(h * 64 + (r - 64)) * 1024);
      ldsload16(Bl + rbase * 64, bsrc + kc + lcs);
    }
    __syncthreads();
#pragma unroll
    for (int ko = 0; ko < 64; ko += 32) {
      int g0 = ko >> 3;
      s8v af[4], bfr[4];
#pragma unroll
      for (int tm = 0; tm < 4; ++tm)
        af[tm] = *(const s8v*)(Al + (wm * 64 + tm * 16 + m16) * 64 + ((g0 + quad) ^ sw) * 8);
#pragma unroll
      for (int tn = 0; tn < 4; ++tn)
        bfr[tn] = *(const s8v*)(Bl + (wn * 64 + tn * 16 + m16) * 64 + ((g0 + quad) ^ sw) * 8);
#pragma unroll
      for (int tm = 0; tm < 4; ++tm)
#pragma unroll
        for (int tn = 0; tn < 4; ++tn)
          acc[tm][tn] = mfma16(af[tm], bfr[tn], acc[tm][tn]);
    }
  }
  __syncthreads();
  // epilogue: kp = relu(k*norm)+stab (wn==0), v unchanged (wn==1); write transposed to LDS
  u16* KPT = smem;             // [64 m][136 s]
  u16* VT = smem + 64 * 136;   // [64 d][136 s]
  {
    u16* dst = wn ? VT : KPT;
#pragma unroll
    for (int tm = 0; tm < 4; ++tm)
#pragma unroll
      for (int tn = 0; tn < 4; ++tn)
#pragma unroll
        for (int r = 0; r < 4; ++r) {
          int srow = wm * 64 + tm * 16 + quad * 4 + r;
          int feat = tn * 16 + m16;
          float v = acc[tm][tn][r];
          if (wn == 0) v = fmaxf(v * NORM_OBJ, 0.f) + STAB;
          dst[feat * 136 + srow] = f2bf(v);
        }
  }
  __syncthreads();
  // ksum partial
  if (t < 64) {
    float s = 0.f;
#pragma unroll
    for (int i = 0; i < 128; i += 8) {
      uint4 v = *(const uint4*)(KPT + t * 136 + i);
      u32 a[4] = {v.x, v.y, v.z, v.w};
#pragma unroll
      for (int q = 0; q < 4; ++q) {
        s += __uint_as_float(a[q] << 16);
        s += __uint_as_float(a[q] & 0xffff0000u);
      }
    }
    atomicAdd(&ksum[(size_t)(b * 16 + h) * 64 + t], s);
  }
  // second GEMM: kv_partial[64 m][64 d] = sum_s kp[s][m] * v[s][d]  (K=128)
  f4v a2[4];
#pragma unroll
  for (int tn = 0; tn < 4; ++tn) a2[tn] = {0.f, 0.f, 0.f, 0.f};
#pragma unroll
  for (int ks = 0; ks < 128; ks += 32) {
    s8v af = *(const s8v*)(KPT + (wid * 16 + m16) * 136 + ks + quad * 8);
#pragma unroll
    for (int tn = 0; tn < 4; ++tn) {
      s8v bv = *(const s8v*)(VT + (tn * 16 + m16) * 136 + ks + quad * 8);
      a2[tn] = mfma16(af, bv, a2[tn]);
    }
  }
#pragma unroll
  for (int tn = 0; tn < 4; ++tn)
#pragma unroll
    for (int r = 0; r < 4; ++r) {
      int m = wid * 16 + quad * 4 + r;
      int d = tn * 16 + m16;
      atomicAdd(&kv[((size_t)(b * 16 + h) * 64 + m) * 64 + d], a2[tn][r]);
    }
}

// ---------------- obj favor: out = (qp @ kv) / (qp . ksum) per row/head ----------------
// grid (256 row-blocks, 4 head-groups)
__global__ __launch_bounds__(256) void q2_kernel(const u16* __restrict__ qp,
    const float* __restrict__ kv, const float* __restrict__ ks, u16* __restrict__ out) {
  int wid = threadIdx.x >> 6, lane = threadIdx.x & 63;
  int row = blockIdx.x * 4 + wid;
  int b = row >> 7;
  int h0 = blockIdx.y * 4;
  for (int h = h0; h < h0 + 4; ++h) {
    const float* kvp = kv + (size_t)((b * 16 + h) * 64) * 64;
    const float* ksp = ks + (size_t)(b * 16 + h) * 64;
    const u16* qpp = qp + (size_t)row * 1024 + h * 64;
    float num = 0.f, den = 0.f;
    for (int m = 0; m < 64; ++m) {
      float qv = bf2f(qpp[m]);
      num += qv * kvp[m * 64 + lane];
      den += qv * ksp[m];
    }
    out[(size_t)row * 1024 + h * 64 + lane] = f2bf(num / den);
  }
}

// ---------------- layernorm over 1024, one block per row (shuffle reduction) ----------------
__global__ __launch_bounds__(256) void ln_kernel(const float* __restrict__ in,
    const float* __restrict__ g, const float* __restrict__ bb,
    float* __restrict__ outF, u16* __restrict__ outB) {
  int row = blockIdx.x, t = threadIdx.x;
  int wid = t >> 6;
  const float* x = in + (size_t)row * 1024;
  float v[4];
  float s = 0.f, ss = 0.f;
#pragma unroll
  for (int j = 0; j < 4; ++j) {
    v[j] = x[t + 256 * j];
    s += v[j];
    ss += v[j] * v[j];
  }
#pragma unroll
  for (int o = 32; o > 0; o >>= 1) {
    s += __shfl_down(s, o);
    ss += __shfl_down(ss, o);
  }
  __shared__ float ws[8];
  if ((t & 63) == 0) { ws[wid] = s; ws[wid + 4] = ss; }
  __syncthreads();
  s = ws[0] + ws[1] + ws[2] + ws[3];
  ss = ws[4] + ws[5] + ws[6] + ws[7];
  float mean = s * (1.f / 1024.f);
  float var = ss * (1.f / 1024.f) - mean * mean;
  float rstd = rsqrtf(var + LN_EPS);
#pragma unroll
  for (int j = 0; j < 4; ++j) {
    int c = t + 256 * j;
    float o = (v[j] - mean) * rstd * g[c] + bb[c];
    if (outF) outF[(size_t)row * 1024 + c] = o;
    if (outB) outB[(size_t)row * 1024 + c] = f2bf(o);
  }
}

// ---------------- workspace layout (bytes) ----------------
static constexpr size_t MBy = 1048576;
static constexpr size_t OFF_XROAD = 0;                       // 4 MB f32 (65536x16)
static constexpr size_t OFF_RGOUT = 4 * MBy;                 // 128 MiB bf16 (65536x1024)
static constexpr size_t OFF_KVR = OFF_RGOUT + 128 * MBy;     // 2048 B
static constexpr size_t OFF_KSR = OFF_KVR + 2048;            // 512 B
static constexpr size_t OFF_KVO = OFF_KVR + 4096;            // 2 MB f32
static constexpr size_t OFF_KSO = OFF_KVO + 2 * MBy;         // 32 KB f32
static constexpr size_t OFF_WT = OFF_KSO + 65536;            // 21 MB bf16 transposed weights
static constexpr size_t OFF_XOBJ = OFF_WT + 21 * MBy;        // 4 MB f32
static constexpr size_t OFF_XOBJB = OFF_XOBJ + 4 * MBy;      // 2 MB bf16
static constexpr size_t OFF_QP = OFF_XOBJB + 2 * MBy;        // 2 MB bf16
static constexpr size_t OFF_FOUT = OFF_QP + 2 * MBy;         // 2 MB bf16
static constexpr size_t OFF_T1 = OFF_FOUT + 2 * MBy;         // 4 MB f32
static constexpr size_t OFF_N = OFF_T1 + 4 * MBy;            // 4 MB f32
static constexpr size_t OFF_NB = OFF_N + 4 * MBy;            // 2 MB bf16
static constexpr size_t OFF_OBJB = OFF_NB + 2 * MBy;         // 1 MB bf16 (1024x512)

extern "C" void kernel_launch(void* const* d_in, const int* in_sizes, int n_in,
                              void* d_out, int out_size, void* d_ws, size_t ws_size,
                              hipStream_t stream) {
  (void)in_sizes; (void)n_in; (void)out_size; (void)ws_size;
  const float* obj = (const float*)d_in[0];
  const float* road = (const float*)d_in[1];
  const float* rgdW = (const float*)d_in[2];
  const float* rgdb = (const float*)d_in[3];
  const float* qkvW = (const float*)d_in[4];
  const float* qkvb = (const float*)d_in[5];
  const float* rgWq = (const float*)d_in[6];
  const float* rgWk = (const float*)d_in[7];
  const float* rgWv = (const float*)d_in[8];
  const float* rgWo = (const float*)d_in[9];
  const float* rglng = (const float*)d_in[10];
  const float* rglnb = (const float*)d_in[11];
  const float* rgfcW = (const float*)d_in[12];
  const float* rgfcb = (const float*)d_in[13];
  const float* rgoW = (const float*)d_in[14];
  const float* rgob = (const float*)d_in[15];
  const float* denW = (const float*)d_in[16];
  const float* denb = (const float*)d_in[17];
  const float* pose = (const float*)d_in[18];
  const float* Wq = (const float*)d_in[19];
  const float* Wk = (const float*)d_in[20];
  const float* Wv = (const float*)d_in[21];
  const float* Wo = (const float*)d_in[22];
  const float* lng = (const float*)d_in[23];
  const float* lnb = (const float*)d_in[24];
  const float* fcW = (const float*)d_in[25];
  const float* fcb = (const float*)d_in[26];

  char* w = (char*)d_ws;
  float* xroad = (float*)(w + OFF_XROAD);
  u16* rgout = (u16*)(w + OFF_RGOUT);
  float* kvr = (float*)(w + OFF_KVR);
  float* ksr = (float*)(w + OFF_KSR);
  float* kvo = (float*)(w + OFF_KVO);
  float* kso = (float*)(w + OFF_KSO);
  u16* wt = (u16*)(w + OFF_WT);
  float* xobj = (float*)(w + OFF_XOBJ);
  u16* xobjb = (u16*)(w + OFF_XOBJB);
  u16* qpB = (u16*)(w + OFF_QP);
  u16* fout = (u16*)(w + OFF_FOUT);
  float* t1 = (float*)(w + OFF_T1);
  float* nF = (float*)(w + OFF_N);
  u16* nB = (u16*)(w + OFF_NB);
  u16* objb = (u16*)(w + OFF_OBJB);

  const size_t E = 1048576;  // elems of a 1024x1024 matrix
  u16* wqT[2] = {wt + 0 * E, wt + 1 * E};
  u16* wkT[2] = {wt + 2 * E, wt + 3 * E};
  u16* wvT[2] = {wt + 4 * E, wt + 5 * E};
  u16* woT[2] = {wt + 6 * E, wt + 7 * E};
  u16* fcT[2] = {wt + 8 * E, wt + 9 * E};
  u16* denT = wt + 10 * E;

  // one-time weight transposes+convert (f32 K x N -> bf16 N x K)
  TP11 tb;
  const float* srcs[10] = {Wq, Wq + E, Wk, Wk + E, Wv, Wv + E, Wo, Wo + E, fcW, fcW + E};
  u16* dsts[10] = {wqT[0], wqT[1], wkT[0], wkT[1], wvT[0], wvT[1], woT[0], woT[1], fcT[0], fcT[1]};
  for (int j = 0; j < 11; ++j) { tb.p[j].s = srcs[j < 10 ? j : 0]; tb.p[j].d = dsts[j < 10 ? j : 0]; }
  transpose_kernel<<<dim3(16, 16, 10), 256, 0, stream>>>(tb, 1024, 1024);
  TP11 td;
  for (int j = 0; j < 11; ++j) { td.p[j].s = denW; td.p[j].d = denT; }
  transpose_kernel<<<dim3(16, 8, 1), 256, 0, stream>>>(td, 512, 1024);
  // obj f32 -> bf16 (1024x512 = 524288 elems)
  cvt_kernel<<<dim3(512), 256, 0, stream>>>(obj, objb);

  // road-graph encoder
  r0_kernel<<<dim3(256), 256, 0, stream>>>(road, rgdW, rgdb, xroad);
  for (int i = 0; i < 2; ++i) {
    hipMemsetAsync(w + OFF_KVR, 0, 2560, stream);
    ra_kernel<<<dim3(256), 256, 0, stream>>>(xroad, qkvW, qkvb, rgWk + i * 256, rgWv + i * 256,
                                             kvr, ksr);
    rb_kernel<<<dim3(256), 256, 0, stream>>>(xroad, qkvW, qkvb, rgWq + i * 256, rgWo + i * 256,
                                             rglng + i * 16, rglnb + i * 16, rgfcW + i * 256,
                                             rgfcb + i * 16, kvr, ksr);
  }
  rc_kernel<<<dim3(4, 4096), 256, 0, stream>>>(xroad, rgoW, rgob, rgout);

  // object encoder init: x = relu(obj @ dense_W + b) + pos_emb
  gemm_kernel<<<dim3(8, 8), 256, 0, stream>>>(objb, denT, 512, xobj, xobjb, denb, pose, 128,
                                              1.f, 1, 0.f);

  for (int i = 0; i < 2; ++i) {
    hipMemsetAsync(w + OFF_KVO, 0, 2 * MBy + 32768, stream);
    kv_kernel<<<dim3(64, 16, 8), 256, 0, stream>>>(rgout, wkT[i], wvT[i], kvo, kso);
    gemm_kernel<<<dim3(8, 8), 256, 0, stream>>>(xobjb, wqT[i], 1024, nullptr, qpB, nullptr,
                                                nullptr, 1024, NORM_OBJ, 1, STAB);
    q2_kernel<<<dim3(256, 4), 256, 0, stream>>>(qpB, kvo, kso, fout);
    gemm_kernel<<<dim3(8, 8), 256, 0, stream>>>(fout, woT[i], 1024, t1, nullptr, nullptr, xobj,
                                                1024, 1.f, 0, 0.f);
    ln_kernel<<<dim3(1024), 256, 0, stream>>>(t1, lng + i * 1024, lnb + i * 1024, nF, nB);
    gemm_kernel<<<dim3(8, 8), 256, 0, stream>>>(nB, fcT[i], 1024, t1, nullptr, fcb + i * 1024, nF,
                                                1024, 1.f, 1, 0.f);
    if (i == 0)
      ln_kernel<<<dim3(1024), 256, 0, stream>>>(t1, lng, lnb, xobj, xobjb);
    else
      ln_kernel<<<dim3(1024), 256, 0, stream>>>(t1, lng + 1024, lnb + 1024, (float*)d_out, nullptr);
  }
}

// Round 8
// 1680.122 us; speedup vs baseline: 1.4107x; 1.3000x over previous
//
#include <hip/hip_runtime.h>

typedef unsigned short u16;
typedef unsigned int u32;

using s8v = __attribute__((ext_vector_type(8))) short;  // 8 bf16
using f4v = __attribute__((ext_vector_type(4))) float;  // 4 fp32

#define LN_EPS 0.001f
#define STAB 0.001f
#define NORM_OBJ 0.35355339059327373f   // 64^-0.25
#define NORM_ROAD 0.7071067811865476f   // 4^-0.25

__device__ __forceinline__ float bf2f(u16 v) { return __uint_as_float(((u32)v) << 16); }
__device__ __forceinline__ u16 f2bf(float f) {
  u32 u = __float_as_uint(f);
  u32 r = (u + 0x7fffu + ((u >> 16) & 1u)) >> 16;
  return (u16)r;
}
__device__ __forceinline__ f4v mfma16(s8v a, s8v b, f4v c) {
  return __builtin_amdgcn_mfma_f32_16x16x32_bf16(a, b, c, 0, 0, 0);
}
// async global->LDS, 16 B/lane; LDS dest = wave-uniform base + lane*16
__device__ __forceinline__ void ldsload16(void* lds, const void* g) {
  __builtin_amdgcn_global_load_lds((const __attribute__((address_space(1))) u32*)g,
                                   (__attribute__((address_space(3))) u32*)lds, 16, 0, 0);
}

// ---------------- transpose+convert: src[K][N] f32 -> dst[N][K] bf16 ----------------
struct TPair { const float* s; u16* d; };
struct TP11 { TPair p[11]; };

__global__ __launch_bounds__(256) void transpose_kernel(TP11 ps, int K, int N) {
  const float* __restrict__ src = ps.p[blockIdx.z].s;
  u16* __restrict__ dst = ps.p[blockIdx.z].d;
  int n0 = blockIdx.x * 64, k0 = blockIdx.y * 64;
  int t = threadIdx.x;
  __shared__ __align__(16) u16 lt[64 * 72];
#pragma unroll
  for (int j = 0; j < 4; ++j) {
    int p = t + 256 * j;
    int r = p >> 4, cb = p & 15;
    float4 v = *(const float4*)(src + (size_t)(k0 + r) * N + n0 + cb * 4);
    lt[r * 72 + cb * 4 + 0] = f2bf(v.x);
    lt[r * 72 + cb * 4 + 1] = f2bf(v.y);
    lt[r * 72 + cb * 4 + 2] = f2bf(v.z);
    lt[r * 72 + cb * 4 + 3] = f2bf(v.w);
  }
  __syncthreads();
#pragma unroll
  for (int j = 0; j < 2; ++j) {
    int q = t + 256 * j;
    int on = q >> 3, ocb = q & 7;
    u16 e[8];
#pragma unroll
    for (int i = 0; i < 8; ++i) e[i] = lt[(ocb * 8 + i) * 72 + on];
    uint4 v;
    v.x = (u32)e[0] | ((u32)e[1] << 16);
    v.y = (u32)e[2] | ((u32)e[3] << 16);
    v.z = (u32)e[4] | ((u32)e[5] << 16);
    v.w = (u32)e[6] | ((u32)e[7] << 16);
    *(uint4*)(dst + (size_t)(n0 + on) * K + k0 + ocb * 8) = v;
  }
}

// ---------------- f32 -> bf16 convert ----------------
__global__ __launch_bounds__(256) void cvt_kernel(const float* __restrict__ src,
                                                  u16* __restrict__ dst) {
  int i = (blockIdx.x * 256 + threadIdx.x) * 4;
  float4 v = *(const float4*)(src + i);
  uint2 o;
  o.x = (u32)f2bf(v.x) | ((u32)f2bf(v.y) << 16);
  o.y = (u32)f2bf(v.z) | ((u32)f2bf(v.w) << 16);
  *(uint2*)(dst + i) = o;
}

// ---------------- road: x = relu(road @ Wd + bd), 65536 x (8->16) ----------------
__global__ __launch_bounds__(256) void r0_kernel(const float* __restrict__ road,
    const float* __restrict__ W, const float* __restrict__ bias, float* __restrict__ x) {
  int row = blockIdx.x * 256 + threadIdx.x;
  float in[8];
  float4 v0 = *(const float4*)(road + (size_t)row * 8);
  float4 v1 = *(const float4*)(road + (size_t)row * 8 + 4);
  in[0] = v0.x; in[1] = v0.y; in[2] = v0.z; in[3] = v0.w;
  in[4] = v1.x; in[5] = v1.y; in[6] = v1.z; in[7] = v1.w;
#pragma unroll
  for (int j = 0; j < 16; ++j) {
    float s = bias[j];
#pragma unroll
    for (int c = 0; c < 8; ++c) s += in[c] * W[c * 16 + j];
    x[(size_t)row * 16 + j] = fmaxf(s, 0.f);
  }
}

// ---------------- road favor pass1: accumulate kv_road/ksum_road ----------------
__global__ __launch_bounds__(256) void ra_kernel(const float* __restrict__ x,
    const float* __restrict__ qkvW, const float* __restrict__ qkvb,
    const float* __restrict__ Wk, const float* __restrict__ Wv,
    float* __restrict__ kvr, float* __restrict__ ksr) {
  int t = threadIdx.x;
  int row = blockIdx.x * 256 + t;
  int b = row >> 13;
  float xv[16];
#pragma unroll
  for (int e = 0; e < 16; ++e) xv[e] = x[(size_t)row * 16 + e];
  float q16[16];
#pragma unroll
  for (int j = 0; j < 16; ++j) {
    float s = qkvb[j];
#pragma unroll
    for (int c = 0; c < 16; ++c) s += xv[c] * qkvW[c * 48 + j];
    q16[j] = fmaxf(s, 0.f);
  }
  float kp[16], vh[16];
#pragma unroll
  for (int hm = 0; hm < 16; ++hm) {
    float sk = 0.f, sv = 0.f;
#pragma unroll
    for (int c = 0; c < 16; ++c) {
      float q = q16[c];
      sk += q * Wk[c * 16 + hm];
      sv += q * Wv[c * 16 + hm];
    }
    kp[hm] = fmaxf(sk * NORM_ROAD, 0.f) + STAB;
    vh[hm] = sv;
  }
  __shared__ float l[80];
  if (t < 80) l[t] = 0.f;
  __syncthreads();
#pragma unroll
  for (int h = 0; h < 4; ++h)
#pragma unroll
    for (int m = 0; m < 4; ++m) {
      float kpv = kp[h * 4 + m];
      atomicAdd(&l[64 + h * 4 + m], kpv);
#pragma unroll
      for (int d = 0; d < 4; ++d) atomicAdd(&l[h * 16 + m * 4 + d], kpv * vh[h * 4 + d]);
    }
  __syncthreads();
  if (t < 64) atomicAdd(&kvr[b * 64 + t], l[t]);
  else if (t < 80) atomicAdd(&ksr[b * 16 + (t - 64)], l[t]);
}

__device__ __forceinline__ void ln16(const float* tv, const float* g, const float* bb, float* o) {
  float m = 0.f;
#pragma unroll
  for (int e = 0; e < 16; ++e) m += tv[e];
  m *= (1.f / 16.f);
  float var = 0.f;
#pragma unroll
  for (int e = 0; e < 16; ++e) { float d = tv[e] - m; var += d * d; }
  var *= (1.f / 16.f);
  float rstd = rsqrtf(var + LN_EPS);
#pragma unroll
  for (int e = 0; e < 16; ++e) o[e] = (tv[e] - m) * rstd * g[e] + bb[e];
}

// ---------------- road favor pass2 + LN + fc + LN (in-place x update) ----------------
__global__ __launch_bounds__(256) void rb_kernel(float* __restrict__ x,
    const float* __restrict__ qkvW, const float* __restrict__ qkvb,
    const float* __restrict__ Wq, const float* __restrict__ Wo,
    const float* __restrict__ lng, const float* __restrict__ lnb,
    const float* __restrict__ fcW, const float* __restrict__ fcb,
    const float* __restrict__ kvr, const float* __restrict__ ksr) {
  int row = blockIdx.x * 256 + threadIdx.x;
  int b = row >> 13;
  float xv[16];
#pragma unroll
  for (int e = 0; e < 16; ++e) xv[e] = x[(size_t)row * 16 + e];
  float q16[16];
#pragma unroll
  for (int j = 0; j < 16; ++j) {
    float s = qkvb[j];
#pragma unroll
    for (int c = 0; c < 16; ++c) s += xv[c] * qkvW[c * 48 + j];
    q16[j] = fmaxf(s, 0.f);
  }
  float qp[16];
#pragma unroll
  for (int hm = 0; hm < 16; ++hm) {
    float s = 0.f;
#pragma unroll
    for (int c = 0; c < 16; ++c) s += q16[c] * Wq[c * 16 + hm];
    qp[hm] = fmaxf(s * NORM_ROAD, 0.f) + STAB;
  }
  float attn[16];
#pragma unroll
  for (int e = 0; e < 16; ++e) attn[e] = 0.f;
#pragma unroll
  for (int h = 0; h < 4; ++h) {
    float den = 0.f;
#pragma unroll
    for (int m = 0; m < 4; ++m) den += qp[h * 4 + m] * ksr[b * 16 + h * 4 + m];
    float od[4];
#pragma unroll
    for (int d = 0; d < 4; ++d) {
      float num = 0.f;
#pragma unroll
      for (int m = 0; m < 4; ++m) num += qp[h * 4 + m] * kvr[b * 64 + h * 16 + m * 4 + d];
      od[d] = num / den;
    }
#pragma unroll
    for (int d = 0; d < 4; ++d)
#pragma unroll
      for (int e = 0; e < 16; ++e) attn[e] += od[d] * Wo[(h * 4 + d) * 16 + e];
  }
  float tv[16], n[16], o2[16];
#pragma unroll
  for (int e = 0; e < 16; ++e) tv[e] = attn[e] + xv[e];
  ln16(tv, lng, lnb, n);
#pragma unroll
  for (int j = 0; j < 16; ++j) {
    float s = fcb[j];
#pragma unroll
    for (int e = 0; e < 16; ++e) s += n[e] * fcW[e * 16 + j];
    tv[j] = n[j] + fmaxf(s, 0.f);
  }
  ln16(tv, lng, lnb, o2);
#pragma unroll
  for (int e = 0; e < 16; ++e) x[(size_t)row * 16 + e] = o2[e];
}

// ---------------- rg_out = relu(x_road @ rg_out_W + b) -> bf16, 65536x1024 ----------------
__global__ __launch_bounds__(256) void rc_kernel(const float* __restrict__ x,
    const float* __restrict__ W, const float* __restrict__ bias, u16* __restrict__ out) {
  const int t = threadIdx.x;
  const int cg = t & 63, rg = t >> 6;
  const int c0 = blockIdx.x * 256 + cg * 4;
  const int r0 = blockIdx.y * 16;
  __shared__ float lx[256];
  lx[t] = x[(size_t)(r0 + (t >> 4)) * 16 + (t & 15)];
  __syncthreads();
  float4 wv[16];
#pragma unroll
  for (int c = 0; c < 16; ++c) wv[c] = *(const float4*)(W + (size_t)c * 1024 + c0);
  float4 bv = *(const float4*)(bias + c0);
#pragma unroll
  for (int k = 0; k < 4; ++k) {
    int rr = rg * 4 + k;
    float s0 = bv.x, s1 = bv.y, s2 = bv.z, s3 = bv.w;
#pragma unroll
    for (int c = 0; c < 16; ++c) {
      float xv = lx[rr * 16 + c];
      s0 += xv * wv[c].x; s1 += xv * wv[c].y; s2 += xv * wv[c].z; s3 += xv * wv[c].w;
    }
    uint2 o;
    o.x = (u32)f2bf(fmaxf(s0, 0.f)) | ((u32)f2bf(fmaxf(s1, 0.f)) << 16);
    o.y = (u32)f2bf(fmaxf(s2, 0.f)) | ((u32)f2bf(fmaxf(s3, 0.f)) << 16);
    *(uint2*)(out + (size_t)(r0 + rr) * 1024 + c0) = o;
  }
}

// ---------------- generic MFMA GEMM: C = act(A[MxK] @ BT[NxK]^T), 128x128 tile ----------------
// LDS staged via global_load_lds with XOR swizzle
__global__ __launch_bounds__(256) void gemm_kernel(
    const u16* __restrict__ A, const u16* __restrict__ BT, int K,
    float* __restrict__ outF, u16* __restrict__ outB,
    const float* __restrict__ bias, const float* __restrict__ resF, int resmod,
    float scale, int do_relu, float post) {
  const int n0 = blockIdx.x * 128, m0 = blockIdx.y * 128;
  const int t = threadIdx.x;
  const int wid = t >> 6, lane = t & 63, quad = lane >> 4, m16 = lane & 15;
  const int wm = wid >> 1, wn = wid & 1;
  const int lrr = lane >> 3;
  const int lcs = (((lane & 7) ^ lrr) * 8);
  const int sw = m16 & 7;
  __shared__ __align__(16) u16 smem[2 * 128 * 64];
  u16* Al = smem;
  u16* Bl = smem + 128 * 64;
  f4v acc[4][4];
#pragma unroll
  for (int i = 0; i < 4; ++i)
#pragma unroll
    for (int j = 0; j < 4; ++j) acc[i][j] = {0.f, 0.f, 0.f, 0.f};

  for (int kc = 0; kc < K; kc += 64) {
    __syncthreads();
#pragma unroll
    for (int j = 0; j < 4; ++j) {
      int rbase = wid * 32 + j * 8;
      ldsload16(Al + rbase * 64, A + (size_t)(m0 + rbase + lrr) * K + kc + lcs);
      ldsload16(Bl + rbase * 64, BT + (size_t)(n0 + rbase + lrr) * K + kc + lcs);
    }
    __syncthreads();
#pragma unroll
    for (int ko = 0; ko < 64; ko += 32) {
      int g0 = ko >> 3;
      s8v af[4], bfr[4];
#pragma unroll
      for (int tm = 0; tm < 4; ++tm)
        af[tm] = *(const s8v*)(Al + (wm * 64 + tm * 16 + m16) * 64 + ((g0 + quad) ^ sw) * 8);
#pragma unroll
      for (int tn = 0; tn < 4; ++tn)
        bfr[tn] = *(const s8v*)(Bl + (wn * 64 + tn * 16 + m16) * 64 + ((g0 + quad) ^ sw) * 8);
#pragma unroll
      for (int tm = 0; tm < 4; ++tm)
#pragma unroll
        for (int tn = 0; tn < 4; ++tn)
          acc[tm][tn] = mfma16(af[tm], bfr[tn], acc[tm][tn]);
    }
  }
#pragma unroll
  for (int tm = 0; tm < 4; ++tm)
#pragma unroll
    for (int tn = 0; tn < 4; ++tn)
#pragma unroll
      for (int r = 0; r < 4; ++r) {
        int row = m0 + wm * 64 + tm * 16 + quad * 4 + r;
        int col = n0 + wn * 64 + tn * 16 + m16;
        float v = acc[tm][tn][r] * scale;
        if (bias) v += bias[col];
        if (do_relu) v = fmaxf(v, 0.f);
        v += post;
        if (resF) v += resF[(size_t)(row % resmod) * 1024 + col];
        if (outF) outF[(size_t)row * 1024 + col] = v;
        if (outB) outB[(size_t)row * 1024 + col] = f2bf(v);
      }
}

// ---------------- fused K/V projection + kv/ksum accumulation ----------------
// grid (64 s-tiles, 16 heads, 8 batches): blockIdx.x = mt so the 16 head-blocks sharing an
// A-tile have linear ids spaced 64 apart (64 % 8 == 0) -> same XCD -> A-tile L2 reuse.
__global__ __launch_bounds__(256) void kv_kernel(
    const u16* __restrict__ rgout, const u16* __restrict__ WkT, const u16* __restrict__ WvT,
    float* __restrict__ kv, float* __restrict__ ksum) {
  const int mt = blockIdx.x, h = blockIdx.y, b = blockIdx.z;
  const int t = threadIdx.x;
  const int wid = t >> 6, lane = t & 63, quad = lane >> 4, m16 = lane & 15;
  const int wm = wid >> 1, wn = wid & 1;
  const int lrr = lane >> 3;
  const int lcs = (((lane & 7) ^ lrr) * 8);
  const int sw = m16 & 7;
  __shared__ __align__(16) u16 smem[2 * 128 * 72];
  u16* Al = smem;              // [128][64] swizzled
  u16* Bl = smem + 128 * 64;   // [128][64] swizzled
  const size_t abase = ((size_t)b * 8192 + (size_t)mt * 128) * 1024;
  f4v acc[4][4];
#pragma unroll
  for (int i = 0; i < 4; ++i)
#pragma unroll
    for (int j = 0; j < 4; ++j) acc[i][j] = {0.f, 0.f, 0.f, 0.f};

  for (int kc = 0; kc < 1024; kc += 64) {
    __syncthreads();
#pragma unroll
    for (int j = 0; j < 4; ++j) {
      int rbase = wid * 32 + j * 8;
      int r = rbase + lrr;
      ldsload16(Al + rbase * 64, rgout + abase + (size_t)r * 1024 + kc + lcs);
      const u16* bsrc = (r < 64) ? (WkT + (size_t)(h * 64 + r) * 1024)
                                 : (WvT + (size_t)(h * 64 + (r - 64)) * 1024);
      ldsload16(Bl + rbase * 64, bsrc + kc + lcs);
    }
    __syncthreads();
#pragma unroll
    for (int ko = 0; ko < 64; ko += 32) {
      int g0 = ko >> 3;
      s8v af[4], bfr[4];
#pragma unroll
      for (int tm = 0; tm < 4; ++tm)
        af[tm] = *(const s8v*)(Al + (wm * 64 + tm * 16 + m16) * 64 + ((g0 + quad) ^ sw) * 8);
#pragma unroll
      for (int tn = 0; tn < 4; ++tn)
        bfr[tn] = *(const s8v*)(Bl + (wn * 64 + tn * 16 + m16) * 64 + ((g0 + quad) ^ sw) * 8);
#pragma unroll
      for (int tm = 0; tm < 4; ++tm)
#pragma unroll
        for (int tn = 0; tn < 4; ++tn)
          acc[tm][tn] = mfma16(af[tm], bfr[tn], acc[tm][tn]);
    }
  }
  __syncthreads();
  // epilogue: kp = relu(k*norm)+stab (wn==0), v unchanged (wn==1); write transposed to LDS.
  // For fixed (tm,tn) the 4 acc regs are 4 CONSECUTIVE s-rows -> one packed b64 store.
  u16* KPT = smem;             // [64 m][136 s]
  u16* VT = smem + 64 * 136;   // [64 d][136 s]
  {
    u16* dst = wn ? VT : KPT;
    const int sbase = wm * 64 + quad * 4;
#pragma unroll
    for (int tm = 0; tm < 4; ++tm)
#pragma unroll
      for (int tn = 0; tn < 4; ++tn) {
        float v0 = acc[tm][tn][0], v1 = acc[tm][tn][1];
        float v2 = acc[tm][tn][2], v3 = acc[tm][tn][3];
        if (wn == 0) {
          v0 = fmaxf(v0 * NORM_OBJ, 0.f) + STAB;
          v1 = fmaxf(v1 * NORM_OBJ, 0.f) + STAB;
          v2 = fmaxf(v2 * NORM_OBJ, 0.f) + STAB;
          v3 = fmaxf(v3 * NORM_OBJ, 0.f) + STAB;
        }
        uint2 o;
        o.x = (u32)f2bf(v0) | ((u32)f2bf(v1) << 16);
        o.y = (u32)f2bf(v2) | ((u32)f2bf(v3) << 16);
        int feat = tn * 16 + m16;
        *(uint2*)(dst + feat * 136 + sbase + tm * 16) = o;
      }
  }
  __syncthreads();
  // ksum partial
  if (t < 64) {
    float s = 0.f;
#pragma unroll
    for (int i = 0; i < 128; i += 8) {
      uint4 v = *(const uint4*)(KPT + t * 136 + i);
      u32 a[4] = {v.x, v.y, v.z, v.w};
#pragma unroll
      for (int q = 0; q < 4; ++q) {
        s += __uint_as_float(a[q] << 16);
        s += __uint_as_float(a[q] & 0xffff0000u);
      }
    }
    atomicAdd(&ksum[(size_t)(b * 16 + h) * 64 + t], s);
  }
  // second GEMM: kv_partial[64 m][64 d] = sum_s kp[s][m] * v[s][d]  (K=128)
  f4v a2[4];
#pragma unroll
  for (int tn = 0; tn < 4; ++tn) a2[tn] = {0.f, 0.f, 0.f, 0.f};
#pragma unroll
  for (int ks = 0; ks < 128; ks += 32) {
    s8v af = *(const s8v*)(KPT + (wid * 16 + m16) * 136 + ks + quad * 8);
#pragma unroll
    for (int tn = 0; tn < 4; ++tn) {
      s8v bv = *(const s8v*)(VT + (tn * 16 + m16) * 136 + ks + quad * 8);
      a2[tn] = mfma16(af, bv, a2[tn]);
    }
  }
#pragma unroll
  for (int tn = 0; tn < 4; ++tn)
#pragma unroll
    for (int r = 0; r < 4; ++r) {
      int m = wid * 16 + quad * 4 + r;
      int d = tn * 16 + m16;
      atomicAdd(&kv[((size_t)(b * 16 + h) * 64 + m) * 64 + d], a2[tn][r]);
    }
}

// ---------------- obj favor: out = (qp @ kv) / (qp . ksum) per row/head ----------------
// grid (256 row-blocks, 4 head-groups)
__global__ __launch_bounds__(256) void q2_kernel(const u16* __restrict__ qp,
    const float* __restrict__ kv, const float* __restrict__ ks, u16* __restrict__ out) {
  int wid = threadIdx.x >> 6, lane = threadIdx.x & 63;
  int row = blockIdx.x * 4 + wid;
  int b = row >> 7;
  int h0 = blockIdx.y * 4;
  for (int h = h0; h < h0 + 4; ++h) {
    const float* kvp = kv + (size_t)((b * 16 + h) * 64) * 64;
    const float* ksp = ks + (size_t)(b * 16 + h) * 64;
    const u16* qpp = qp + (size_t)row * 1024 + h * 64;
    float num = 0.f, den = 0.f;
    for (int m = 0; m < 64; ++m) {
      float qv = bf2f(qpp[m]);
      num += qv * kvp[m * 64 + lane];
      den += qv * ksp[m];
    }
    out[(size_t)row * 1024 + h * 64 + lane] = f2bf(num / den);
  }
}

// ---------------- layernorm over 1024, one block per row ----------------
__global__ __launch_bounds__(256) void ln_kernel(const float* __restrict__ in,
    const float* __restrict__ g, const float* __restrict__ bb,
    float* __restrict__ outF, u16* __restrict__ outB) {
  int row = blockIdx.x, t = threadIdx.x;
  const float* x = in + (size_t)row * 1024;
  float v[4];
  float s = 0.f, ss = 0.f;
#pragma unroll
  for (int j = 0; j < 4; ++j) {
    v[j] = x[t + 256 * j];
    s += v[j];
    ss += v[j] * v[j];
  }
  __shared__ float rs[256], rss[256];
  rs[t] = s; rss[t] = ss;
  __syncthreads();
  for (int o = 128; o > 0; o >>= 1) {
    if (t < o) { rs[t] += rs[t + o]; rss[t] += rss[t + o]; }
    __syncthreads();
  }
  float mean = rs[0] * (1.f / 1024.f);
  float var = rss[0] * (1.f / 1024.f) - mean * mean;
  float rstd = rsqrtf(var + LN_EPS);
#pragma unroll
  for (int j = 0; j < 4; ++j) {
    int c = t + 256 * j;
    float o = (v[j] - mean) * rstd * g[c] + bb[c];
    if (outF) outF[(size_t)row * 1024 + c] = o;
    if (outB) outB[(size_t)row * 1024 + c] = f2bf(o);
  }
}

// ---------------- workspace layout (bytes) ----------------
static constexpr size_t MBy = 1048576;
static constexpr size_t OFF_XROAD = 0;                       // 4 MB f32 (65536x16)
static constexpr size_t OFF_RGOUT = 4 * MBy;                 // 128 MiB bf16 (65536x1024)
static constexpr size_t OFF_KVR = OFF_RGOUT + 128 * MBy;     // 2048 B
static constexpr size_t OFF_KSR = OFF_KVR + 2048;            // 512 B
static constexpr size_t OFF_KVO = OFF_KVR + 4096;            // 2 MB f32
static constexpr size_t OFF_KSO = OFF_KVO + 2 * MBy;         // 32 KB f32
static constexpr size_t OFF_WT = OFF_KSO + 65536;            // 21 MB bf16 transposed weights
static constexpr size_t OFF_XOBJ = OFF_WT + 21 * MBy;        // 4 MB f32
static constexpr size_t OFF_XOBJB = OFF_XOBJ + 4 * MBy;      // 2 MB bf16
static constexpr size_t OFF_QP = OFF_XOBJB + 2 * MBy;        // 2 MB bf16
static constexpr size_t OFF_FOUT = OFF_QP + 2 * MBy;         // 2 MB bf16
static constexpr size_t OFF_T1 = OFF_FOUT + 2 * MBy;         // 4 MB f32
static constexpr size_t OFF_N = OFF_T1 + 4 * MBy;            // 4 MB f32
static constexpr size_t OFF_NB = OFF_N + 4 * MBy;            // 2 MB bf16
static constexpr size_t OFF_OBJB = OFF_NB + 2 * MBy;         // 1 MB bf16 (1024x512)

extern "C" void kernel_launch(void* const* d_in, const int* in_sizes, int n_in,
                              void* d_out, int out_size, void* d_ws, size_t ws_size,
                              hipStream_t stream) {
  (void)in_sizes; (void)n_in; (void)out_size; (void)ws_size;
  const float* obj = (const float*)d_in[0];
  const float* road = (const float*)d_in[1];
  const float* rgdW = (const float*)d_in[2];
  const float* rgdb = (const float*)d_in[3];
  const float* qkvW = (const float*)d_in[4];
  const float* qkvb = (const float*)d_in[5];
  const float* rgWq = (const float*)d_in[6];
  const float* rgWk = (const float*)d_in[7];
  const float* rgWv = (const float*)d_in[8];
  const float* rgWo = (const float*)d_in[9];
  const float* rglng = (const float*)d_in[10];
  const float* rglnb = (const float*)d_in[11];
  const float* rgfcW = (const float*)d_in[12];
  const float* rgfcb = (const float*)d_in[13];
  const float* rgoW = (const float*)d_in[14];
  const float* rgob = (const float*)d_in[15];
  const float* denW = (const float*)d_in[16];
  const float* denb = (const float*)d_in[17];
  const float* pose = (const float*)d_in[18];
  const float* Wq = (const float*)d_in[19];
  const float* Wk = (const float*)d_in[20];
  const float* Wv = (const float*)d_in[21];
  const float* Wo = (const float*)d_in[22];
  const float* lng = (const float*)d_in[23];
  const float* lnb = (const float*)d_in[24];
  const float* fcW = (const float*)d_in[25];
  const float* fcb = (const float*)d_in[26];

  char* w = (char*)d_ws;
  float* xroad = (float*)(w + OFF_XROAD);
  u16* rgout = (u16*)(w + OFF_RGOUT);
  float* kvr = (float*)(w + OFF_KVR);
  float* ksr = (float*)(w + OFF_KSR);
  float* kvo = (float*)(w + OFF_KVO);
  float* kso = (float*)(w + OFF_KSO);
  u16* wt = (u16*)(w + OFF_WT);
  float* xobj = (float*)(w + OFF_XOBJ);
  u16* xobjb = (u16*)(w + OFF_XOBJB);
  u16* qpB = (u16*)(w + OFF_QP);
  u16* fout = (u16*)(w + OFF_FOUT);
  float* t1 = (float*)(w + OFF_T1);
  float* nF = (float*)(w + OFF_N);
  u16* nB = (u16*)(w + OFF_NB);
  u16* objb = (u16*)(w + OFF_OBJB);

  const size_t E = 1048576;  // elems of a 1024x1024 matrix
  u16* wqT[2] = {wt + 0 * E, wt + 1 * E};
  u16* wkT[2] = {wt + 2 * E, wt + 3 * E};
  u16* wvT[2] = {wt + 4 * E, wt + 5 * E};
  u16* woT[2] = {wt + 6 * E, wt + 7 * E};
  u16* fcT[2] = {wt + 8 * E, wt + 9 * E};
  u16* denT = wt + 10 * E;

  // one-time weight transposes+convert (f32 K x N -> bf16 N x K)
  TP11 tb;
  const float* srcs[10] = {Wq, Wq + E, Wk, Wk + E, Wv, Wv + E, Wo, Wo + E, fcW, fcW + E};
  u16* dsts[10] = {wqT[0], wqT[1], wkT[0], wkT[1], wvT[0], wvT[1], woT[0], woT[1], fcT[0], fcT[1]};
  for (int j = 0; j < 11; ++j) { tb.p[j].s = srcs[j < 10 ? j : 0]; tb.p[j].d = dsts[j < 10 ? j : 0]; }
  transpose_kernel<<<dim3(16, 16, 10), 256, 0, stream>>>(tb, 1024, 1024);
  TP11 td;
  for (int j = 0; j < 11; ++j) { td.p[j].s = denW; td.p[j].d = denT; }
  transpose_kernel<<<dim3(16, 8, 1), 256, 0, stream>>>(td, 512, 1024);
  // obj f32 -> bf16 (1024x512 = 524288 elems)
  cvt_kernel<<<dim3(512), 256, 0, stream>>>(obj, objb);

  // road-graph encoder
  r0_kernel<<<dim3(256), 256, 0, stream>>>(road, rgdW, rgdb, xroad);
  for (int i = 0; i < 2; ++i) {
    hipMemsetAsync(w + OFF_KVR, 0, 2560, stream);
    ra_kernel<<<dim3(256), 256, 0, stream>>>(xroad, qkvW, qkvb, rgWk + i * 256, rgWv + i * 256,
                                             kvr, ksr);
    rb_kernel<<<dim3(256), 256, 0, stream>>>(xroad, qkvW, qkvb, rgWq + i * 256, rgWo + i * 256,
                                             rglng + i * 16, rglnb + i * 16, rgfcW + i * 256,
                                             rgfcb + i * 16, kvr, ksr);
  }
  rc_kernel<<<dim3(4, 4096), 256, 0, stream>>>(xroad, rgoW, rgob, rgout);

  // object encoder init: x = relu(obj @ dense_W + b) + pos_emb
  gemm_kernel<<<dim3(8, 8), 256, 0, stream>>>(objb, denT, 512, xobj, xobjb, denb, pose, 128,
                                              1.f, 1, 0.f);

  for (int i = 0; i < 2; ++i) {
    hipMemsetAsync(w + OFF_KVO, 0, 2 * MBy + 32768, stream);
    kv_kernel<<<dim3(64, 16, 8), 256, 0, stream>>>(rgout, wkT[i], wvT[i], kvo, kso);
    gemm_kernel<<<dim3(8, 8), 256, 0, stream>>>(xobjb, wqT[i], 1024, nullptr, qpB, nullptr,
                                                nullptr, 1024, NORM_OBJ, 1, STAB);
    q2_kernel<<<dim3(256, 4), 256, 0, stream>>>(qpB, kvo, kso, fout);
    gemm_kernel<<<dim3(8, 8), 256, 0, stream>>>(fout, woT[i], 1024, t1, nullptr, nullptr, xobj,
                                                1024, 1.f, 0, 0.f);
    ln_kernel<<<dim3(1024), 256, 0, stream>>>(t1, lng + i * 1024, lnb + i * 1024, nF, nB);
    gemm_kernel<<<dim3(8, 8), 256, 0, stream>>>(nB, fcT[i], 1024, t1, nullptr, fcb + i * 1024, nF,
                                                1024, 1.f, 1, 0.f);
    if (i == 0)
      ln_kernel<<<dim3(1024), 256, 0, stream>>>(t1, lng, lnb, xobj, xobjb);
    else
      ln_kernel<<<dim3(1024), 256, 0, stream>>>(t1, lng + 1024, lnb + 1024, (float*)d_out, nullptr);
  }
}

// Round 9
// 1668.210 us; speedup vs baseline: 1.4208x; 1.0071x over previous
//
#include <hip/hip_runtime.h>

typedef unsigned short u16;
typedef unsigned int u32;

using s8v = __attribute__((ext_vector_type(8))) short;  // 8 bf16
using f4v = __attribute__((ext_vector_type(4))) float;  // 4 fp32

#define LN_EPS 0.001f
#define STAB 0.001f
#define NORM_OBJ 0.35355339059327373f   // 64^-0.25
#define NORM_ROAD 0.7071067811865476f   // 4^-0.25

__device__ __forceinline__ float bf2f(u16 v) { return __uint_as_float(((u32)v) << 16); }
__device__ __forceinline__ u16 f2bf(float f) {
  u32 u = __float_as_uint(f);
  u32 r = (u + 0x7fffu + ((u >> 16) & 1u)) >> 16;
  return (u16)r;
}
__device__ __forceinline__ f4v mfma16(s8v a, s8v b, f4v c) {
  return __builtin_amdgcn_mfma_f32_16x16x32_bf16(a, b, c, 0, 0, 0);
}
// async global->LDS, 16 B/lane; LDS dest = wave-uniform base + lane*16
__device__ __forceinline__ void ldsload16(void* lds, const void* g) {
  __builtin_amdgcn_global_load_lds((const __attribute__((address_space(1))) u32*)g,
                                   (__attribute__((address_space(3))) u32*)lds, 16, 0, 0);
}

// ---------------- transpose+convert: src[K][N] f32 -> dst[N][K] bf16 ----------------
struct TPair { const float* s; u16* d; };
struct TP11 { TPair p[11]; };

__global__ __launch_bounds__(256) void transpose_kernel(TP11 ps, int K, int N) {
  const float* __restrict__ src = ps.p[blockIdx.z].s;
  u16* __restrict__ dst = ps.p[blockIdx.z].d;
  int n0 = blockIdx.x * 64, k0 = blockIdx.y * 64;
  int t = threadIdx.x;
  __shared__ __align__(16) u16 lt[64 * 72];
#pragma unroll
  for (int j = 0; j < 4; ++j) {
    int p = t + 256 * j;
    int r = p >> 4, cb = p & 15;
    float4 v = *(const float4*)(src + (size_t)(k0 + r) * N + n0 + cb * 4);
    lt[r * 72 + cb * 4 + 0] = f2bf(v.x);
    lt[r * 72 + cb * 4 + 1] = f2bf(v.y);
    lt[r * 72 + cb * 4 + 2] = f2bf(v.z);
    lt[r * 72 + cb * 4 + 3] = f2bf(v.w);
  }
  __syncthreads();
#pragma unroll
  for (int j = 0; j < 2; ++j) {
    int q = t + 256 * j;
    int on = q >> 3, ocb = q & 7;
    u16 e[8];
#pragma unroll
    for (int i = 0; i < 8; ++i) e[i] = lt[(ocb * 8 + i) * 72 + on];
    uint4 v;
    v.x = (u32)e[0] | ((u32)e[1] << 16);
    v.y = (u32)e[2] | ((u32)e[3] << 16);
    v.z = (u32)e[4] | ((u32)e[5] << 16);
    v.w = (u32)e[6] | ((u32)e[7] << 16);
    *(uint4*)(dst + (size_t)(n0 + on) * K + k0 + ocb * 8) = v;
  }
}

// ---------------- f32 -> bf16 convert ----------------
__global__ __launch_bounds__(256) void cvt_kernel(const float* __restrict__ src,
                                                  u16* __restrict__ dst) {
  int i = (blockIdx.x * 256 + threadIdx.x) * 4;
  float4 v = *(const float4*)(src + i);
  uint2 o;
  o.x = (u32)f2bf(v.x) | ((u32)f2bf(v.y) << 16);
  o.y = (u32)f2bf(v.z) | ((u32)f2bf(v.w) << 16);
  *(uint2*)(dst + i) = o;
}

// ---------------- road: x = relu(road @ Wd + bd), 65536 x (8->16) ----------------
__global__ __launch_bounds__(256) void r0_kernel(const float* __restrict__ road,
    const float* __restrict__ W, const float* __restrict__ bias, float* __restrict__ x) {
  int row = blockIdx.x * 256 + threadIdx.x;
  float in[8];
  float4 v0 = *(const float4*)(road + (size_t)row * 8);
  float4 v1 = *(const float4*)(road + (size_t)row * 8 + 4);
  in[0] = v0.x; in[1] = v0.y; in[2] = v0.z; in[3] = v0.w;
  in[4] = v1.x; in[5] = v1.y; in[6] = v1.z; in[7] = v1.w;
#pragma unroll
  for (int j = 0; j < 16; ++j) {
    float s = bias[j];
#pragma unroll
    for (int c = 0; c < 8; ++c) s += in[c] * W[c * 16 + j];
    x[(size_t)row * 16 + j] = fmaxf(s, 0.f);
  }
}

// ---------------- road favor pass1: accumulate kv_road/ksum_road ----------------
__global__ __launch_bounds__(256) void ra_kernel(const float* __restrict__ x,
    const float* __restrict__ qkvW, const float* __restrict__ qkvb,
    const float* __restrict__ Wk, const float* __restrict__ Wv,
    float* __restrict__ kvr, float* __restrict__ ksr) {
  int t = threadIdx.x;
  int row = blockIdx.x * 256 + t;
  int b = row >> 13;
  float xv[16];
#pragma unroll
  for (int e = 0; e < 16; ++e) xv[e] = x[(size_t)row * 16 + e];
  float q16[16];
#pragma unroll
  for (int j = 0; j < 16; ++j) {
    float s = qkvb[j];
#pragma unroll
    for (int c = 0; c < 16; ++c) s += xv[c] * qkvW[c * 48 + j];
    q16[j] = fmaxf(s, 0.f);
  }
  float kp[16], vh[16];
#pragma unroll
  for (int hm = 0; hm < 16; ++hm) {
    float sk = 0.f, sv = 0.f;
#pragma unroll
    for (int c = 0; c < 16; ++c) {
      float q = q16[c];
      sk += q * Wk[c * 16 + hm];
      sv += q * Wv[c * 16 + hm];
    }
    kp[hm] = fmaxf(sk * NORM_ROAD, 0.f) + STAB;
    vh[hm] = sv;
  }
  __shared__ float l[80];
  if (t < 80) l[t] = 0.f;
  __syncthreads();
#pragma unroll
  for (int h = 0; h < 4; ++h)
#pragma unroll
    for (int m = 0; m < 4; ++m) {
      float kpv = kp[h * 4 + m];
      atomicAdd(&l[64 + h * 4 + m], kpv);
#pragma unroll
      for (int d = 0; d < 4; ++d) atomicAdd(&l[h * 16 + m * 4 + d], kpv * vh[h * 4 + d]);
    }
  __syncthreads();
  if (t < 64) atomicAdd(&kvr[b * 64 + t], l[t]);
  else if (t < 80) atomicAdd(&ksr[b * 16 + (t - 64)], l[t]);
}

__device__ __forceinline__ void ln16(const float* tv, const float* g, const float* bb, float* o) {
  float m = 0.f;
#pragma unroll
  for (int e = 0; e < 16; ++e) m += tv[e];
  m *= (1.f / 16.f);
  float var = 0.f;
#pragma unroll
  for (int e = 0; e < 16; ++e) { float d = tv[e] - m; var += d * d; }
  var *= (1.f / 16.f);
  float rstd = rsqrtf(var + LN_EPS);
#pragma unroll
  for (int e = 0; e < 16; ++e) o[e] = (tv[e] - m) * rstd * g[e] + bb[e];
}

// ---------------- road favor pass2 + LN + fc + LN (in-place x update) ----------------
__global__ __launch_bounds__(256) void rb_kernel(float* __restrict__ x,
    const float* __restrict__ qkvW, const float* __restrict__ qkvb,
    const float* __restrict__ Wq, const float* __restrict__ Wo,
    const float* __restrict__ lng, const float* __restrict__ lnb,
    const float* __restrict__ fcW, const float* __restrict__ fcb,
    const float* __restrict__ kvr, const float* __restrict__ ksr) {
  int row = blockIdx.x * 256 + threadIdx.x;
  int b = row >> 13;
  float xv[16];
#pragma unroll
  for (int e = 0; e < 16; ++e) xv[e] = x[(size_t)row * 16 + e];
  float q16[16];
#pragma unroll
  for (int j = 0; j < 16; ++j) {
    float s = qkvb[j];
#pragma unroll
    for (int c = 0; c < 16; ++c) s += xv[c] * qkvW[c * 48 + j];
    q16[j] = fmaxf(s, 0.f);
  }
  float qp[16];
#pragma unroll
  for (int hm = 0; hm < 16; ++hm) {
    float s = 0.f;
#pragma unroll
    for (int c = 0; c < 16; ++c) s += q16[c] * Wq[c * 16 + hm];
    qp[hm] = fmaxf(s * NORM_ROAD, 0.f) + STAB;
  }
  float attn[16];
#pragma unroll
  for (int e = 0; e < 16; ++e) attn[e] = 0.f;
#pragma unroll
  for (int h = 0; h < 4; ++h) {
    float den = 0.f;
#pragma unroll
    for (int m = 0; m < 4; ++m) den += qp[h * 4 + m] * ksr[b * 16 + h * 4 + m];
    float od[4];
#pragma unroll
    for (int d = 0; d < 4; ++d) {
      float num = 0.f;
#pragma unroll
      for (int m = 0; m < 4; ++m) num += qp[h * 4 + m] * kvr[b * 64 + h * 16 + m * 4 + d];
      od[d] = num / den;
    }
#pragma unroll
    for (int d = 0; d < 4; ++d)
#pragma unroll
      for (int e = 0; e < 16; ++e) attn[e] += od[d] * Wo[(h * 4 + d) * 16 + e];
  }
  float tv[16], n[16], o2[16];
#pragma unroll
  for (int e = 0; e < 16; ++e) tv[e] = attn[e] + xv[e];
  ln16(tv, lng, lnb, n);
#pragma unroll
  for (int j = 0; j < 16; ++j) {
    float s = fcb[j];
#pragma unroll
    for (int e = 0; e < 16; ++e) s += n[e] * fcW[e * 16 + j];
    tv[j] = n[j] + fmaxf(s, 0.f);
  }
  ln16(tv, lng, lnb, o2);
#pragma unroll
  for (int e = 0; e < 16; ++e) x[(size_t)row * 16 + e] = o2[e];
}

// ---------------- rg_out = relu(x_road @ rg_out_W + b) -> bf16, 65536x1024 ----------------
__global__ __launch_bounds__(256) void rc_kernel(const float* __restrict__ x,
    const float* __restrict__ W, const float* __restrict__ bias, u16* __restrict__ out) {
  const int t = threadIdx.x;
  const int cg = t & 63, rg = t >> 6;
  const int c0 = blockIdx.x * 256 + cg * 4;
  const int r0 = blockIdx.y * 16;
  __shared__ float lx[256];
  lx[t] = x[(size_t)(r0 + (t >> 4)) * 16 + (t & 15)];
  __syncthreads();
  float4 wv[16];
#pragma unroll
  for (int c = 0; c < 16; ++c) wv[c] = *(const float4*)(W + (size_t)c * 1024 + c0);
  float4 bv = *(const float4*)(bias + c0);
#pragma unroll
  for (int k = 0; k < 4; ++k) {
    int rr = rg * 4 + k;
    float s0 = bv.x, s1 = bv.y, s2 = bv.z, s3 = bv.w;
#pragma unroll
    for (int c = 0; c < 16; ++c) {
      float xv = lx[rr * 16 + c];
      s0 += xv * wv[c].x; s1 += xv * wv[c].y; s2 += xv * wv[c].z; s3 += xv * wv[c].w;
    }
    uint2 o;
    o.x = (u32)f2bf(fmaxf(s0, 0.f)) | ((u32)f2bf(fmaxf(s1, 0.f)) << 16);
    o.y = (u32)f2bf(fmaxf(s2, 0.f)) | ((u32)f2bf(fmaxf(s3, 0.f)) << 16);
    *(uint2*)(out + (size_t)(r0 + rr) * 1024 + c0) = o;
  }
}

// ---------------- generic MFMA GEMM: C = act(A[MxK] @ BT[NxK]^T), 128x128 tile ----------------
// LDS staged via global_load_lds with XOR swizzle
__global__ __launch_bounds__(256) void gemm_kernel(
    const u16* __restrict__ A, const u16* __restrict__ BT, int K,
    float* __restrict__ outF, u16* __restrict__ outB,
    const float* __restrict__ bias, const float* __restrict__ resF, int resmod,
    float scale, int do_relu, float post) {
  const int n0 = blockIdx.x * 128, m0 = blockIdx.y * 128;
  const int t = threadIdx.x;
  const int wid = t >> 6, lane = t & 63, quad = lane >> 4, m16 = lane & 15;
  const int wm = wid >> 1, wn = wid & 1;
  const int lrr = lane >> 3;
  const int lcs = (((lane & 7) ^ lrr) * 8);
  const int sw = m16 & 7;
  __shared__ __align__(16) u16 smem[2 * 128 * 64];
  u16* Al = smem;
  u16* Bl = smem + 128 * 64;
  f4v acc[4][4];
#pragma unroll
  for (int i = 0; i < 4; ++i)
#pragma unroll
    for (int j = 0; j < 4; ++j) acc[i][j] = {0.f, 0.f, 0.f, 0.f};

  for (int kc = 0; kc < K; kc += 64) {
    __syncthreads();
#pragma unroll
    for (int j = 0; j < 4; ++j) {
      int rbase = wid * 32 + j * 8;
      ldsload16(Al + rbase * 64, A + (size_t)(m0 + rbase + lrr) * K + kc + lcs);
      ldsload16(Bl + rbase * 64, BT + (size_t)(n0 + rbase + lrr) * K + kc + lcs);
    }
    __syncthreads();
#pragma unroll
    for (int ko = 0; ko < 64; ko += 32) {
      int g0 = ko >> 3;
      s8v af[4], bfr[4];
#pragma unroll
      for (int tm = 0; tm < 4; ++tm)
        af[tm] = *(const s8v*)(Al + (wm * 64 + tm * 16 + m16) * 64 + ((g0 + quad) ^ sw) * 8);
#pragma unroll
      for (int tn = 0; tn < 4; ++tn)
        bfr[tn] = *(const s8v*)(Bl + (wn * 64 + tn * 16 + m16) * 64 + ((g0 + quad) ^ sw) * 8);
#pragma unroll
      for (int tm = 0; tm < 4; ++tm)
#pragma unroll
        for (int tn = 0; tn < 4; ++tn)
          acc[tm][tn] = mfma16(af[tm], bfr[tn], acc[tm][tn]);
    }
  }
#pragma unroll
  for (int tm = 0; tm < 4; ++tm)
#pragma unroll
    for (int tn = 0; tn < 4; ++tn)
#pragma unroll
      for (int r = 0; r < 4; ++r) {
        int row = m0 + wm * 64 + tm * 16 + quad * 4 + r;
        int col = n0 + wn * 64 + tn * 16 + m16;
        float v = acc[tm][tn][r] * scale;
        if (bias) v += bias[col];
        if (do_relu) v = fmaxf(v, 0.f);
        v += post;
        if (resF) v += resF[(size_t)(row % resmod) * 1024 + col];
        if (outF) outF[(size_t)row * 1024 + col] = v;
        if (outB) outB[(size_t)row * 1024 + col] = f2bf(v);
      }
}

// ---------------- fused K/V projection + kv/ksum accumulation, BOTH layers ----------------
// grid (64 s-tiles, 32 layer*head, 8 batches): blockIdx.x = mt keeps the XCD swizzle
// (consumers of one A-tile spaced by 64 ≡ 0 mod 8 -> same XCD L2). blockIdx.y: bit4 =
// layer, bits0-3 = head. Single dispatch for both layers (kv depends only on rgout).
__global__ __launch_bounds__(256) void kv_kernel(
    const u16* __restrict__ rgout,
    const u16* __restrict__ WkT0, const u16* __restrict__ WvT0,
    const u16* __restrict__ WkT1, const u16* __restrict__ WvT1,
    float* __restrict__ kv, float* __restrict__ ksum) {
  const int mt = blockIdx.x, h2 = blockIdx.y, b = blockIdx.z;
  const int lay = h2 >> 4, h = h2 & 15;
  const u16* __restrict__ WkT = lay ? WkT1 : WkT0;
  const u16* __restrict__ WvT = lay ? WvT1 : WvT0;
  kv += (size_t)lay * 524288;   // 8*16*64*64 floats per layer
  ksum += (size_t)lay * 8192;   // 8*16*64 floats per layer
  const int t = threadIdx.x;
  const int wid = t >> 6, lane = t & 63, quad = lane >> 4, m16 = lane & 15;
  const int wm = wid >> 1, wn = wid & 1;
  const int lrr = lane >> 3;
  const int lcs = (((lane & 7) ^ lrr) * 8);
  const int sw = m16 & 7;
  __shared__ __align__(16) u16 smem[2 * 128 * 72];
  u16* Al = smem;              // [128][64] swizzled
  u16* Bl = smem + 128 * 64;   // [128][64] swizzled
  const size_t abase = ((size_t)b * 8192 + (size_t)mt * 128) * 1024;
  f4v acc[4][4];
#pragma unroll
  for (int i = 0; i < 4; ++i)
#pragma unroll
    for (int j = 0; j < 4; ++j) acc[i][j] = {0.f, 0.f, 0.f, 0.f};

  for (int kc = 0; kc < 1024; kc += 64) {
    __syncthreads();
#pragma unroll
    for (int j = 0; j < 4; ++j) {
      int rbase = wid * 32 + j * 8;
      int r = rbase + lrr;
      ldsload16(Al + rbase * 64, rgout + abase + (size_t)r * 1024 + kc + lcs);
      const u16* bsrc = (r < 64) ? (WkT + (size_t)(h * 64 + r) * 1024)
                                 : (WvT + (size_t)(h * 64 + (r - 64)) * 1024);
      ldsload16(Bl + rbase * 64, bsrc + kc + lcs);
    }
    __syncthreads();
#pragma unroll
    for (int ko = 0; ko < 64; ko += 32) {
      int g0 = ko >> 3;
      s8v af[4], bfr[4];
#pragma unroll
      for (int tm = 0; tm < 4; ++tm)
        af[tm] = *(const s8v*)(Al + (wm * 64 + tm * 16 + m16) * 64 + ((g0 + quad) ^ sw) * 8);
#pragma unroll
      for (int tn = 0; tn < 4; ++tn)
        bfr[tn] = *(const s8v*)(Bl + (wn * 64 + tn * 16 + m16) * 64 + ((g0 + quad) ^ sw) * 8);
#pragma unroll
      for (int tm = 0; tm < 4; ++tm)
#pragma unroll
        for (int tn = 0; tn < 4; ++tn)
          acc[tm][tn] = mfma16(af[tm], bfr[tn], acc[tm][tn]);
    }
  }
  __syncthreads();
  // epilogue: kp = relu(k*norm)+stab (wn==0), v unchanged (wn==1); write transposed to LDS.
  // For fixed (tm,tn) the 4 acc regs are 4 CONSECUTIVE s-rows -> one packed b64 store.
  u16* KPT = smem;             // [64 m][136 s]
  u16* VT = smem + 64 * 136;   // [64 d][136 s]
  {
    u16* dst = wn ? VT : KPT;
    const int sbase = wm * 64 + quad * 4;
#pragma unroll
    for (int tm = 0; tm < 4; ++tm)
#pragma unroll
      for (int tn = 0; tn < 4; ++tn) {
        float v0 = acc[tm][tn][0], v1 = acc[tm][tn][1];
        float v2 = acc[tm][tn][2], v3 = acc[tm][tn][3];
        if (wn == 0) {
          v0 = fmaxf(v0 * NORM_OBJ, 0.f) + STAB;
          v1 = fmaxf(v1 * NORM_OBJ, 0.f) + STAB;
          v2 = fmaxf(v2 * NORM_OBJ, 0.f) + STAB;
          v3 = fmaxf(v3 * NORM_OBJ, 0.f) + STAB;
        }
        uint2 o;
        o.x = (u32)f2bf(v0) | ((u32)f2bf(v1) << 16);
        o.y = (u32)f2bf(v2) | ((u32)f2bf(v3) << 16);
        int feat = tn * 16 + m16;
        *(uint2*)(dst + feat * 136 + sbase + tm * 16) = o;
      }
  }
  __syncthreads();
  // ksum partial
  if (t < 64) {
    float s = 0.f;
#pragma unroll
    for (int i = 0; i < 128; i += 8) {
      uint4 v = *(const uint4*)(KPT + t * 136 + i);
      u32 a[4] = {v.x, v.y, v.z, v.w};
#pragma unroll
      for (int q = 0; q < 4; ++q) {
        s += __uint_as_float(a[q] << 16);
        s += __uint_as_float(a[q] & 0xffff0000u);
      }
    }
    atomicAdd(&ksum[(size_t)(b * 16 + h) * 64 + t], s);
  }
  // second GEMM: kv_partial[64 m][64 d] = sum_s kp[s][m] * v[s][d]  (K=128)
  f4v a2[4];
#pragma unroll
  for (int tn = 0; tn < 4; ++tn) a2[tn] = {0.f, 0.f, 0.f, 0.f};
#pragma unroll
  for (int ks = 0; ks < 128; ks += 32) {
    s8v af = *(const s8v*)(KPT + (wid * 16 + m16) * 136 + ks + quad * 8);
#pragma unroll
    for (int tn = 0; tn < 4; ++tn) {
      s8v bv = *(const s8v*)(VT + (tn * 16 + m16) * 136 + ks + quad * 8);
      a2[tn] = mfma16(af, bv, a2[tn]);
    }
  }
#pragma unroll
  for (int tn = 0; tn < 4; ++tn)
#pragma unroll
    for (int r = 0; r < 4; ++r) {
      int m = wid * 16 + quad * 4 + r;
      int d = tn * 16 + m16;
      atomicAdd(&kv[((size_t)(b * 16 + h) * 64 + m) * 64 + d], a2[tn][r]);
    }
}

// ---------------- obj favor: out = (qp @ kv) / (qp . ksum) per row/head ----------------
// grid (256 row-blocks, 4 head-groups)
__global__ __launch_bounds__(256) void q2_kernel(const u16* __restrict__ qp,
    const float* __restrict__ kv, const float* __restrict__ ks, u16* __restrict__ out) {
  int wid = threadIdx.x >> 6, lane = threadIdx.x & 63;
  int row = blockIdx.x * 4 + wid;
  int b = row >> 7;
  int h0 = blockIdx.y * 4;
  for (int h = h0; h < h0 + 4; ++h) {
    const float* kvp = kv + (size_t)((b * 16 + h) * 64) * 64;
    const float* ksp = ks + (size_t)(b * 16 + h) * 64;
    const u16* qpp = qp + (size_t)row * 1024 + h * 64;
    float num = 0.f, den = 0.f;
    for (int m = 0; m < 64; ++m) {
      float qv = bf2f(qpp[m]);
      num += qv * kvp[m * 64 + lane];
      den += qv * ksp[m];
    }
    out[(size_t)row * 1024 + h * 64 + lane] = f2bf(num / den);
  }
}

// ---------------- layernorm over 1024, one block per row ----------------
__global__ __launch_bounds__(256) void ln_kernel(const float* __restrict__ in,
    const float* __restrict__ g, const float* __restrict__ bb,
    float* __restrict__ outF, u16* __restrict__ outB) {
  int row = blockIdx.x, t = threadIdx.x;
  const float* x = in + (size_t)row * 1024;
  float v[4];
  float s = 0.f, ss = 0.f;
#pragma unroll
  for (int j = 0; j < 4; ++j) {
    v[j] = x[t + 256 * j];
    s += v[j];
    ss += v[j] * v[j];
  }
  __shared__ float rs[256], rss[256];
  rs[t] = s; rss[t] = ss;
  __syncthreads();
  for (int o = 128; o > 0; o >>= 1) {
    if (t < o) { rs[t] += rs[t + o]; rss[t] += rss[t + o]; }
    __syncthreads();
  }
  float mean = rs[0] * (1.f / 1024.f);
  float var = rss[0] * (1.f / 1024.f) - mean * mean;
  float rstd = rsqrtf(var + LN_EPS);
#pragma unroll
  for (int j = 0; j < 4; ++j) {
    int c = t + 256 * j;
    float o = (v[j] - mean) * rstd * g[c] + bb[c];
    if (outF) outF[(size_t)row * 1024 + c] = o;
    if (outB) outB[(size_t)row * 1024 + c] = f2bf(o);
  }
}

// ---------------- workspace layout (bytes) ----------------
static constexpr size_t MBy = 1048576;
static constexpr size_t OFF_XROAD = 0;                       // 4 MB f32 (65536x16)
static constexpr size_t OFF_RGOUT = 4 * MBy;                 // 128 MiB bf16 (65536x1024)
static constexpr size_t OFF_KVR = OFF_RGOUT + 128 * MBy;     // 2048 B
static constexpr size_t OFF_KSR = OFF_KVR + 2048;            // 512 B
static constexpr size_t OFF_KVO = OFF_KVR + 4096;            // 4 MB f32 (2 layers x 2MB)
static constexpr size_t OFF_KSO = OFF_KVO + 4 * MBy;         // 64 KB f32 (2 layers x 32KB)
static constexpr size_t OFF_WT = OFF_KSO + 65536;            // 21 MB bf16 transposed weights
static constexpr size_t OFF_XOBJ = OFF_WT + 21 * MBy;        // 4 MB f32
static constexpr size_t OFF_XOBJB = OFF_XOBJ + 4 * MBy;      // 2 MB bf16
static constexpr size_t OFF_QP = OFF_XOBJB + 2 * MBy;        // 2 MB bf16
static constexpr size_t OFF_FOUT = OFF_QP + 2 * MBy;         // 2 MB bf16
static constexpr size_t OFF_T1 = OFF_FOUT + 2 * MBy;         // 4 MB f32
static constexpr size_t OFF_N = OFF_T1 + 4 * MBy;            // 4 MB f32
static constexpr size_t OFF_NB = OFF_N + 4 * MBy;            // 2 MB bf16
static constexpr size_t OFF_OBJB = OFF_NB + 2 * MBy;         // 1 MB bf16 (1024x512)

extern "C" void kernel_launch(void* const* d_in, const int* in_sizes, int n_in,
                              void* d_out, int out_size, void* d_ws, size_t ws_size,
                              hipStream_t stream) {
  (void)in_sizes; (void)n_in; (void)out_size; (void)ws_size;
  const float* obj = (const float*)d_in[0];
  const float* road = (const float*)d_in[1];
  const float* rgdW = (const float*)d_in[2];
  const float* rgdb = (const float*)d_in[3];
  const float* qkvW = (const float*)d_in[4];
  const float* qkvb = (const float*)d_in[5];
  const float* rgWq = (const float*)d_in[6];
  const float* rgWk = (const float*)d_in[7];
  const float* rgWv = (const float*)d_in[8];
  const float* rgWo = (const float*)d_in[9];
  const float* rglng = (const float*)d_in[10];
  const float* rglnb = (const float*)d_in[11];
  const float* rgfcW = (const float*)d_in[12];
  const float* rgfcb = (const float*)d_in[13];
  const float* rgoW = (const float*)d_in[14];
  const float* rgob = (const float*)d_in[15];
  const float* denW = (const float*)d_in[16];
  const float* denb = (const float*)d_in[17];
  const float* pose = (const float*)d_in[18];
  const float* Wq = (const float*)d_in[19];
  const float* Wk = (const float*)d_in[20];
  const float* Wv = (const float*)d_in[21];
  const float* Wo = (const float*)d_in[22];
  const float* lng = (const float*)d_in[23];
  const float* lnb = (const float*)d_in[24];
  const float* fcW = (const float*)d_in[25];
  const float* fcb = (const float*)d_in[26];

  char* w = (char*)d_ws;
  float* xroad = (float*)(w + OFF_XROAD);
  u16* rgout = (u16*)(w + OFF_RGOUT);
  float* kvr = (float*)(w + OFF_KVR);
  float* ksr = (float*)(w + OFF_KSR);
  float* kvo = (float*)(w + OFF_KVO);
  float* kso = (float*)(w + OFF_KSO);
  u16* wt = (u16*)(w + OFF_WT);
  float* xobj = (float*)(w + OFF_XOBJ);
  u16* xobjb = (u16*)(w + OFF_XOBJB);
  u16* qpB = (u16*)(w + OFF_QP);
  u16* fout = (u16*)(w + OFF_FOUT);
  float* t1 = (float*)(w + OFF_T1);
  float* nF = (float*)(w + OFF_N);
  u16* nB = (u16*)(w + OFF_NB);
  u16* objb = (u16*)(w + OFF_OBJB);

  const size_t E = 1048576;  // elems of a 1024x1024 matrix
  u16* wqT[2] = {wt + 0 * E, wt + 1 * E};
  u16* wkT[2] = {wt + 2 * E, wt + 3 * E};
  u16* wvT[2] = {wt + 4 * E, wt + 5 * E};
  u16* woT[2] = {wt + 6 * E, wt + 7 * E};
  u16* fcT[2] = {wt + 8 * E, wt + 9 * E};
  u16* denT = wt + 10 * E;

  // one-time weight transposes+convert (f32 K x N -> bf16 N x K)
  TP11 tb;
  const float* srcs[10] = {Wq, Wq + E, Wk, Wk + E, Wv, Wv + E, Wo, Wo + E, fcW, fcW + E};
  u16* dsts[10] = {wqT[0], wqT[1], wkT[0], wkT[1], wvT[0], wvT[1], woT[0], woT[1], fcT[0], fcT[1]};
  for (int j = 0; j < 11; ++j) { tb.p[j].s = srcs[j < 10 ? j : 0]; tb.p[j].d = dsts[j < 10 ? j : 0]; }
  transpose_kernel<<<dim3(16, 16, 10), 256, 0, stream>>>(tb, 1024, 1024);
  TP11 td;
  for (int j = 0; j < 11; ++j) { td.p[j].s = denW; td.p[j].d = denT; }
  transpose_kernel<<<dim3(16, 8, 1), 256, 0, stream>>>(td, 512, 1024);
  // obj f32 -> bf16 (1024x512 = 524288 elems)
  cvt_kernel<<<dim3(512), 256, 0, stream>>>(obj, objb);

  // road-graph encoder
  r0_kernel<<<dim3(256), 256, 0, stream>>>(road, rgdW, rgdb, xroad);
  for (int i = 0; i < 2; ++i) {
    hipMemsetAsync(w + OFF_KVR, 0, 2560, stream);
    ra_kernel<<<dim3(256), 256, 0, stream>>>(xroad, qkvW, qkvb, rgWk + i * 256, rgWv + i * 256,
                                             kvr, ksr);
    rb_kernel<<<dim3(256), 256, 0, stream>>>(xroad, qkvW, qkvb, rgWq + i * 256, rgWo + i * 256,
                                             rglng + i * 16, rglnb + i * 16, rgfcW + i * 256,
                                             rgfcb + i * 16, kvr, ksr);
  }
  rc_kernel<<<dim3(4, 4096), 256, 0, stream>>>(xroad, rgoW, rgob, rgout);

  // both layers' kv/ksum in one dispatch (depends only on rgout + weights)
  hipMemsetAsync(w + OFF_KVO, 0, 4 * MBy + 65536, stream);
  kv_kernel<<<dim3(64, 32, 8), 256, 0, stream>>>(rgout, wkT[0], wvT[0], wkT[1], wvT[1], kvo, kso);

  // object encoder init: x = relu(obj @ dense_W + b) + pos_emb
  gemm_kernel<<<dim3(8, 8), 256, 0, stream>>>(objb, denT, 512, xobj, xobjb, denb, pose, 128,
                                              1.f, 1, 0.f);

  for (int i = 0; i < 2; ++i) {
    gemm_kernel<<<dim3(8, 8), 256, 0, stream>>>(xobjb, wqT[i], 1024, nullptr, qpB, nullptr,
                                                nullptr, 1024, NORM_OBJ, 1, STAB);
    q2_kernel<<<dim3(256, 4), 256, 0, stream>>>(qpB, kvo + (size_t)i * 524288,
                                                kso + (size_t)i * 8192, fout);
    gemm_kernel<<<dim3(8, 8), 256, 0, stream>>>(fout, woT[i], 1024, t1, nullptr, nullptr, xobj,
                                                1024, 1.f, 0, 0.f);
    ln_kernel<<<dim3(1024), 256, 0, stream>>>(t1, lng + i * 1024, lnb + i * 1024, nF, nB);
    gemm_kernel<<<dim3(8, 8), 256, 0, stream>>>(nB, fcT[i], 1024, t1, nullptr, fcb + i * 1024, nF,
                                                1024, 1.f, 1, 0.f);
    if (i == 0)
      ln_kernel<<<dim3(1024), 256, 0, stream>>>(t1, lng, lnb, xobj, xobjb);
    else
      ln_kernel<<<dim3(1024), 256, 0, stream>>>(t1, lng + 1024, lnb + 1024, (float*)d_out, nullptr);
  }
}

// Round 10
// 1483.830 us; speedup vs baseline: 1.5973x; 1.1243x over previous
//
#include <hip/hip_runtime.h>

typedef unsigned short u16;
typedef unsigned int u32;

using s8v = __attribute__((ext_vector_type(8))) short;  // 8 bf16
using f4v = __attribute__((ext_vector_type(4))) float;  // 4 fp32

#define LN_EPS 0.001f
#define STAB 0.001f
#define NORM_OBJ 0.35355339059327373f   // 64^-0.25
#define NORM_ROAD 0.7071067811865476f   // 4^-0.25

__device__ __forceinline__ float bf2f(u16 v) { return __uint_as_float(((u32)v) << 16); }
__device__ __forceinline__ u16 f2bf(float f) {
  u32 u = __float_as_uint(f);
  u32 r = (u + 0x7fffu + ((u >> 16) & 1u)) >> 16;
  return (u16)r;
}
__device__ __forceinline__ f4v mfma16(s8v a, s8v b, f4v c) {
  return __builtin_amdgcn_mfma_f32_16x16x32_bf16(a, b, c, 0, 0, 0);
}
// async global->LDS, 16 B/lane; LDS dest = wave-uniform base + lane*16
__device__ __forceinline__ void ldsload16(void* lds, const void* g) {
  __builtin_amdgcn_global_load_lds((const __attribute__((address_space(1))) u32*)g,
                                   (__attribute__((address_space(3))) u32*)lds, 16, 0, 0);
}

// ---------------- transpose+convert: src[K][N] f32 -> dst[N][K] bf16 ----------------
struct TPair { const float* s; u16* d; };
struct TP11 { TPair p[11]; };

__global__ __launch_bounds__(256) void transpose_kernel(TP11 ps, int K, int N) {
  const float* __restrict__ src = ps.p[blockIdx.z].s;
  u16* __restrict__ dst = ps.p[blockIdx.z].d;
  int n0 = blockIdx.x * 64, k0 = blockIdx.y * 64;
  int t = threadIdx.x;
  __shared__ __align__(16) u16 lt[64 * 72];
#pragma unroll
  for (int j = 0; j < 4; ++j) {
    int p = t + 256 * j;
    int r = p >> 4, cb = p & 15;
    float4 v = *(const float4*)(src + (size_t)(k0 + r) * N + n0 + cb * 4);
    lt[r * 72 + cb * 4 + 0] = f2bf(v.x);
    lt[r * 72 + cb * 4 + 1] = f2bf(v.y);
    lt[r * 72 + cb * 4 + 2] = f2bf(v.z);
    lt[r * 72 + cb * 4 + 3] = f2bf(v.w);
  }
  __syncthreads();
#pragma unroll
  for (int j = 0; j < 2; ++j) {
    int q = t + 256 * j;
    int on = q >> 3, ocb = q & 7;
    u16 e[8];
#pragma unroll
    for (int i = 0; i < 8; ++i) e[i] = lt[(ocb * 8 + i) * 72 + on];
    uint4 v;
    v.x = (u32)e[0] | ((u32)e[1] << 16);
    v.y = (u32)e[2] | ((u32)e[3] << 16);
    v.z = (u32)e[4] | ((u32)e[5] << 16);
    v.w = (u32)e[6] | ((u32)e[7] << 16);
    *(uint4*)(dst + (size_t)(n0 + on) * K + k0 + ocb * 8) = v;
  }
}

// ---------------- f32 -> bf16 convert ----------------
__global__ __launch_bounds__(256) void cvt_kernel(const float* __restrict__ src,
                                                  u16* __restrict__ dst) {
  int i = (blockIdx.x * 256 + threadIdx.x) * 4;
  float4 v = *(const float4*)(src + i);
  uint2 o;
  o.x = (u32)f2bf(v.x) | ((u32)f2bf(v.y) << 16);
  o.y = (u32)f2bf(v.z) | ((u32)f2bf(v.w) << 16);
  *(uint2*)(dst + i) = o;
}

// ---------------- road: x = relu(road @ Wd + bd), 65536 x (8->16) ----------------
__global__ __launch_bounds__(256) void r0_kernel(const float* __restrict__ road,
    const float* __restrict__ W, const float* __restrict__ bias, float* __restrict__ x) {
  int row = blockIdx.x * 256 + threadIdx.x;
  float in[8];
  float4 v0 = *(const float4*)(road + (size_t)row * 8);
  float4 v1 = *(const float4*)(road + (size_t)row * 8 + 4);
  in[0] = v0.x; in[1] = v0.y; in[2] = v0.z; in[3] = v0.w;
  in[4] = v1.x; in[5] = v1.y; in[6] = v1.z; in[7] = v1.w;
#pragma unroll
  for (int j = 0; j < 16; ++j) {
    float s = bias[j];
#pragma unroll
    for (int c = 0; c < 8; ++c) s += in[c] * W[c * 16 + j];
    x[(size_t)row * 16 + j] = fmaxf(s, 0.f);
  }
}

// ---------------- road favor pass1: accumulate kv_road/ksum_road ----------------
__global__ __launch_bounds__(256) void ra_kernel(const float* __restrict__ x,
    const float* __restrict__ qkvW, const float* __restrict__ qkvb,
    const float* __restrict__ Wk, const float* __restrict__ Wv,
    float* __restrict__ kvr, float* __restrict__ ksr) {
  int t = threadIdx.x;
  int row = blockIdx.x * 256 + t;
  int b = row >> 13;
  float xv[16];
#pragma unroll
  for (int e = 0; e < 16; ++e) xv[e] = x[(size_t)row * 16 + e];
  float q16[16];
#pragma unroll
  for (int j = 0; j < 16; ++j) {
    float s = qkvb[j];
#pragma unroll
    for (int c = 0; c < 16; ++c) s += xv[c] * qkvW[c * 48 + j];
    q16[j] = fmaxf(s, 0.f);
  }
  float kp[16], vh[16];
#pragma unroll
  for (int hm = 0; hm < 16; ++hm) {
    float sk = 0.f, sv = 0.f;
#pragma unroll
    for (int c = 0; c < 16; ++c) {
      float q = q16[c];
      sk += q * Wk[c * 16 + hm];
      sv += q * Wv[c * 16 + hm];
    }
    kp[hm] = fmaxf(sk * NORM_ROAD, 0.f) + STAB;
    vh[hm] = sv;
  }
  __shared__ float l[80];
  if (t < 80) l[t] = 0.f;
  __syncthreads();
#pragma unroll
  for (int h = 0; h < 4; ++h)
#pragma unroll
    for (int m = 0; m < 4; ++m) {
      float kpv = kp[h * 4 + m];
      atomicAdd(&l[64 + h * 4 + m], kpv);
#pragma unroll
      for (int d = 0; d < 4; ++d) atomicAdd(&l[h * 16 + m * 4 + d], kpv * vh[h * 4 + d]);
    }
  __syncthreads();
  if (t < 64) atomicAdd(&kvr[b * 64 + t], l[t]);
  else if (t < 80) atomicAdd(&ksr[b * 16 + (t - 64)], l[t]);
}

__device__ __forceinline__ void ln16(const float* tv, const float* g, const float* bb, float* o) {
  float m = 0.f;
#pragma unroll
  for (int e = 0; e < 16; ++e) m += tv[e];
  m *= (1.f / 16.f);
  float var = 0.f;
#pragma unroll
  for (int e = 0; e < 16; ++e) { float d = tv[e] - m; var += d * d; }
  var *= (1.f / 16.f);
  float rstd = rsqrtf(var + LN_EPS);
#pragma unroll
  for (int e = 0; e < 16; ++e) o[e] = (tv[e] - m) * rstd * g[e] + bb[e];
}

// ---------------- road favor pass2 + LN + fc + LN (in-place x update) ----------------
__global__ __launch_bounds__(256) void rb_kernel(float* __restrict__ x,
    const float* __restrict__ qkvW, const float* __restrict__ qkvb,
    const float* __restrict__ Wq, const float* __restrict__ Wo,
    const float* __restrict__ lng, const float* __restrict__ lnb,
    const float* __restrict__ fcW, const float* __restrict__ fcb,
    const float* __restrict__ kvr, const float* __restrict__ ksr) {
  int row = blockIdx.x * 256 + threadIdx.x;
  int b = row >> 13;
  float xv[16];
#pragma unroll
  for (int e = 0; e < 16; ++e) xv[e] = x[(size_t)row * 16 + e];
  float q16[16];
#pragma unroll
  for (int j = 0; j < 16; ++j) {
    float s = qkvb[j];
#pragma unroll
    for (int c = 0; c < 16; ++c) s += xv[c] * qkvW[c * 48 + j];
    q16[j] = fmaxf(s, 0.f);
  }
  float qp[16];
#pragma unroll
  for (int hm = 0; hm < 16; ++hm) {
    float s = 0.f;
#pragma unroll
    for (int c = 0; c < 16; ++c) s += q16[c] * Wq[c * 16 + hm];
    qp[hm] = fmaxf(s * NORM_ROAD, 0.f) + STAB;
  }
  float attn[16];
#pragma unroll
  for (int e = 0; e < 16; ++e) attn[e] = 0.f;
#pragma unroll
  for (int h = 0; h < 4; ++h) {
    float den = 0.f;
#pragma unroll
    for (int m = 0; m < 4; ++m) den += qp[h * 4 + m] * ksr[b * 16 + h * 4 + m];
    float od[4];
#pragma unroll
    for (int d = 0; d < 4; ++d) {
      float num = 0.f;
#pragma unroll
      for (int m = 0; m < 4; ++m) num += qp[h * 4 + m] * kvr[b * 64 + h * 16 + m * 4 + d];
      od[d] = num / den;
    }
#pragma unroll
    for (int d = 0; d < 4; ++d)
#pragma unroll
      for (int e = 0; e < 16; ++e) attn[e] += od[d] * Wo[(h * 4 + d) * 16 + e];
  }
  float tv[16], n[16], o2[16];
#pragma unroll
  for (int e = 0; e < 16; ++e) tv[e] = attn[e] + xv[e];
  ln16(tv, lng, lnb, n);
#pragma unroll
  for (int j = 0; j < 16; ++j) {
    float s = fcb[j];
#pragma unroll
    for (int e = 0; e < 16; ++e) s += n[e] * fcW[e * 16 + j];
    tv[j] = n[j] + fmaxf(s, 0.f);
  }
  ln16(tv, lng, lnb, o2);
#pragma unroll
  for (int e = 0; e < 16; ++e) x[(size_t)row * 16 + e] = o2[e];
}

// ---------------- rg_out = relu(x_road @ rg_out_W + b) -> bf16, 65536x1024 ----------------
__global__ __launch_bounds__(256) void rc_kernel(const float* __restrict__ x,
    const float* __restrict__ W, const float* __restrict__ bias, u16* __restrict__ out) {
  const int t = threadIdx.x;
  const int cg = t & 63, rg = t >> 6;
  const int c0 = blockIdx.x * 256 + cg * 4;
  const int r0 = blockIdx.y * 16;
  __shared__ float lx[256];
  lx[t] = x[(size_t)(r0 + (t >> 4)) * 16 + (t & 15)];
  __syncthreads();
  float4 wv[16];
#pragma unroll
  for (int c = 0; c < 16; ++c) wv[c] = *(const float4*)(W + (size_t)c * 1024 + c0);
  float4 bv = *(const float4*)(bias + c0);
#pragma unroll
  for (int k = 0; k < 4; ++k) {
    int rr = rg * 4 + k;
    float s0 = bv.x, s1 = bv.y, s2 = bv.z, s3 = bv.w;
#pragma unroll
    for (int c = 0; c < 16; ++c) {
      float xv = lx[rr * 16 + c];
      s0 += xv * wv[c].x; s1 += xv * wv[c].y; s2 += xv * wv[c].z; s3 += xv * wv[c].w;
    }
    uint2 o;
    o.x = (u32)f2bf(fmaxf(s0, 0.f)) | ((u32)f2bf(fmaxf(s1, 0.f)) << 16);
    o.y = (u32)f2bf(fmaxf(s2, 0.f)) | ((u32)f2bf(fmaxf(s3, 0.f)) << 16);
    *(uint2*)(out + (size_t)(r0 + rr) * 1024 + c0) = o;
  }
}

// ---------------- generic MFMA GEMM: C = act(A[MxK] @ BT[NxK]^T), 128x128 tile ----------------
// LDS staged via global_load_lds with XOR swizzle
__global__ __launch_bounds__(256) void gemm_kernel(
    const u16* __restrict__ A, const u16* __restrict__ BT, int K,
    float* __restrict__ outF, u16* __restrict__ outB,
    const float* __restrict__ bias, const float* __restrict__ resF, int resmod,
    float scale, int do_relu, float post) {
  const int n0 = blockIdx.x * 128, m0 = blockIdx.y * 128;
  const int t = threadIdx.x;
  const int wid = t >> 6, lane = t & 63, quad = lane >> 4, m16 = lane & 15;
  const int wm = wid >> 1, wn = wid & 1;
  const int lrr = lane >> 3;
  const int lcs = (((lane & 7) ^ lrr) * 8);
  const int sw = m16 & 7;
  __shared__ __align__(16) u16 smem[2 * 128 * 64];
  u16* Al = smem;
  u16* Bl = smem + 128 * 64;
  f4v acc[4][4];
#pragma unroll
  for (int i = 0; i < 4; ++i)
#pragma unroll
    for (int j = 0; j < 4; ++j) acc[i][j] = {0.f, 0.f, 0.f, 0.f};

  for (int kc = 0; kc < K; kc += 64) {
    __syncthreads();
#pragma unroll
    for (int j = 0; j < 4; ++j) {
      int rbase = wid * 32 + j * 8;
      ldsload16(Al + rbase * 64, A + (size_t)(m0 + rbase + lrr) * K + kc + lcs);
      ldsload16(Bl + rbase * 64, BT + (size_t)(n0 + rbase + lrr) * K + kc + lcs);
    }
    __syncthreads();
#pragma unroll
    for (int ko = 0; ko < 64; ko += 32) {
      int g0 = ko >> 3;
      s8v af[4], bfr[4];
#pragma unroll
      for (int tm = 0; tm < 4; ++tm)
        af[tm] = *(const s8v*)(Al + (wm * 64 + tm * 16 + m16) * 64 + ((g0 + quad) ^ sw) * 8);
#pragma unroll
      for (int tn = 0; tn < 4; ++tn)
        bfr[tn] = *(const s8v*)(Bl + (wn * 64 + tn * 16 + m16) * 64 + ((g0 + quad) ^ sw) * 8);
#pragma unroll
      for (int tm = 0; tm < 4; ++tm)
#pragma unroll
        for (int tn = 0; tn < 4; ++tn)
          acc[tm][tn] = mfma16(af[tm], bfr[tn], acc[tm][tn]);
    }
  }
#pragma unroll
  for (int tm = 0; tm < 4; ++tm)
#pragma unroll
    for (int tn = 0; tn < 4; ++tn)
#pragma unroll
      for (int r = 0; r < 4; ++r) {
        int row = m0 + wm * 64 + tm * 16 + quad * 4 + r;
        int col = n0 + wn * 64 + tn * 16 + m16;
        float v = acc[tm][tn][r] * scale;
        if (bias) v += bias[col];
        if (do_relu) v = fmaxf(v, 0.f);
        v += post;
        if (resF) v += resF[(size_t)(row % resmod) * 1024 + col];
        if (outF) outF[(size_t)row * 1024 + col] = v;
        if (outB) outB[(size_t)row * 1024 + col] = f2bf(v);
      }
}

// ---------------- fused K/V projection + kv/ksum accumulation, BOTH layers ----------------
// 512 threads (8 waves), tile 128 s-rows x 256 cols = 2 heads x (64k|64v).
// grid (64 s-tiles, 16 lay*headpair, 8 batches): blockIdx.x = mt keeps the XCD swizzle
// (consumers of one A-tile spaced by 64 ≡ 0 mod 8 -> same XCD L2). A staged once per 2 heads.
__global__ __launch_bounds__(512) void kv_kernel(
    const u16* __restrict__ rgout,
    const u16* __restrict__ WkT0, const u16* __restrict__ WvT0,
    const u16* __restrict__ WkT1, const u16* __restrict__ WvT1,
    float* __restrict__ kv, float* __restrict__ ksum) {
  const int mt = blockIdx.x, y = blockIdx.y, b = blockIdx.z;
  const int lay = y >> 3, hp = y & 7;
  const u16* __restrict__ WkT = lay ? WkT1 : WkT0;
  const u16* __restrict__ WvT = lay ? WvT1 : WvT0;
  kv += (size_t)lay * 524288;   // 8*16*64*64 floats per layer
  ksum += (size_t)lay * 8192;   // 8*16*64 floats per layer
  const int t = threadIdx.x;
  const int wid = t >> 6, lane = t & 63, quad = lane >> 4, m16 = lane & 15;
  const int wm = wid >> 2, wn = wid & 3;   // 2 x 4 wave grid over 128 x 256 tile
  const int lrr = lane >> 3;
  const int lcs = (((lane & 7) ^ lrr) * 8);
  const int sw = m16 & 7;
  const int HSZ = 64 * 136;
  __shared__ __align__(16) u16 smem[4 * 64 * 136];  // 69632 B; main loop uses 49152 B
  u16* Al = smem;               // [128][64] swizzled
  u16* Bl = smem + 128 * 64;    // [256][64] swizzled
  const size_t abase = ((size_t)b * 8192 + (size_t)mt * 128) * 1024;
  f4v acc[4][4];
#pragma unroll
  for (int i = 0; i < 4; ++i)
#pragma unroll
    for (int j = 0; j < 4; ++j) acc[i][j] = {0.f, 0.f, 0.f, 0.f};

  for (int kc = 0; kc < 1024; kc += 64) {
    __syncthreads();
#pragma unroll
    for (int j = 0; j < 2; ++j) {
      int rbase = wid * 16 + j * 8;
      ldsload16(Al + rbase * 64, rgout + abase + (size_t)(rbase + lrr) * 1024 + kc + lcs);
    }
#pragma unroll
    for (int j = 0; j < 4; ++j) {
      int rbase = wid * 32 + j * 8;
      int r = rbase + lrr;
      int h = hp * 2 + (r >> 7), rr = r & 127;
      const u16* bsrc = (rr < 64) ? (WkT + (size_t)(h * 64 + rr) * 1024)
                                  : (WvT + (size_t)(h * 64 + (rr - 64)) * 1024);
      ldsload16(Bl + rbase * 64, bsrc + kc + lcs);
    }
    __syncthreads();
#pragma unroll
    for (int ko = 0; ko < 64; ko += 32) {
      int g0 = ko >> 3;
      s8v af[4], bfr[4];
#pragma unroll
      for (int tm = 0; tm < 4; ++tm)
        af[tm] = *(const s8v*)(Al + (wm * 64 + tm * 16 + m16) * 64 + ((g0 + quad) ^ sw) * 8);
#pragma unroll
      for (int tn = 0; tn < 4; ++tn)
        bfr[tn] = *(const s8v*)(Bl + (wn * 64 + tn * 16 + m16) * 64 + ((g0 + quad) ^ sw) * 8);
#pragma unroll
      for (int tm = 0; tm < 4; ++tm)
#pragma unroll
        for (int tn = 0; tn < 4; ++tn)
          acc[tm][tn] = mfma16(af[tm], bfr[tn], acc[tm][tn]);
    }
  }
  __syncthreads();
  // epilogue: wave wn -> head hh = wn>>1, (wn&1)==0 -> kp (relu*norm+stab) else v.
  // For fixed (tm,tn) the 4 acc regs are 4 CONSECUTIVE s-rows -> one packed b64 store.
  {
    int hh = wn >> 1;
    u16* dst = smem + (size_t)(hh * 2 + (wn & 1)) * HSZ;  // [64 feat][136 s]
    const int iskp = (wn & 1) == 0;
    const int sbase = wm * 64 + quad * 4;
#pragma unroll
    for (int tm = 0; tm < 4; ++tm)
#pragma unroll
      for (int tn = 0; tn < 4; ++tn) {
        float v0 = acc[tm][tn][0], v1 = acc[tm][tn][1];
        float v2 = acc[tm][tn][2], v3 = acc[tm][tn][3];
        if (iskp) {
          v0 = fmaxf(v0 * NORM_OBJ, 0.f) + STAB;
          v1 = fmaxf(v1 * NORM_OBJ, 0.f) + STAB;
          v2 = fmaxf(v2 * NORM_OBJ, 0.f) + STAB;
          v3 = fmaxf(v3 * NORM_OBJ, 0.f) + STAB;
        }
        uint2 o;
        o.x = (u32)f2bf(v0) | ((u32)f2bf(v1) << 16);
        o.y = (u32)f2bf(v2) | ((u32)f2bf(v3) << 16);
        int feat = tn * 16 + m16;
        *(uint2*)(dst + feat * 136 + sbase + tm * 16) = o;
      }
  }
  __syncthreads();
  // ksum partials: threads 0..127: head = t>>6, m = t&63
  if (t < 128) {
    int hh = t >> 6, m = t & 63;
    const u16* base = smem + (size_t)(hh * 2) * HSZ + m * 136;
    float s = 0.f;
#pragma unroll
    for (int i = 0; i < 128; i += 8) {
      uint4 v = *(const uint4*)(base + i);
      u32 a[4] = {v.x, v.y, v.z, v.w};
#pragma unroll
      for (int q = 0; q < 4; ++q) {
        s += __uint_as_float(a[q] << 16);
        s += __uint_as_float(a[q] & 0xffff0000u);
      }
    }
    atomicAdd(&ksum[(size_t)(b * 16 + hp * 2 + hh) * 64 + m], s);
  }
  // second GEMM: per head kv_partial[64 m][64 d] = sum_s kp[s][m]*v[s][d], K=128.
  // 8 waves: head hh = wid>>2, m-rows (wid&3)*16..+15
  {
    int hh = wid >> 2, mq = wid & 3;
    const u16* KPh = smem + (size_t)(hh * 2) * HSZ;
    const u16* Vh = KPh + HSZ;
    f4v a2[4];
#pragma unroll
    for (int tn = 0; tn < 4; ++tn) a2[tn] = {0.f, 0.f, 0.f, 0.f};
#pragma unroll
    for (int ks = 0; ks < 128; ks += 32) {
      s8v af = *(const s8v*)(KPh + (mq * 16 + m16) * 136 + ks + quad * 8);
#pragma unroll
      for (int tn = 0; tn < 4; ++tn) {
        s8v bv = *(const s8v*)(Vh + (tn * 16 + m16) * 136 + ks + quad * 8);
        a2[tn] = mfma16(af, bv, a2[tn]);
      }
    }
    int h = hp * 2 + hh;
#pragma unroll
    for (int tn = 0; tn < 4; ++tn)
#pragma unroll
      for (int r = 0; r < 4; ++r) {
        int m = mq * 16 + quad * 4 + r;
        int d = tn * 16 + m16;
        atomicAdd(&kv[((size_t)(b * 16 + h) * 64 + m) * 64 + d], a2[tn][r]);
      }
  }
}

// ---------------- obj favor: out = (qp @ kv) / (qp . ksum) per row/head ----------------
// grid (256 row-blocks, 4 head-groups)
__global__ __launch_bounds__(256) void q2_kernel(const u16* __restrict__ qp,
    const float* __restrict__ kv, const float* __restrict__ ks, u16* __restrict__ out) {
  int wid = threadIdx.x >> 6, lane = threadIdx.x & 63;
  int row = blockIdx.x * 4 + wid;
  int b = row >> 7;
  int h0 = blockIdx.y * 4;
  for (int h = h0; h < h0 + 4; ++h) {
    const float* kvp = kv + (size_t)((b * 16 + h) * 64) * 64;
    const float* ksp = ks + (size_t)(b * 16 + h) * 64;
    const u16* qpp = qp + (size_t)row * 1024 + h * 64;
    float num = 0.f, den = 0.f;
    for (int m = 0; m < 64; ++m) {
      float qv = bf2f(qpp[m]);
      num += qv * kvp[m * 64 + lane];
      den += qv * ksp[m];
    }
    out[(size_t)row * 1024 + h * 64 + lane] = f2bf(num / den);
  }
}

// ---------------- layernorm over 1024, one block per row ----------------
__global__ __launch_bounds__(256) void ln_kernel(const float* __restrict__ in,
    const float* __restrict__ g, const float* __restrict__ bb,
    float* __restrict__ outF, u16* __restrict__ outB) {
  int row = blockIdx.x, t = threadIdx.x;
  const float* x = in + (size_t)row * 1024;
  float v[4];
  float s = 0.f, ss = 0.f;
#pragma unroll
  for (int j = 0; j < 4; ++j) {
    v[j] = x[t + 256 * j];
    s += v[j];
    ss += v[j] * v[j];
  }
  __shared__ float rs[256], rss[256];
  rs[t] = s; rss[t] = ss;
  __syncthreads();
  for (int o = 128; o > 0; o >>= 1) {
    if (t < o) { rs[t] += rs[t + o]; rss[t] += rss[t + o]; }
    __syncthreads();
  }
  float mean = rs[0] * (1.f / 1024.f);
  float var = rss[0] * (1.f / 1024.f) - mean * mean;
  float rstd = rsqrtf(var + LN_EPS);
#pragma unroll
  for (int j = 0; j < 4; ++j) {
    int c = t + 256 * j;
    float o = (v[j] - mean) * rstd * g[c] + bb[c];
    if (outF) outF[(size_t)row * 1024 + c] = o;
    if (outB) outB[(size_t)row * 1024 + c] = f2bf(o);
  }
}

// ---------------- workspace layout (bytes) ----------------
static constexpr size_t MBy = 1048576;
static constexpr size_t OFF_XROAD = 0;                       // 4 MB f32 (65536x16)
static constexpr size_t OFF_RGOUT = 4 * MBy;                 // 128 MiB bf16 (65536x1024)
static constexpr size_t OFF_KVR = OFF_RGOUT + 128 * MBy;     // 2048 B
static constexpr size_t OFF_KSR = OFF_KVR + 2048;            // 512 B
static constexpr size_t OFF_KVO = OFF_KVR + 4096;            // 4 MB f32 (2 layers x 2MB)
static constexpr size_t OFF_KSO = OFF_KVO + 4 * MBy;         // 64 KB f32 (2 layers x 32KB)
static constexpr size_t OFF_WT = OFF_KSO + 65536;            // 21 MB bf16 transposed weights
static constexpr size_t OFF_XOBJ = OFF_WT + 21 * MBy;        // 4 MB f32
static constexpr size_t OFF_XOBJB = OFF_XOBJ + 4 * MBy;      // 2 MB bf16
static constexpr size_t OFF_QP = OFF_XOBJB + 2 * MBy;        // 2 MB bf16
static constexpr size_t OFF_FOUT = OFF_QP + 2 * MBy;         // 2 MB bf16
static constexpr size_t OFF_T1 = OFF_FOUT + 2 * MBy;         // 4 MB f32
static constexpr size_t OFF_N = OFF_T1 + 4 * MBy;            // 4 MB f32
static constexpr size_t OFF_NB = OFF_N + 4 * MBy;            // 2 MB bf16
static constexpr size_t OFF_OBJB = OFF_NB + 2 * MBy;         // 1 MB bf16 (1024x512)

extern "C" void kernel_launch(void* const* d_in, const int* in_sizes, int n_in,
                              void* d_out, int out_size, void* d_ws, size_t ws_size,
                              hipStream_t stream) {
  (void)in_sizes; (void)n_in; (void)out_size; (void)ws_size;
  const float* obj = (const float*)d_in[0];
  const float* road = (const float*)d_in[1];
  const float* rgdW = (const float*)d_in[2];
  const float* rgdb = (const float*)d_in[3];
  const float* qkvW = (const float*)d_in[4];
  const float* qkvb = (const float*)d_in[5];
  const float* rgWq = (const float*)d_in[6];
  const float* rgWk = (const float*)d_in[7];
  const float* rgWv = (const float*)d_in[8];
  const float* rgWo = (const float*)d_in[9];
  const float* rglng = (const float*)d_in[10];
  const float* rglnb = (const float*)d_in[11];
  const float* rgfcW = (const float*)d_in[12];
  const float* rgfcb = (const float*)d_in[13];
  const float* rgoW = (const float*)d_in[14];
  const float* rgob = (const float*)d_in[15];
  const float* denW = (const float*)d_in[16];
  const float* denb = (const float*)d_in[17];
  const float* pose = (const float*)d_in[18];
  const float* Wq = (const float*)d_in[19];
  const float* Wk = (const float*)d_in[20];
  const float* Wv = (const float*)d_in[21];
  const float* Wo = (const float*)d_in[22];
  const float* lng = (const float*)d_in[23];
  const float* lnb = (const float*)d_in[24];
  const float* fcW = (const float*)d_in[25];
  const float* fcb = (const float*)d_in[26];

  char* w = (char*)d_ws;
  float* xroad = (float*)(w + OFF_XROAD);
  u16* rgout = (u16*)(w + OFF_RGOUT);
  float* kvr = (float*)(w + OFF_KVR);
  float* ksr = (float*)(w + OFF_KSR);
  float* kvo = (float*)(w + OFF_KVO);
  float* kso = (float*)(w + OFF_KSO);
  u16* wt = (u16*)(w + OFF_WT);
  float* xobj = (float*)(w + OFF_XOBJ);
  u16* xobjb = (u16*)(w + OFF_XOBJB);
  u16* qpB = (u16*)(w + OFF_QP);
  u16* fout = (u16*)(w + OFF_FOUT);
  float* t1 = (float*)(w + OFF_T1);
  float* nF = (float*)(w + OFF_N);
  u16* nB = (u16*)(w + OFF_NB);
  u16* objb = (u16*)(w + OFF_OBJB);

  const size_t E = 1048576;  // elems of a 1024x1024 matrix
  u16* wqT[2] = {wt + 0 * E, wt + 1 * E};
  u16* wkT[2] = {wt + 2 * E, wt + 3 * E};
  u16* wvT[2] = {wt + 4 * E, wt + 5 * E};
  u16* woT[2] = {wt + 6 * E, wt + 7 * E};
  u16* fcT[2] = {wt + 8 * E, wt + 9 * E};
  u16* denT = wt + 10 * E;

  // one-time weight transposes+convert (f32 K x N -> bf16 N x K)
  TP11 tb;
  const float* srcs[10] = {Wq, Wq + E, Wk, Wk + E, Wv, Wv + E, Wo, Wo + E, fcW, fcW + E};
  u16* dsts[10] = {wqT[0], wqT[1], wkT[0], wkT[1], wvT[0], wvT[1], woT[0], woT[1], fcT[0], fcT[1]};
  for (int j = 0; j < 11; ++j) { tb.p[j].s = srcs[j < 10 ? j : 0]; tb.p[j].d = dsts[j < 10 ? j : 0]; }
  transpose_kernel<<<dim3(16, 16, 10), 256, 0, stream>>>(tb, 1024, 1024);
  TP11 td;
  for (int j = 0; j < 11; ++j) { td.p[j].s = denW; td.p[j].d = denT; }
  transpose_kernel<<<dim3(16, 8, 1), 256, 0, stream>>>(td, 512, 1024);
  // obj f32 -> bf16 (1024x512 = 524288 elems)
  cvt_kernel<<<dim3(512), 256, 0, stream>>>(obj, objb);

  // road-graph encoder
  r0_kernel<<<dim3(256), 256, 0, stream>>>(road, rgdW, rgdb, xroad);
  for (int i = 0; i < 2; ++i) {
    hipMemsetAsync(w + OFF_KVR, 0, 2560, stream);
    ra_kernel<<<dim3(256), 256, 0, stream>>>(xroad, qkvW, qkvb, rgWk + i * 256, rgWv + i * 256,
                                             kvr, ksr);
    rb_kernel<<<dim3(256), 256, 0, stream>>>(xroad, qkvW, qkvb, rgWq + i * 256, rgWo + i * 256,
                                             rglng + i * 16, rglnb + i * 16, rgfcW + i * 256,
                                             rgfcb + i * 16, kvr, ksr);
  }
  rc_kernel<<<dim3(4, 4096), 256, 0, stream>>>(xroad, rgoW, rgob, rgout);

  // both layers' kv/ksum in one dispatch (depends only on rgout + weights)
  hipMemsetAsync(w + OFF_KVO, 0, 4 * MBy + 65536, stream);
  kv_kernel<<<dim3(64, 16, 8), 512, 0, stream>>>(rgout, wkT[0], wvT[0], wkT[1], wvT[1], kvo, kso);

  // object encoder init: x = relu(obj @ dense_W + b) + pos_emb
  gemm_kernel<<<dim3(8, 8), 256, 0, stream>>>(objb, denT, 512, xobj, xobjb, denb, pose, 128,
                                              1.f, 1, 0.f);

  for (int i = 0; i < 2; ++i) {
    gemm_kernel<<<dim3(8, 8), 256, 0, stream>>>(xobjb, wqT[i], 1024, nullptr, qpB, nullptr,
                                                nullptr, 1024, NORM_OBJ, 1, STAB);
    q2_kernel<<<dim3(256, 4), 256, 0, stream>>>(qpB, kvo + (size_t)i * 524288,
                                                kso + (size_t)i * 8192, fout);
    gemm_kernel<<<dim3(8, 8), 256, 0, stream>>>(fout, woT[i], 1024, t1, nullptr, nullptr, xobj,
                                                1024, 1.f, 0, 0.f);
    ln_kernel<<<dim3(1024), 256, 0, stream>>>(t1, lng + i * 1024, lnb + i * 1024, nF, nB);
    gemm_kernel<<<dim3(8, 8), 256, 0, stream>>>(nB, fcT[i], 1024, t1, nullptr, fcb + i * 1024, nF,
                                                1024, 1.f, 1, 0.f);
    if (i == 0)
      ln_kernel<<<dim3(1024), 256, 0, stream>>>(t1, lng, lnb, xobj, xobjb);
    else
      ln_kernel<<<dim3(1024), 256, 0, stream>>>(t1, lng + 1024, lnb + 1024, (float*)d_out, nullptr);
  }
}

// Round 11
// 1379.584 us; speedup vs baseline: 1.7180x; 1.0756x over previous
//
#include <hip/hip_runtime.h>

typedef unsigned short u16;
typedef unsigned int u32;

using s8v = __attribute__((ext_vector_type(8))) short;  // 8 bf16
using f4v = __attribute__((ext_vector_type(4))) float;  // 4 fp32

#define LN_EPS 0.001f
#define STAB 0.001f
#define NORM_OBJ 0.35355339059327373f   // 64^-0.25
#define NORM_ROAD 0.7071067811865476f   // 4^-0.25

__device__ __forceinline__ float bf2f(u16 v) { return __uint_as_float(((u32)v) << 16); }
__device__ __forceinline__ u16 f2bf(float f) {
  u32 u = __float_as_uint(f);
  u32 r = (u + 0x7fffu + ((u >> 16) & 1u)) >> 16;
  return (u16)r;
}
__device__ __forceinline__ f4v mfma16(s8v a, s8v b, f4v c) {
  return __builtin_amdgcn_mfma_f32_16x16x32_bf16(a, b, c, 0, 0, 0);
}
// async global->LDS, 16 B/lane; LDS dest = wave-uniform base + lane*16
__device__ __forceinline__ void ldsload16(void* lds, const void* g) {
  __builtin_amdgcn_global_load_lds((const __attribute__((address_space(1))) u32*)g,
                                   (__attribute__((address_space(3))) u32*)lds, 16, 0, 0);
}

// ---------------- transpose+convert: src[K][1024] f32 -> dst[1024][K] bf16 ----------------
struct TPair { const float* s; u16* d; int K; };
struct TP11 { TPair p[11]; };

__global__ __launch_bounds__(256) void transpose_kernel(TP11 ps) {
  const TPair pp = ps.p[blockIdx.z];
  const int K = pp.K;
  const float* __restrict__ src = pp.s;
  u16* __restrict__ dst = pp.d;
  int n0 = blockIdx.x * 64, k0 = blockIdx.y * 64;
  if (k0 >= K) return;
  int t = threadIdx.x;
  __shared__ __align__(16) u16 lt[64 * 72];
#pragma unroll
  for (int j = 0; j < 4; ++j) {
    int p = t + 256 * j;
    int r = p >> 4, cb = p & 15;
    float4 v = *(const float4*)(src + (size_t)(k0 + r) * 1024 + n0 + cb * 4);
    lt[r * 72 + cb * 4 + 0] = f2bf(v.x);
    lt[r * 72 + cb * 4 + 1] = f2bf(v.y);
    lt[r * 72 + cb * 4 + 2] = f2bf(v.z);
    lt[r * 72 + cb * 4 + 3] = f2bf(v.w);
  }
  __syncthreads();
#pragma unroll
  for (int j = 0; j < 2; ++j) {
    int q = t + 256 * j;
    int on = q >> 3, ocb = q & 7;
    u16 e[8];
#pragma unroll
    for (int i = 0; i < 8; ++i) e[i] = lt[(ocb * 8 + i) * 72 + on];
    uint4 v;
    v.x = (u32)e[0] | ((u32)e[1] << 16);
    v.y = (u32)e[2] | ((u32)e[3] << 16);
    v.z = (u32)e[4] | ((u32)e[5] << 16);
    v.w = (u32)e[6] | ((u32)e[7] << 16);
    *(uint4*)(dst + (size_t)(n0 + on) * K + k0 + ocb * 8) = v;
  }
}

// ---------------- f32 -> bf16 convert ----------------
__global__ __launch_bounds__(256) void cvt_kernel(const float* __restrict__ src,
                                                  u16* __restrict__ dst) {
  int i = (blockIdx.x * 256 + threadIdx.x) * 4;
  float4 v = *(const float4*)(src + i);
  uint2 o;
  o.x = (u32)f2bf(v.x) | ((u32)f2bf(v.y) << 16);
  o.y = (u32)f2bf(v.z) | ((u32)f2bf(v.w) << 16);
  *(uint2*)(dst + i) = o;
}

// ---------------- road favor accumulation helper (per-row kp/vh -> block reduce) ---------
__device__ __forceinline__ void road_acc(const float* q16, const float* Wk, const float* Wv,
                                         float* l, int t, int b,
                                         float* kvr, float* ksr) {
  float kp[16], vh[16];
#pragma unroll
  for (int hm = 0; hm < 16; ++hm) {
    float sk = 0.f, sv = 0.f;
#pragma unroll
    for (int c = 0; c < 16; ++c) {
      float q = q16[c];
      sk += q * Wk[c * 16 + hm];
      sv += q * Wv[c * 16 + hm];
    }
    kp[hm] = fmaxf(sk * NORM_ROAD, 0.f) + STAB;
    vh[hm] = sv;
  }
  if (t < 80) l[t] = 0.f;
  __syncthreads();
#pragma unroll
  for (int h = 0; h < 4; ++h)
#pragma unroll
    for (int m = 0; m < 4; ++m) {
      float kpv = kp[h * 4 + m];
      atomicAdd(&l[64 + h * 4 + m], kpv);
#pragma unroll
      for (int d = 0; d < 4; ++d) atomicAdd(&l[h * 16 + m * 4 + d], kpv * vh[h * 4 + d]);
    }
  __syncthreads();
  if (t < 64) atomicAdd(&kvr[b * 64 + t], l[t]);
  else if (t < 80) atomicAdd(&ksr[b * 16 + (t - 64)], l[t]);
}

// ---------------- fused road dense + favor pass1 (layer 0) ----------------
__global__ __launch_bounds__(256) void r0ra_kernel(const float* __restrict__ road,
    const float* __restrict__ W, const float* __restrict__ bias, float* __restrict__ x,
    const float* __restrict__ qkvW, const float* __restrict__ qkvb,
    const float* __restrict__ Wk, const float* __restrict__ Wv,
    float* __restrict__ kvr, float* __restrict__ ksr) {
  int t = threadIdx.x;
  int row = blockIdx.x * 256 + t;
  int b = row >> 13;
  float in[8];
  float4 v0 = *(const float4*)(road + (size_t)row * 8);
  float4 v1 = *(const float4*)(road + (size_t)row * 8 + 4);
  in[0] = v0.x; in[1] = v0.y; in[2] = v0.z; in[3] = v0.w;
  in[4] = v1.x; in[5] = v1.y; in[6] = v1.z; in[7] = v1.w;
  float xv[16];
#pragma unroll
  for (int j = 0; j < 16; ++j) {
    float s = bias[j];
#pragma unroll
    for (int c = 0; c < 8; ++c) s += in[c] * W[c * 16 + j];
    xv[j] = fmaxf(s, 0.f);
    x[(size_t)row * 16 + j] = xv[j];
  }
  float q16[16];
#pragma unroll
  for (int j = 0; j < 16; ++j) {
    float s = qkvb[j];
#pragma unroll
    for (int c = 0; c < 16; ++c) s += xv[c] * qkvW[c * 48 + j];
    q16[j] = fmaxf(s, 0.f);
  }
  __shared__ float l[80];
  road_acc(q16, Wk, Wv, l, t, b, kvr, ksr);
}

__device__ __forceinline__ void ln16(const float* tv, const float* g, const float* bb, float* o) {
  float m = 0.f;
#pragma unroll
  for (int e = 0; e < 16; ++e) m += tv[e];
  m *= (1.f / 16.f);
  float var = 0.f;
#pragma unroll
  for (int e = 0; e < 16; ++e) { float d = tv[e] - m; var += d * d; }
  var *= (1.f / 16.f);
  float rstd = rsqrtf(var + LN_EPS);
#pragma unroll
  for (int e = 0; e < 16; ++e) o[e] = (tv[e] - m) * rstd * g[e] + bb[e];
}

// ---------------- fused road favor pass2 + LN + fc + LN (+ next-layer pass1) -------------
__global__ __launch_bounds__(256) void rbra_kernel(float* __restrict__ x,
    const float* __restrict__ qkvW, const float* __restrict__ qkvb,
    const float* __restrict__ Wq, const float* __restrict__ Wo,
    const float* __restrict__ lng, const float* __restrict__ lnb,
    const float* __restrict__ fcW, const float* __restrict__ fcb,
    const float* __restrict__ kvr, const float* __restrict__ ksr,
    const float* __restrict__ Wkn, const float* __restrict__ Wvn,
    float* __restrict__ kvrn, float* __restrict__ ksrn, int do_next) {
  int t = threadIdx.x;
  int row = blockIdx.x * 256 + t;
  int b = row >> 13;
  float xv[16];
#pragma unroll
  for (int e = 0; e < 16; ++e) xv[e] = x[(size_t)row * 16 + e];
  float q16[16];
#pragma unroll
  for (int j = 0; j < 16; ++j) {
    float s = qkvb[j];
#pragma unroll
    for (int c = 0; c < 16; ++c) s += xv[c] * qkvW[c * 48 + j];
    q16[j] = fmaxf(s, 0.f);
  }
  float qp[16];
#pragma unroll
  for (int hm = 0; hm < 16; ++hm) {
    float s = 0.f;
#pragma unroll
    for (int c = 0; c < 16; ++c) s += q16[c] * Wq[c * 16 + hm];
    qp[hm] = fmaxf(s * NORM_ROAD, 0.f) + STAB;
  }
  float attn[16];
#pragma unroll
  for (int e = 0; e < 16; ++e) attn[e] = 0.f;
#pragma unroll
  for (int h = 0; h < 4; ++h) {
    float den = 0.f;
#pragma unroll
    for (int m = 0; m < 4; ++m) den += qp[h * 4 + m] * ksr[b * 16 + h * 4 + m];
    float od[4];
#pragma unroll
    for (int d = 0; d < 4; ++d) {
      float num = 0.f;
#pragma unroll
      for (int m = 0; m < 4; ++m) num += qp[h * 4 + m] * kvr[b * 64 + h * 16 + m * 4 + d];
      od[d] = num / den;
    }
#pragma unroll
    for (int d = 0; d < 4; ++d)
#pragma unroll
      for (int e = 0; e < 16; ++e) attn[e] += od[d] * Wo[(h * 4 + d) * 16 + e];
  }
  float tv[16], n[16], o2[16];
#pragma unroll
  for (int e = 0; e < 16; ++e) tv[e] = attn[e] + xv[e];
  ln16(tv, lng, lnb, n);
#pragma unroll
  for (int j = 0; j < 16; ++j) {
    float s = fcb[j];
#pragma unroll
    for (int e = 0; e < 16; ++e) s += n[e] * fcW[e * 16 + j];
    tv[j] = n[j] + fmaxf(s, 0.f);
  }
  ln16(tv, lng, lnb, o2);
#pragma unroll
  for (int e = 0; e < 16; ++e) x[(size_t)row * 16 + e] = o2[e];
  __shared__ float l[80];
  if (do_next) {
    float q16n[16];
#pragma unroll
    for (int j = 0; j < 16; ++j) {
      float s = qkvb[j];
#pragma unroll
      for (int c = 0; c < 16; ++c) s += o2[c] * qkvW[c * 48 + j];
      q16n[j] = fmaxf(s, 0.f);
    }
    road_acc(q16n, Wkn, Wvn, l, t, b, kvrn, ksrn);
  }
}

// ---------------- rg_out = relu(x_road @ rg_out_W + b) -> bf16, 65536x1024 ----------------
__global__ __launch_bounds__(256) void rc_kernel(const float* __restrict__ x,
    const float* __restrict__ W, const float* __restrict__ bias, u16* __restrict__ out) {
  const int t = threadIdx.x;
  const int cg = t & 63, rg = t >> 6;
  const int c0 = blockIdx.x * 256 + cg * 4;
  const int r0 = blockIdx.y * 16;
  __shared__ float lx[256];
  lx[t] = x[(size_t)(r0 + (t >> 4)) * 16 + (t & 15)];
  __syncthreads();
  float4 wv[16];
#pragma unroll
  for (int c = 0; c < 16; ++c) wv[c] = *(const float4*)(W + (size_t)c * 1024 + c0);
  float4 bv = *(const float4*)(bias + c0);
#pragma unroll
  for (int k = 0; k < 4; ++k) {
    int rr = rg * 4 + k;
    float s0 = bv.x, s1 = bv.y, s2 = bv.z, s3 = bv.w;
#pragma unroll
    for (int c = 0; c < 16; ++c) {
      float xv = lx[rr * 16 + c];
      s0 += xv * wv[c].x; s1 += xv * wv[c].y; s2 += xv * wv[c].z; s3 += xv * wv[c].w;
    }
    uint2 o;
    o.x = (u32)f2bf(fmaxf(s0, 0.f)) | ((u32)f2bf(fmaxf(s1, 0.f)) << 16);
    o.y = (u32)f2bf(fmaxf(s2, 0.f)) | ((u32)f2bf(fmaxf(s3, 0.f)) << 16);
    *(uint2*)(out + (size_t)(r0 + rr) * 1024 + c0) = o;
  }
}

// ---------------- generic MFMA GEMM: C = act(A[MxK] @ BT[NxK]^T), 128x128 tile ----------------
// Optional split-K over blockIdx.z: each z handles K/gridDim.z, writes to outF + z*zstride.
__global__ __launch_bounds__(256) void gemm_kernel(
    const u16* __restrict__ A, const u16* __restrict__ BT, int K,
    float* __restrict__ outF, u16* __restrict__ outB,
    const float* __restrict__ bias, const float* __restrict__ resF, int resmod,
    float scale, int do_relu, float post, size_t zstride) {
  const int n0 = blockIdx.x * 128, m0 = blockIdx.y * 128;
  const int t = threadIdx.x;
  const int wid = t >> 6, lane = t & 63, quad = lane >> 4, m16 = lane & 15;
  const int wm = wid >> 1, wn = wid & 1;
  const int lrr = lane >> 3;
  const int lcs = (((lane & 7) ^ lrr) * 8);
  const int sw = m16 & 7;
  if (outF) outF += (size_t)blockIdx.z * zstride;
  const int kper = K / gridDim.z;
  const int kbeg = blockIdx.z * kper;
  __shared__ __align__(16) u16 smem[2 * 128 * 64];
  u16* Al = smem;
  u16* Bl = smem + 128 * 64;
  f4v acc[4][4];
#pragma unroll
  for (int i = 0; i < 4; ++i)
#pragma unroll
    for (int j = 0; j < 4; ++j) acc[i][j] = {0.f, 0.f, 0.f, 0.f};

  for (int kc = kbeg; kc < kbeg + kper; kc += 64) {
    __syncthreads();
#pragma unroll
    for (int j = 0; j < 4; ++j) {
      int rbase = wid * 32 + j * 8;
      ldsload16(Al + rbase * 64, A + (size_t)(m0 + rbase + lrr) * K + kc + lcs);
      ldsload16(Bl + rbase * 64, BT + (size_t)(n0 + rbase + lrr) * K + kc + lcs);
    }
    __syncthreads();
#pragma unroll
    for (int ko = 0; ko < 64; ko += 32) {
      int g0 = ko >> 3;
      s8v af[4], bfr[4];
#pragma unroll
      for (int tm = 0; tm < 4; ++tm)
        af[tm] = *(const s8v*)(Al + (wm * 64 + tm * 16 + m16) * 64 + ((g0 + quad) ^ sw) * 8);
#pragma unroll
      for (int tn = 0; tn < 4; ++tn)
        bfr[tn] = *(const s8v*)(Bl + (wn * 64 + tn * 16 + m16) * 64 + ((g0 + quad) ^ sw) * 8);
#pragma unroll
      for (int tm = 0; tm < 4; ++tm)
#pragma unroll
        for (int tn = 0; tn < 4; ++tn)
          acc[tm][tn] = mfma16(af[tm], bfr[tn], acc[tm][tn]);
    }
  }
#pragma unroll
  for (int tm = 0; tm < 4; ++tm)
#pragma unroll
    for (int tn = 0; tn < 4; ++tn)
#pragma unroll
      for (int r = 0; r < 4; ++r) {
        int row = m0 + wm * 64 + tm * 16 + quad * 4 + r;
        int col = n0 + wn * 64 + tn * 16 + m16;
        float v = acc[tm][tn][r] * scale;
        if (bias) v += bias[col];
        if (do_relu) v = fmaxf(v, 0.f);
        v += post;
        if (resF) v += resF[(size_t)(row % resmod) * 1024 + col];
        if (outF) outF[(size_t)row * 1024 + col] = v;
        if (outB) outB[(size_t)row * 1024 + col] = f2bf(v);
      }
}

// ---------------- fused K/V projection + kv/ksum accumulation, BOTH layers ----------------
// 512 threads (8 waves), tile 128 s-rows x 256 cols = 2 heads x (64k|64v).
// grid (64 s-tiles, 16 lay*headpair, 8 batches): blockIdx.x = mt keeps the XCD swizzle.
__global__ __launch_bounds__(512) void kv_kernel(
    const u16* __restrict__ rgout,
    const u16* __restrict__ WkT0, const u16* __restrict__ WvT0,
    const u16* __restrict__ WkT1, const u16* __restrict__ WvT1,
    float* __restrict__ kv, float* __restrict__ ksum) {
  const int mt = blockIdx.x, y = blockIdx.y, b = blockIdx.z;
  const int lay = y >> 3, hp = y & 7;
  const u16* __restrict__ WkT = lay ? WkT1 : WkT0;
  const u16* __restrict__ WvT = lay ? WvT1 : WvT0;
  kv += (size_t)lay * 524288;
  ksum += (size_t)lay * 8192;
  const int t = threadIdx.x;
  const int wid = t >> 6, lane = t & 63, quad = lane >> 4, m16 = lane & 15;
  const int wm = wid >> 2, wn = wid & 3;
  const int lrr = lane >> 3;
  const int lcs = (((lane & 7) ^ lrr) * 8);
  const int sw = m16 & 7;
  const int HSZ = 64 * 136;
  __shared__ __align__(16) u16 smem[4 * 64 * 136];
  u16* Al = smem;
  u16* Bl = smem + 128 * 64;
  const size_t abase = ((size_t)b * 8192 + (size_t)mt * 128) * 1024;
  f4v acc[4][4];
#pragma unroll
  for (int i = 0; i < 4; ++i)
#pragma unroll
    for (int j = 0; j < 4; ++j) acc[i][j] = {0.f, 0.f, 0.f, 0.f};

  for (int kc = 0; kc < 1024; kc += 64) {
    __syncthreads();
#pragma unroll
    for (int j = 0; j < 2; ++j) {
      int rbase = wid * 16 + j * 8;
      ldsload16(Al + rbase * 64, rgout + abase + (size_t)(rbase + lrr) * 1024 + kc + lcs);
    }
#pragma unroll
    for (int j = 0; j < 4; ++j) {
      int rbase = wid * 32 + j * 8;
      int r = rbase + lrr;
      int h = hp * 2 + (r >> 7), rr = r & 127;
      const u16* bsrc = (rr < 64) ? (WkT + (size_t)(h * 64 + rr) * 1024)
                                  : (WvT + (size_t)(h * 64 + (rr - 64)) * 1024);
      ldsload16(Bl + rbase * 64, bsrc + kc + lcs);
    }
    __syncthreads();
#pragma unroll
    for (int ko = 0; ko < 64; ko += 32) {
      int g0 = ko >> 3;
      s8v af[4], bfr[4];
#pragma unroll
      for (int tm = 0; tm < 4; ++tm)
        af[tm] = *(const s8v*)(Al + (wm * 64 + tm * 16 + m16) * 64 + ((g0 + quad) ^ sw) * 8);
#pragma unroll
      for (int tn = 0; tn < 4; ++tn)
        bfr[tn] = *(const s8v*)(Bl + (wn * 64 + tn * 16 + m16) * 64 + ((g0 + quad) ^ sw) * 8);
#pragma unroll
      for (int tm = 0; tm < 4; ++tm)
#pragma unroll
        for (int tn = 0; tn < 4; ++tn)
          acc[tm][tn] = mfma16(af[tm], bfr[tn], acc[tm][tn]);
    }
  }
  __syncthreads();
  {
    int hh = wn >> 1;
    u16* dst = smem + (size_t)(hh * 2 + (wn & 1)) * HSZ;
    const int iskp = (wn & 1) == 0;
    const int sbase = wm * 64 + quad * 4;
#pragma unroll
    for (int tm = 0; tm < 4; ++tm)
#pragma unroll
      for (int tn = 0; tn < 4; ++tn) {
        float v0 = acc[tm][tn][0], v1 = acc[tm][tn][1];
        float v2 = acc[tm][tn][2], v3 = acc[tm][tn][3];
        if (iskp) {
          v0 = fmaxf(v0 * NORM_OBJ, 0.f) + STAB;
          v1 = fmaxf(v1 * NORM_OBJ, 0.f) + STAB;
          v2 = fmaxf(v2 * NORM_OBJ, 0.f) + STAB;
          v3 = fmaxf(v3 * NORM_OBJ, 0.f) + STAB;
        }
        uint2 o;
        o.x = (u32)f2bf(v0) | ((u32)f2bf(v1) << 16);
        o.y = (u32)f2bf(v2) | ((u32)f2bf(v3) << 16);
        int feat = tn * 16 + m16;
        *(uint2*)(dst + feat * 136 + sbase + tm * 16) = o;
      }
  }
  __syncthreads();
  if (t < 128) {
    int hh = t >> 6, m = t & 63;
    const u16* base = smem + (size_t)(hh * 2) * HSZ + m * 136;
    float s = 0.f;
#pragma unroll
    for (int i = 0; i < 128; i += 8) {
      uint4 v = *(const uint4*)(base + i);
      u32 a[4] = {v.x, v.y, v.z, v.w};
#pragma unroll
      for (int q = 0; q < 4; ++q) {
        s += __uint_as_float(a[q] << 16);
        s += __uint_as_float(a[q] & 0xffff0000u);
      }
    }
    atomicAdd(&ksum[(size_t)(b * 16 + hp * 2 + hh) * 64 + m], s);
  }
  {
    int hh = wid >> 2, mq = wid & 3;
    const u16* KPh = smem + (size_t)(hh * 2) * HSZ;
    const u16* Vh = KPh + HSZ;
    f4v a2[4];
#pragma unroll
    for (int tn = 0; tn < 4; ++tn) a2[tn] = {0.f, 0.f, 0.f, 0.f};
#pragma unroll
    for (int ks = 0; ks < 128; ks += 32) {
      s8v af = *(const s8v*)(KPh + (mq * 16 + m16) * 136 + ks + quad * 8);
#pragma unroll
      for (int tn = 0; tn < 4; ++tn) {
        s8v bv = *(const s8v*)(Vh + (tn * 16 + m16) * 136 + ks + quad * 8);
        a2[tn] = mfma16(af, bv, a2[tn]);
      }
    }
    int h = hp * 2 + hh;
#pragma unroll
    for (int tn = 0; tn < 4; ++tn)
#pragma unroll
      for (int r = 0; r < 4; ++r) {
        int m = mq * 16 + quad * 4 + r;
        int d = tn * 16 + m16;
        atomicAdd(&kv[((size_t)(b * 16 + h) * 64 + m) * 64 + d], a2[tn][r]);
      }
  }
}

// ---------------- obj favor: qp from split-K partials; out = (qp@kv)/(qp.ksum) ----------
__global__ __launch_bounds__(256) void q2_kernel(const float* __restrict__ p0,
    const float* __restrict__ p1,
    const float* __restrict__ kv, const float* __restrict__ ks, u16* __restrict__ out) {
  int wid = threadIdx.x >> 6, lane = threadIdx.x & 63;
  int row = blockIdx.x * 4 + wid;
  int b = row >> 7;
  int h0 = blockIdx.y * 4;
  for (int h = h0; h < h0 + 4; ++h) {
    const float* kvp = kv + (size_t)((b * 16 + h) * 64) * 64;
    const float* ksp = ks + (size_t)(b * 16 + h) * 64;
    size_t base = (size_t)row * 1024 + h * 64;
    float num = 0.f, den = 0.f;
    for (int m = 0; m < 64; ++m) {
      float qv = fmaxf((p0[base + m] + p1[base + m]) * NORM_OBJ, 0.f) + STAB;
      num += qv * kvp[m * 64 + lane];
      den += qv * ksp[m];
    }
    out[base + lane] = f2bf(num / den);
  }
}

// ---------------- layernorm over 1024 with split-K combine prologue ----------------
// v = p0+p1 [+bias] [relu] [+res]; then LN(g,bb) -> outF/outB
__global__ __launch_bounds__(256) void ln_kernel(const float* __restrict__ p0,
    const float* __restrict__ p1, const float* __restrict__ bias,
    const float* __restrict__ res, int do_relu,
    const float* __restrict__ g, const float* __restrict__ bb,
    float* __restrict__ outF, u16* __restrict__ outB) {
  int row = blockIdx.x, t = threadIdx.x;
  size_t base = (size_t)row * 1024;
  float v[4];
  float s = 0.f, ss = 0.f;
#pragma unroll
  for (int j = 0; j < 4; ++j) {
    int c = t + 256 * j;
    float x = p0[base + c] + p1[base + c];
    if (bias) x += bias[c];
    if (do_relu) x = fmaxf(x, 0.f);
    if (res) x += res[base + c];
    v[j] = x;
    s += x;
    ss += x * x;
  }
  __shared__ float rs[256], rss[256];
  rs[t] = s; rss[t] = ss;
  __syncthreads();
  for (int o = 128; o > 0; o >>= 1) {
    if (t < o) { rs[t] += rs[t + o]; rss[t] += rss[t + o]; }
    __syncthreads();
  }
  float mean = rs[0] * (1.f / 1024.f);
  float var = rss[0] * (1.f / 1024.f) - mean * mean;
  float rstd = rsqrtf(var + LN_EPS);
#pragma unroll
  for (int j = 0; j < 4; ++j) {
    int c = t + 256 * j;
    float o = (v[j] - mean) * rstd * g[c] + bb[c];
    if (outF) outF[base + c] = o;
    if (outB) outB[base + c] = f2bf(o);
  }
}

// ---------------- workspace layout (bytes) ----------------
static constexpr size_t MBy = 1048576;
static constexpr size_t OFF_XROAD = 0;                       // 4 MB f32 (65536x16)
static constexpr size_t OFF_RGOUT = 4 * MBy;                 // 128 MiB bf16 (65536x1024)
static constexpr size_t OFF_KVR = OFF_RGOUT + 128 * MBy;     // 4096 B (2 layers x 8 x 64 f32)
static constexpr size_t OFF_KSR = OFF_KVR + 4096;            // 1024 B (2 layers x 8 x 16 f32)
static constexpr size_t OFF_KVO = OFF_KVR + 8192;            // 4 MB f32 (2 layers x 2MB)
static constexpr size_t OFF_KSO = OFF_KVO + 4 * MBy;         // 64 KB f32 (2 layers x 32KB)
static constexpr size_t OFF_WT = OFF_KSO + 65536;            // 21 MB bf16 transposed weights
static constexpr size_t OFF_XOBJ = OFF_WT + 21 * MBy;        // 4 MB f32
static constexpr size_t OFF_XOBJB = OFF_XOBJ + 4 * MBy;      // 2 MB bf16
static constexpr size_t OFF_P0 = OFF_XOBJB + 2 * MBy;        // 8 MB f32 (two 4MB split-K partials)
static constexpr size_t OFF_FOUT = OFF_P0 + 8 * MBy;         // 2 MB bf16
static constexpr size_t OFF_N = OFF_FOUT + 2 * MBy;          // 4 MB f32
static constexpr size_t OFF_NB = OFF_N + 4 * MBy;            // 2 MB bf16
static constexpr size_t OFF_OBJB = OFF_NB + 2 * MBy;         // 1 MB bf16 (1024x512)

extern "C" void kernel_launch(void* const* d_in, const int* in_sizes, int n_in,
                              void* d_out, int out_size, void* d_ws, size_t ws_size,
                              hipStream_t stream) {
  (void)in_sizes; (void)n_in; (void)out_size; (void)ws_size;
  const float* obj = (const float*)d_in[0];
  const float* road = (const float*)d_in[1];
  const float* rgdW = (const float*)d_in[2];
  const float* rgdb = (const float*)d_in[3];
  const float* qkvW = (const float*)d_in[4];
  const float* qkvb = (const float*)d_in[5];
  const float* rgWq = (const float*)d_in[6];
  const float* rgWk = (const float*)d_in[7];
  const float* rgWv = (const float*)d_in[8];
  const float* rgWo = (const float*)d_in[9];
  const float* rglng = (const float*)d_in[10];
  const float* rglnb = (const float*)d_in[11];
  const float* rgfcW = (const float*)d_in[12];
  const float* rgfcb = (const float*)d_in[13];
  const float* rgoW = (const float*)d_in[14];
  const float* rgob = (const float*)d_in[15];
  const float* denW = (const float*)d_in[16];
  const float* denb = (const float*)d_in[17];
  const float* pose = (const float*)d_in[18];
  const float* Wq = (const float*)d_in[19];
  const float* Wk = (const float*)d_in[20];
  const float* Wv = (const float*)d_in[21];
  const float* Wo = (const float*)d_in[22];
  const float* lng = (const float*)d_in[23];
  const float* lnb = (const float*)d_in[24];
  const float* fcW = (const float*)d_in[25];
  const float* fcb = (const float*)d_in[26];

  char* w = (char*)d_ws;
  float* xroad = (float*)(w + OFF_XROAD);
  u16* rgout = (u16*)(w + OFF_RGOUT);
  float* kvr = (float*)(w + OFF_KVR);
  float* ksr = (float*)(w + OFF_KSR);
  float* kvo = (float*)(w + OFF_KVO);
  float* kso = (float*)(w + OFF_KSO);
  u16* wt = (u16*)(w + OFF_WT);
  float* xobj = (float*)(w + OFF_XOBJ);
  u16* xobjb = (u16*)(w + OFF_XOBJB);
  float* P0 = (float*)(w + OFF_P0);
  float* P1 = P0 + 1048576;
  u16* fout = (u16*)(w + OFF_FOUT);
  float* nF = (float*)(w + OFF_N);
  u16* nB = (u16*)(w + OFF_NB);
  u16* objb = (u16*)(w + OFF_OBJB);

  const size_t E = 1048576;  // elems of a 1024x1024 matrix
  u16* wqT[2] = {wt + 0 * E, wt + 1 * E};
  u16* wkT[2] = {wt + 2 * E, wt + 3 * E};
  u16* wvT[2] = {wt + 4 * E, wt + 5 * E};
  u16* woT[2] = {wt + 6 * E, wt + 7 * E};
  u16* fcT[2] = {wt + 8 * E, wt + 9 * E};
  u16* denT = wt + 10 * E;

  // one-time weight transposes+convert (f32 K x 1024 -> bf16 1024 x K), single dispatch
  TP11 tb;
  const float* srcs[11] = {Wq, Wq + E, Wk, Wk + E, Wv, Wv + E, Wo, Wo + E, fcW, fcW + E, denW};
  u16* dsts[11] = {wqT[0], wqT[1], wkT[0], wkT[1], wvT[0], wvT[1], woT[0], woT[1],
                   fcT[0], fcT[1], denT};
  for (int j = 0; j < 11; ++j) { tb.p[j].s = srcs[j]; tb.p[j].d = dsts[j]; tb.p[j].K = (j == 10) ? 512 : 1024; }
  transpose_kernel<<<dim3(16, 16, 11), 256, 0, stream>>>(tb);
  // obj f32 -> bf16 (1024x512 = 524288 elems)
  cvt_kernel<<<dim3(512), 256, 0, stream>>>(obj, objb);

  // road-graph encoder (fused): r0+ra0 -> rb0+ra1 -> rb1 -> rc
  hipMemsetAsync(w + OFF_KVR, 0, 5120, stream);
  r0ra_kernel<<<dim3(256), 256, 0, stream>>>(road, rgdW, rgdb, xroad, qkvW, qkvb,
                                             rgWk, rgWv, kvr, ksr);
  rbra_kernel<<<dim3(256), 256, 0, stream>>>(xroad, qkvW, qkvb, rgWq, rgWo, rglng, rglnb,
                                             rgfcW, rgfcb, kvr, ksr,
                                             rgWk + 256, rgWv + 256, kvr + 512, ksr + 128, 1);
  rbra_kernel<<<dim3(256), 256, 0, stream>>>(xroad, qkvW, qkvb, rgWq + 256, rgWo + 256,
                                             rglng + 16, rglnb + 16, rgfcW + 256, rgfcb + 16,
                                             kvr + 512, ksr + 128,
                                             nullptr, nullptr, nullptr, nullptr, 0);
  rc_kernel<<<dim3(4, 4096), 256, 0, stream>>>(xroad, rgoW, rgob, rgout);

  // both layers' kv/ksum in one dispatch (depends only on rgout + weights)
  hipMemsetAsync(w + OFF_KVO, 0, 4 * MBy + 65536, stream);
  kv_kernel<<<dim3(64, 16, 8), 512, 0, stream>>>(rgout, wkT[0], wvT[0], wkT[1], wvT[1], kvo, kso);

  // object encoder init: x = relu(obj @ dense_W + b) + pos_emb
  gemm_kernel<<<dim3(8, 8, 1), 256, 0, stream>>>(objb, denT, 512, xobj, xobjb, denb, pose, 128,
                                                 1.f, 1, 0.f, 0);

  for (int i = 0; i < 2; ++i) {
    // qp partials (combine + act folded into q2)
    gemm_kernel<<<dim3(8, 8, 2), 256, 0, stream>>>(xobjb, wqT[i], 1024, P0, nullptr, nullptr,
                                                   nullptr, 1024, 1.f, 0, 0.f, 1048576);
    q2_kernel<<<dim3(256, 4), 256, 0, stream>>>(P0, P1, kvo + (size_t)i * 524288,
                                                kso + (size_t)i * 8192, fout);
    // attn @ Wo partials (combine + residual folded into ln)
    gemm_kernel<<<dim3(8, 8, 2), 256, 0, stream>>>(fout, woT[i], 1024, P0, nullptr, nullptr,
                                                   nullptr, 1024, 1.f, 0, 0.f, 1048576);
    ln_kernel<<<dim3(1024), 256, 0, stream>>>(P0, P1, nullptr, xobj, 0,
                                              lng + i * 1024, lnb + i * 1024, nF, nB);
    // fc partials (combine + bias + relu + residual folded into ln)
    gemm_kernel<<<dim3(8, 8, 2), 256, 0, stream>>>(nB, fcT[i], 1024, P0, nullptr, nullptr,
                                                   nullptr, 1024, 1.f, 0, 0.f, 1048576);
    if (i == 0)
      ln_kernel<<<dim3(1024), 256, 0, stream>>>(P0, P1, fcb, nF, 1, lng, lnb, xobj, xobjb);
    else
      ln_kernel<<<dim3(1024), 256, 0, stream>>>(P0, P1, fcb + 1024, nF, 1, lng + 1024,
                                                lnb + 1024, (float*)d_out, nullptr);
  }
}